// Round 5
// baseline (24578.445 us; speedup 1.0000x reference)
//
#include <hip/hip_runtime.h>

#define BATCH 32
#define TENC  1024
#define HD    1024
#define ED    128
#define LL    128
#define GD    4096
#define IND   1152
#define HSTEP (BATCH*HD)

// ws float offsets
#define HBUF_OFF 131072                       // base: [0, 131072)
#define CNT_OFF  (HBUF_OFF + 129*HSTEP)       // h ring [129][32][1024]
#define E_OFF    (CNT_OFF + 64)
#define P_OFF    (E_OFF + BATCH*LL*TENC)
#define CTX_OFF  (P_OFF + BATCH*LL*TENC)

__device__ __forceinline__ float sigf(float x) {
  return __builtin_amdgcn_rcpf(1.0f + __expf(-x));
}
__device__ __forceinline__ float tanhf_fast(float x) {
  return 1.0f - 2.0f * __builtin_amdgcn_rcpf(1.0f + __expf(2.0f * x));
}
__device__ __forceinline__ void cstf(float* p, float v) {   // write-through to MALL
  __hip_atomic_store(p, v, __ATOMIC_RELAXED, __HIP_MEMORY_SCOPE_AGENT);
}
// grid barrier, no cache-flushing fences (R4-proven)
__device__ __forceinline__ void gbar(unsigned* cnt, unsigned target) {
  __syncthreads();
  if (threadIdx.x == 0) {
    __hip_atomic_fetch_add(cnt, 1u, __ATOMIC_RELAXED, __HIP_MEMORY_SCOPE_AGENT);
    while (__hip_atomic_load(cnt, __ATOMIC_RELAXED, __HIP_MEMORY_SCOPE_AGENT) < target)
      __builtin_amdgcn_s_sleep(2);
  }
  __syncthreads();
}

// base[b][g] = b_ih[g]+b_hh[g]+dot(ctx0[b], W_ih[g][E:])
__global__ __launch_bounds__(256) void base_kernel(
    const float* __restrict__ ctxt, const float* __restrict__ Wih,
    const float* __restrict__ bih, const float* __restrict__ bhh,
    float* __restrict__ base) {
  int id = blockIdx.x * 256 + threadIdx.x;
  int b = id & (BATCH - 1);
  int g = id >> 5;
  const float4* c4 = reinterpret_cast<const float4*>(ctxt + (size_t)b * TENC * HD);
  const float4* w4 = reinterpret_cast<const float4*>(Wih + (size_t)g * IND + ED);
  float a = 0.f;
#pragma unroll 8
  for (int kk = 0; kk < HD/4; ++kk) {
    float4 c = c4[kk], w = w4[kk];
    a += c.x*w.x + c.y*w.y + c.z*w.z + c.w*w.w;
  }
  base[(size_t)b * GD + g] = a + bih[g] + bhh[g];
}

// ---------------- Phase A: recurrence only ----------------
// 256 blocks (rg) x 1024 thr. Wave w: q=w>>1 (b-quad), jp=w&1.
// lane: b'=lane>>4, kq=lane&15. Rows r = u*4+gate, j = rg*4 + jp*2 + u.
__global__ __launch_bounds__(1024) void phaseA(
    const float* __restrict__ gt, const float* __restrict__ Wih,
    const float* __restrict__ Whh, float* __restrict__ ws) {
  const int rg = blockIdx.x;
  const int tid = threadIdx.x;
  const int w = tid >> 6, lane = tid & 63;
  const int q = w >> 1, jp = w & 1;
  const int bp = lane >> 4, kq = lane & 15;
  const int b = q * 4 + bp;
  float* base = ws;
  float* hbuf = ws + HBUF_OFF;
  unsigned* cnt = reinterpret_cast<unsigned*>(ws + CNT_OFF);

  int grow[8];
#pragma unroll
  for (int r = 0; r < 8; ++r)
    grow[r] = (r & 3) * HD + rg * 4 + jp * 2 + (r >> 2);

  const int u = kq;                       // valid when kq<2
  const int j = rg * 4 + jp * 2 + u;
  float c_reg = 0.0f;

  for (int k = 0; k < LL; ++k) {
    const float* hp = hbuf + (size_t)k * HSTEP + (size_t)b * HD;
    float acc[8] = {0,0,0,0,0,0,0,0};
#pragma unroll
    for (int half = 0; half < 2; ++half) {
      float4 h4[8];
#pragma unroll
      for (int c = 0; c < 8; ++c)
        h4[c] = *reinterpret_cast<const float4*>(hp + (half*8 + c)*64 + kq*4);
#pragma unroll
      for (int r = 0; r < 8; ++r) {
        const float* wr = Whh + (size_t)grow[r] * HD;
#pragma unroll
        for (int c = 0; c < 8; ++c) {
          float4 wv = *reinterpret_cast<const float4*>(wr + (half*8 + c)*64 + kq*4);
          acc[r] += h4[c].x*wv.x + h4[c].y*wv.y + h4[c].z*wv.z + h4[c].w*wv.w;
        }
      }
    }
    // word part (IND cols [0,128))
    float4 wd0, wd1;
    if (k == 0) {
      wd0 = make_float4(kq == 0 ? 1.0f : 0.0f, 0, 0, 0);
      wd1 = make_float4(0, 0, 0, 0);
    } else {
      const float* gp = gt + ((size_t)b * LL + (k - 1)) * ED + kq * 8;
      wd0 = *reinterpret_cast<const float4*>(gp);
      wd1 = *reinterpret_cast<const float4*>(gp + 4);
    }
#pragma unroll
    for (int r = 0; r < 8; ++r) {
      const float* wi = Wih + (size_t)grow[r] * IND + kq * 8;
      float4 a0 = *reinterpret_cast<const float4*>(wi);
      float4 a1 = *reinterpret_cast<const float4*>(wi + 4);
      acc[r] += wd0.x*a0.x + wd0.y*a0.y + wd0.z*a0.z + wd0.w*a0.w
              + wd1.x*a1.x + wd1.y*a1.y + wd1.z*a1.z + wd1.w*a1.w;
    }
    // allreduce over 16 kq lanes
#pragma unroll
    for (int o = 1; o < 16; o <<= 1) {
#pragma unroll
      for (int r = 0; r < 8; ++r) acc[r] += __shfl_xor(acc[r], o);
    }
    if (kq < 2) {
      const float* bb = base + (size_t)b * GD;
      float ig = sigf(acc[u*4+0] + bb[j]);
      float fg = sigf(acc[u*4+1] + bb[HD + j]);
      float gg = tanhf_fast(acc[u*4+2] + bb[2*HD + j]);
      float og = sigf(acc[u*4+3] + bb[3*HD + j]);
      c_reg = fg * c_reg + ig * gg;
      cstf(hbuf + (size_t)(k + 1) * HSTEP + (size_t)b * HD + j,
           og * tanhf_fast(c_reg));
    }
    if (k < LL - 1) gbar(cnt, (unsigned)((k + 1) * 256));
  }
}

// ---------------- Phase B1: E[b][t][p] = sum_d H[t][d] C[p][d] ----------------
__global__ __launch_bounds__(256) void b1_energy(
    const float* __restrict__ ctxt, float* __restrict__ ws) {
  const int b = blockIdx.x & 31, pt = blockIdx.x >> 5;   // XCD = b%8
  const int p0 = pt * 128;
  const int tid = threadIdx.x, tx = tid & 15, ty = tid >> 4;
  const float* hbuf = ws + HBUF_OFF;
  float* E = ws + E_OFF;
  __shared__ float Ht[128][18];
  __shared__ float CtT[16][132];
  float acc[8][8];
#pragma unroll
  for (int i = 0; i < 8; ++i)
#pragma unroll
    for (int jj = 0; jj < 8; ++jj) acc[i][jj] = 0.f;

  const int sr = tid >> 1, sc = (tid & 1) * 8;
  float4 a0, a1, c0, c1;
  {
    const float* hs = hbuf + (size_t)(sr + 1) * HSTEP + (size_t)b * HD + sc;
    a0 = *reinterpret_cast<const float4*>(hs);
    a1 = *reinterpret_cast<const float4*>(hs + 4);
    const float* cs = ctxt + ((size_t)b * TENC + p0 + sr) * HD + sc;
    c0 = *reinterpret_cast<const float4*>(cs);
    c1 = *reinterpret_cast<const float4*>(cs + 4);
  }
  for (int kt = 0; kt < 64; ++kt) {
    __syncthreads();
    *reinterpret_cast<float4*>(&Ht[sr][sc]) = a0;
    *reinterpret_cast<float4*>(&Ht[sr][sc + 4]) = a1;
    CtT[sc+0][sr] = c0.x; CtT[sc+1][sr] = c0.y; CtT[sc+2][sr] = c0.z; CtT[sc+3][sr] = c0.w;
    CtT[sc+4][sr] = c1.x; CtT[sc+5][sr] = c1.y; CtT[sc+6][sr] = c1.z; CtT[sc+7][sr] = c1.w;
    __syncthreads();
    if (kt < 63) {
      const int d0 = (kt + 1) * 16;
      const float* hs = hbuf + (size_t)(sr + 1) * HSTEP + (size_t)b * HD + d0 + sc;
      a0 = *reinterpret_cast<const float4*>(hs);
      a1 = *reinterpret_cast<const float4*>(hs + 4);
      const float* cs = ctxt + ((size_t)b * TENC + p0 + sr) * HD + d0 + sc;
      c0 = *reinterpret_cast<const float4*>(cs);
      c1 = *reinterpret_cast<const float4*>(cs + 4);
    }
#pragma unroll
    for (int kk2 = 0; kk2 < 8; ++kk2) {
      float2 av[8];
#pragma unroll
      for (int i = 0; i < 8; ++i)
        av[i] = *reinterpret_cast<const float2*>(&Ht[ty*8 + i][kk2*2]);
      float4 b00 = *reinterpret_cast<const float4*>(&CtT[kk2*2][tx*8]);
      float4 b01 = *reinterpret_cast<const float4*>(&CtT[kk2*2][tx*8 + 4]);
      float4 b10 = *reinterpret_cast<const float4*>(&CtT[kk2*2+1][tx*8]);
      float4 b11 = *reinterpret_cast<const float4*>(&CtT[kk2*2+1][tx*8 + 4]);
#pragma unroll
      for (int i = 0; i < 8; ++i) {
        acc[i][0] += av[i].x*b00.x + av[i].y*b10.x;
        acc[i][1] += av[i].x*b00.y + av[i].y*b10.y;
        acc[i][2] += av[i].x*b00.z + av[i].y*b10.z;
        acc[i][3] += av[i].x*b00.w + av[i].y*b10.w;
        acc[i][4] += av[i].x*b01.x + av[i].y*b11.x;
        acc[i][5] += av[i].x*b01.y + av[i].y*b11.y;
        acc[i][6] += av[i].x*b01.z + av[i].y*b11.z;
        acc[i][7] += av[i].x*b01.w + av[i].y*b11.w;
      }
    }
  }
#pragma unroll
  for (int i = 0; i < 8; ++i) {
    float* ep = E + ((size_t)b * LL + ty*8 + i) * TENC + p0 + tx*8;
    *reinterpret_cast<float4*>(ep)     = make_float4(acc[i][0], acc[i][1], acc[i][2], acc[i][3]);
    *reinterpret_cast<float4*>(ep + 4) = make_float4(acc[i][4], acc[i][5], acc[i][6], acc[i][7]);
  }
}

// ---------------- Phase B2: row softmax E -> P ----------------
__global__ __launch_bounds__(1024) void b2_softmax(float* __restrict__ ws) {
  const int b = blockIdx.x;
  const int w = threadIdx.x >> 6, lane = threadIdx.x & 63;
  const float* E = ws + E_OFF;
  float* P = ws + P_OFF;
#pragma unroll
  for (int rr = 0; rr < 8; ++rr) {
    const int t = w * 8 + rr;
    const float4* e4 = reinterpret_cast<const float4*>(E + ((size_t)b * LL + t) * TENC);
    float4 v[4];
#pragma unroll
    for (int c = 0; c < 4; ++c) v[c] = e4[c * 64 + lane];
    float m = fmaxf(fmaxf(fmaxf(v[0].x, v[0].y), fmaxf(v[0].z, v[0].w)),
                    fmaxf(fmaxf(v[1].x, v[1].y), fmaxf(v[1].z, v[1].w)));
    m = fmaxf(m, fmaxf(fmaxf(fmaxf(v[2].x, v[2].y), fmaxf(v[2].z, v[2].w)),
                       fmaxf(fmaxf(v[3].x, v[3].y), fmaxf(v[3].z, v[3].w))));
#pragma unroll
    for (int o = 32; o > 0; o >>= 1) m = fmaxf(m, __shfl_xor(m, o));
    float s = 0.f;
#pragma unroll
    for (int c = 0; c < 4; ++c) {
      v[c].x = __expf(v[c].x - m); v[c].y = __expf(v[c].y - m);
      v[c].z = __expf(v[c].z - m); v[c].w = __expf(v[c].w - m);
      s += v[c].x + v[c].y + v[c].z + v[c].w;
    }
#pragma unroll
    for (int o = 32; o > 0; o >>= 1) s += __shfl_xor(s, o);
    float inv = __builtin_amdgcn_rcpf(s);
    float4* p4 = reinterpret_cast<float4*>(P + ((size_t)b * LL + t) * TENC);
#pragma unroll
    for (int c = 0; c < 4; ++c) {
      float4 o4 = make_float4(v[c].x*inv, v[c].y*inv, v[c].z*inv, v[c].w*inv);
      p4[c * 64 + lane] = o4;
    }
  }
}

// ---------------- Phase B3: CTX[b][t][d] = sum_p P[t][p] C[p][d] ----------------
__global__ __launch_bounds__(256) void b3_ctx(
    const float* __restrict__ ctxt, float* __restrict__ ws) {
  const int b = blockIdx.x & 31, dt = blockIdx.x >> 5;
  const int d0 = dt * 128;
  const int tid = threadIdx.x, tx = tid & 15, ty = tid >> 4;
  const float* P = ws + P_OFF;
  float* CTX = ws + CTX_OFF;
  __shared__ float Pt[128][18];
  __shared__ float Cd[16][132];
  float acc[8][8];
#pragma unroll
  for (int i = 0; i < 8; ++i)
#pragma unroll
    for (int jj = 0; jj < 8; ++jj) acc[i][jj] = 0.f;

  const int sr = tid >> 1, sc = (tid & 1) * 8;       // Pt loader
  const int cr = tid >> 4, cc = (tid & 15) * 8;      // Cd loader
  float4 a0, a1, c0, c1;
  {
    const float* ps = P + ((size_t)b * LL + sr) * TENC + sc;
    a0 = *reinterpret_cast<const float4*>(ps);
    a1 = *reinterpret_cast<const float4*>(ps + 4);
    const float* cs = ctxt + ((size_t)b * TENC + cr) * HD + d0 + cc;
    c0 = *reinterpret_cast<const float4*>(cs);
    c1 = *reinterpret_cast<const float4*>(cs + 4);
  }
  for (int kt = 0; kt < 64; ++kt) {
    __syncthreads();
    *reinterpret_cast<float4*>(&Pt[sr][sc]) = a0;
    *reinterpret_cast<float4*>(&Pt[sr][sc + 4]) = a1;
    *reinterpret_cast<float4*>(&Cd[cr][cc]) = c0;
    *reinterpret_cast<float4*>(&Cd[cr][cc + 4]) = c1;
    __syncthreads();
    if (kt < 63) {
      const int p0k = (kt + 1) * 16;
      const float* ps = P + ((size_t)b * LL + sr) * TENC + p0k + sc;
      a0 = *reinterpret_cast<const float4*>(ps);
      a1 = *reinterpret_cast<const float4*>(ps + 4);
      const float* cs = ctxt + ((size_t)b * TENC + p0k + cr) * HD + d0 + cc;
      c0 = *reinterpret_cast<const float4*>(cs);
      c1 = *reinterpret_cast<const float4*>(cs + 4);
    }
#pragma unroll
    for (int kk2 = 0; kk2 < 8; ++kk2) {
      float2 av[8];
#pragma unroll
      for (int i = 0; i < 8; ++i)
        av[i] = *reinterpret_cast<const float2*>(&Pt[ty*8 + i][kk2*2]);
      float4 b00 = *reinterpret_cast<const float4*>(&Cd[kk2*2][tx*8]);
      float4 b01 = *reinterpret_cast<const float4*>(&Cd[kk2*2][tx*8 + 4]);
      float4 b10 = *reinterpret_cast<const float4*>(&Cd[kk2*2+1][tx*8]);
      float4 b11 = *reinterpret_cast<const float4*>(&Cd[kk2*2+1][tx*8 + 4]);
#pragma unroll
      for (int i = 0; i < 8; ++i) {
        acc[i][0] += av[i].x*b00.x + av[i].y*b10.x;
        acc[i][1] += av[i].x*b00.y + av[i].y*b10.y;
        acc[i][2] += av[i].x*b00.z + av[i].y*b10.z;
        acc[i][3] += av[i].x*b00.w + av[i].y*b10.w;
        acc[i][4] += av[i].x*b01.x + av[i].y*b11.x;
        acc[i][5] += av[i].x*b01.y + av[i].y*b11.y;
        acc[i][6] += av[i].x*b01.z + av[i].y*b11.z;
        acc[i][7] += av[i].x*b01.w + av[i].y*b11.w;
      }
    }
  }
#pragma unroll
  for (int i = 0; i < 8; ++i) {
    float* cp = CTX + ((size_t)b * LL + ty*8 + i) * HD + d0 + tx*8;
    *reinterpret_cast<float4*>(cp)     = make_float4(acc[i][0], acc[i][1], acc[i][2], acc[i][3]);
    *reinterpret_cast<float4*>(cp + 4) = make_float4(acc[i][4], acc[i][5], acc[i][6], acc[i][7]);
  }
}

// ---------------- Phase B4: logits + log-softmax ----------------
__global__ __launch_bounds__(256) void b4_logits(
    const float* __restrict__ Wout, const float* __restrict__ bout,
    const float* __restrict__ ws, float* __restrict__ out) {
  const int b = blockIdx.x & 31, tq = blockIdx.x >> 5;   // tq in [0,4)
  const int t0 = tq * 32;
  const int tid = threadIdx.x, tx = tid & 15, ty = tid >> 4;
  const float* hbuf = ws + HBUF_OFF;
  const float* CTX = ws + CTX_OFF;
  __shared__ float Ft[32][18];
  __shared__ float WtT[16][132];
  __shared__ float lg[32][130];
  float acc[2][8];
#pragma unroll
  for (int i = 0; i < 2; ++i)
#pragma unroll
    for (int jj = 0; jj < 8; ++jj) acc[i][jj] = 0.f;

  const int fr = tid >> 2, fc = (tid & 3) * 4;   // Ft loader (tid<128)
  const int we = tid >> 1, wc = (tid & 1) * 8;   // WtT loader
  for (int kt = 0; kt < 128; ++kt) {
    const int k0 = kt * 16;
    float4 fv = make_float4(0,0,0,0);
    if (tid < 128) {
      const int kk = k0 + fc;
      const float* src = (kk < 1024)
        ? hbuf + (size_t)(t0 + fr + 1) * HSTEP + (size_t)b * HD + kk
        : CTX + ((size_t)b * LL + t0 + fr) * HD + (kk - 1024);
      fv = *reinterpret_cast<const float4*>(src);
    }
    const float* wsrc = Wout + (size_t)we * (2*HD) + k0 + wc;
    float4 w0 = *reinterpret_cast<const float4*>(wsrc);
    float4 w1 = *reinterpret_cast<const float4*>(wsrc + 4);
    __syncthreads();
    if (tid < 128) *reinterpret_cast<float4*>(&Ft[fr][fc]) = fv;
    WtT[wc+0][we] = w0.x; WtT[wc+1][we] = w0.y; WtT[wc+2][we] = w0.z; WtT[wc+3][we] = w0.w;
    WtT[wc+4][we] = w1.x; WtT[wc+5][we] = w1.y; WtT[wc+6][we] = w1.z; WtT[wc+7][we] = w1.w;
    __syncthreads();
#pragma unroll
    for (int kk2 = 0; kk2 < 8; ++kk2) {
      float2 av[2];
      av[0] = *reinterpret_cast<const float2*>(&Ft[ty*2][kk2*2]);
      av[1] = *reinterpret_cast<const float2*>(&Ft[ty*2 + 1][kk2*2]);
      float4 b00 = *reinterpret_cast<const float4*>(&WtT[kk2*2][tx*8]);
      float4 b01 = *reinterpret_cast<const float4*>(&WtT[kk2*2][tx*8 + 4]);
      float4 b10 = *reinterpret_cast<const float4*>(&WtT[kk2*2+1][tx*8]);
      float4 b11 = *reinterpret_cast<const float4*>(&WtT[kk2*2+1][tx*8 + 4]);
#pragma unroll
      for (int i = 0; i < 2; ++i) {
        acc[i][0] += av[i].x*b00.x + av[i].y*b10.x;
        acc[i][1] += av[i].x*b00.y + av[i].y*b10.y;
        acc[i][2] += av[i].x*b00.z + av[i].y*b10.z;
        acc[i][3] += av[i].x*b00.w + av[i].y*b10.w;
        acc[i][4] += av[i].x*b01.x + av[i].y*b11.x;
        acc[i][5] += av[i].x*b01.y + av[i].y*b11.y;
        acc[i][6] += av[i].x*b01.z + av[i].y*b11.z;
        acc[i][7] += av[i].x*b01.w + av[i].y*b11.w;
      }
    }
  }
#pragma unroll
  for (int i = 0; i < 2; ++i)
#pragma unroll
    for (int jj = 0; jj < 8; ++jj)
      lg[ty*2 + i][tx*8 + jj] = acc[i][jj] + bout[tx*8 + jj];
  __syncthreads();
  const int w = tid >> 6, lane = tid & 63;
#pragma unroll
  for (int rr = 0; rr < 8; ++rr) {
    const int row = w * 8 + rr;
    float v0 = lg[row][lane], v1 = lg[row][lane + 64];
    float mx = fmaxf(v0, v1);
#pragma unroll
    for (int o = 32; o > 0; o >>= 1) mx = fmaxf(mx, __shfl_xor(mx, o));
    float sm = __expf(v0 - mx) + __expf(v1 - mx);
#pragma unroll
    for (int o = 32; o > 0; o >>= 1) sm += __shfl_xor(sm, o);
    float lse = mx + __logf(sm);
    float* op = out + ((size_t)b * LL + t0 + row) * ED;
    op[lane]      = v0 - lse;
    op[lane + 64] = v1 - lse;
  }
}

extern "C" void kernel_launch(void* const* d_in, const int* in_sizes, int n_in,
                              void* d_out, int out_size, void* d_ws, size_t ws_size,
                              hipStream_t stream) {
  (void)in_sizes; (void)n_in; (void)out_size; (void)ws_size;
  const float* ctxt = (const float*)d_in[0];
  const float* gt   = (const float*)d_in[1];
  const float* Wih  = (const float*)d_in[2];
  const float* Whh  = (const float*)d_in[3];
  const float* bih  = (const float*)d_in[4];
  const float* bhh  = (const float*)d_in[5];
  const float* Wout = (const float*)d_in[6];
  const float* bout = (const float*)d_in[7];
  float* out = (float*)d_out;
  float* ws  = (float*)d_ws;

  hipMemsetAsync(ws + HBUF_OFF, 0, (size_t)HSTEP * sizeof(float), stream); // h_{-1}=0
  hipMemsetAsync(ws + CNT_OFF, 0, 256, stream);                            // barrier

  base_kernel<<<(BATCH * GD) / 256, 256, 0, stream>>>(ctxt, Wih, bih, bhh, ws);

  void* argsA[] = { (void*)&gt, (void*)&Wih, (void*)&Whh, (void*)&ws };
  hipLaunchCooperativeKernel((const void*)&phaseA, dim3(256), dim3(1024),
                             argsA, 0, stream);

  b1_energy<<<256, 256, 0, stream>>>(ctxt, ws);
  b2_softmax<<<32, 1024, 0, stream>>>(ws);
  b3_ctx<<<256, 256, 0, stream>>>(ctxt, ws);
  b4_logits<<<128, 256, 0, stream>>>(Wout, bout, ws, out);
}

// Round 6
// 4717.152 us; speedup vs baseline: 5.2104x; 5.2104x over previous
//
#include <hip/hip_runtime.h>

#define BATCH 32
#define TENC  1024
#define HD    1024
#define ED    128
#define LL    128
#define GD    4096
#define IND   1152
#define HSTEP (BATCH*HD)

// ws float offsets
#define HBUF_OFF 131072                       // base: [0, 131072)
#define CNT_OFF  (HBUF_OFF + 129*HSTEP)       // h ring [129][32][1024]
#define E_OFF    (CNT_OFF + 64)
#define P_OFF    (E_OFF + BATCH*LL*TENC)
#define CTX_OFF  (P_OFF + BATCH*LL*TENC)
// wordg: bf16[128][4096][32] = 33.5 MB occupies [E_OFF, CTX_OFF) until B1 runs

__device__ __forceinline__ float sigf(float x) {
  return __builtin_amdgcn_rcpf(1.0f + __expf(-x));
}
__device__ __forceinline__ float tanhf_fast(float x) {
  return 1.0f - 2.0f * __builtin_amdgcn_rcpf(1.0f + __expf(2.0f * x));
}
__device__ __forceinline__ unsigned bfrne(float f) {       // f32 -> bf16 RNE
  unsigned v = __float_as_uint(f);
  return (v + 0x7fffu + ((v >> 16) & 1u)) >> 16;
}
__device__ __forceinline__ float bf2f(unsigned short u) {
  return __uint_as_float(((unsigned)u) << 16);
}
__device__ __forceinline__ void cstf(float* p, float v) {   // write-through, device-coherent
  __hip_atomic_store(p, v, __ATOMIC_RELAXED, __HIP_MEMORY_SCOPE_AGENT);
}
// grid barrier, no cache-flushing fences (R4/R5-proven)
__device__ __forceinline__ void gbar(unsigned* cnt, unsigned target) {
  __syncthreads();
  if (threadIdx.x == 0) {
    __hip_atomic_fetch_add(cnt, 1u, __ATOMIC_RELAXED, __HIP_MEMORY_SCOPE_AGENT);
    while (__hip_atomic_load(cnt, __ATOMIC_RELAXED, __HIP_MEMORY_SCOPE_AGENT) < target)
      __builtin_amdgcn_s_sleep(2);
  }
  __syncthreads();
}
__device__ __forceinline__ float sel4(float a0, float a1, float a2, float a3, int i) {
  float r = a0;
  r = (i == 1) ? a1 : r;
  r = (i == 2) ? a2 : r;
  r = (i == 3) ? a3 : r;
  return r;
}

// base[b][g] = b_ih[g]+b_hh[g]+dot(ctx0[b], W_ih[g][E:])
__global__ __launch_bounds__(256) void base_kernel(
    const float* __restrict__ ctxt, const float* __restrict__ Wih,
    const float* __restrict__ bih, const float* __restrict__ bhh,
    float* __restrict__ base) {
  int id = blockIdx.x * 256 + threadIdx.x;
  int b = id & (BATCH - 1);
  int g = id >> 5;
  const float4* c4 = reinterpret_cast<const float4*>(ctxt + (size_t)b * TENC * HD);
  const float4* w4 = reinterpret_cast<const float4*>(Wih + (size_t)g * IND + ED);
  float a = 0.f;
#pragma unroll 8
  for (int kk = 0; kk < HD/4; ++kk) {
    float4 c = c4[kk], w = w4[kk];
    a += c.x*w.x + c.y*w.y + c.z*w.z + c.w*w.w;
  }
  base[(size_t)b * GD + g] = a + bih[g] + bhh[g];
}

// ---------------- Phase 0: wordg[t][row][b] = word_t[b] . Wih[row][0:128] (bf16) ----------------
__global__ __launch_bounds__(256) void phase0_wordg(
    const float* __restrict__ gt, const float* __restrict__ Wih,
    float* __restrict__ ws) {
  const int mt = blockIdx.x & 31, nt = blockIdx.x >> 5;
  const int r0 = mt * 128, n0 = nt * 128;
  const int tid = threadIdx.x, tx = tid & 15, ty = tid >> 4;
  unsigned short* wg = reinterpret_cast<unsigned short*>(ws + E_OFF);
  __shared__ float At[128][18];
  __shared__ float BtT[16][132];
  float acc[8][8];
#pragma unroll
  for (int i = 0; i < 8; ++i)
#pragma unroll
    for (int j = 0; j < 8; ++j) acc[i][j] = 0.f;

  const int sr = tid >> 1, sc = (tid & 1) * 8;
  for (int kt = 0; kt < 8; ++kt) {
    const int k0 = kt * 16;
    const float* ap = Wih + (size_t)(r0 + sr) * IND + k0 + sc;
    float4 a0 = *reinterpret_cast<const float4*>(ap);
    float4 a1 = *reinterpret_cast<const float4*>(ap + 4);
    const int n = n0 + sr, t = n >> 5, bb = n & 31;
    float4 b0, b1;
    if (t == 0) {
      b0 = make_float4((k0 + sc == 0) ? 1.f : 0.f, 0.f, 0.f, 0.f);
      b1 = make_float4(0.f, 0.f, 0.f, 0.f);
    } else {
      const float* bp = gt + ((size_t)bb * LL + (t - 1)) * ED + k0 + sc;
      b0 = *reinterpret_cast<const float4*>(bp);
      b1 = *reinterpret_cast<const float4*>(bp + 4);
    }
    __syncthreads();
    *reinterpret_cast<float4*>(&At[sr][sc]) = a0;
    *reinterpret_cast<float4*>(&At[sr][sc + 4]) = a1;
    BtT[sc+0][sr] = b0.x; BtT[sc+1][sr] = b0.y; BtT[sc+2][sr] = b0.z; BtT[sc+3][sr] = b0.w;
    BtT[sc+4][sr] = b1.x; BtT[sc+5][sr] = b1.y; BtT[sc+6][sr] = b1.z; BtT[sc+7][sr] = b1.w;
    __syncthreads();
#pragma unroll
    for (int kk2 = 0; kk2 < 8; ++kk2) {
      float2 av[8];
#pragma unroll
      for (int i = 0; i < 8; ++i)
        av[i] = *reinterpret_cast<const float2*>(&At[ty*8 + i][kk2*2]);
      float4 c00 = *reinterpret_cast<const float4*>(&BtT[kk2*2][tx*8]);
      float4 c01 = *reinterpret_cast<const float4*>(&BtT[kk2*2][tx*8 + 4]);
      float4 c10 = *reinterpret_cast<const float4*>(&BtT[kk2*2+1][tx*8]);
      float4 c11 = *reinterpret_cast<const float4*>(&BtT[kk2*2+1][tx*8 + 4]);
#pragma unroll
      for (int i = 0; i < 8; ++i) {
        acc[i][0] += av[i].x*c00.x + av[i].y*c10.x;
        acc[i][1] += av[i].x*c00.y + av[i].y*c10.y;
        acc[i][2] += av[i].x*c00.z + av[i].y*c10.z;
        acc[i][3] += av[i].x*c00.w + av[i].y*c10.w;
        acc[i][4] += av[i].x*c01.x + av[i].y*c11.x;
        acc[i][5] += av[i].x*c01.y + av[i].y*c11.y;
        acc[i][6] += av[i].x*c01.z + av[i].y*c11.z;
        acc[i][7] += av[i].x*c01.w + av[i].y*c11.w;
      }
    }
  }
  const int nb = n0 + tx * 8, t = nb >> 5, b0i = nb & 31;
#pragma unroll
  for (int i = 0; i < 8; ++i) {
    const int row = r0 + ty * 8 + i;
    uint4 pk;
    pk.x = bfrne(acc[i][0]) | (bfrne(acc[i][1]) << 16);
    pk.y = bfrne(acc[i][2]) | (bfrne(acc[i][3]) << 16);
    pk.z = bfrne(acc[i][4]) | (bfrne(acc[i][5]) << 16);
    pk.w = bfrne(acc[i][6]) | (bfrne(acc[i][7]) << 16);
    *reinterpret_cast<uint4*>(wg + ((size_t)t * GD + row) * 32 + b0i) = pk;
  }
}

// ---------------- Phase A: recurrence, Whh register-resident, h via LDS ----------------
// 256 blocks x 1024 thr. Block rg owns j = rg*4..rg*4+3 (x 4 gates = 16 rows).
// Wave w: rq=w&3 -> j, bq=w>>2 -> batches bq*8..+7. Lane covers cols [16L,16L+15].
__global__ __launch_bounds__(1024, 4) void phaseA(
    const float* __restrict__ Whh, float* __restrict__ ws) {
  const int rg = blockIdx.x;
  const int tid = threadIdx.x;
  const int lane = tid & 63;
  const int w = tid >> 6;
  const int rq = w & 3, bq = w >> 2;
  const int j = rg * 4 + rq;
  const int lb = lane & 3;
  float* base = ws;
  float* hbuf = ws + HBUF_OFF;
  unsigned* cnt = reinterpret_cast<unsigned*>(ws + CNT_OFF);
  const unsigned short* wg = reinterpret_cast<const unsigned short*>(ws + E_OFF);

  extern __shared__ float h_lds[];   // 32768 floats (128 KB), 16B-unit XOR-swizzled

  // Whh register-resident: 4 gate-rows of j, 16 cols/lane
  float4 Wr[4][4];
  const float4* Whh4 = reinterpret_cast<const float4*>(Whh);
#pragma unroll
  for (int g = 0; g < 4; ++g)
#pragma unroll
    for (int t = 0; t < 4; ++t)
      Wr[g][t] = Whh4[((size_t)(g * HD + j)) * 256 + 4 * lane + t];

  // base per (gate, half) for this lane's b
  float bs[4][2];
#pragma unroll
  for (int g = 0; g < 4; ++g)
#pragma unroll
    for (int hf = 0; hf < 2; ++hf)
      bs[g][hf] = base[(size_t)(bq * 8 + hf * 4 + lb) * GD + g * HD + j];

  float c0 = 0.f, c1 = 0.f;

  for (int k = 0; k < LL; ++k) {
    // stage h[k] -> LDS (swizzled)
    {
      const float4* src = reinterpret_cast<const float4*>(hbuf + (size_t)k * HSTEP);
#pragma unroll
      for (int i = 0; i < 8; ++i) {
        const int u = tid + 1024 * i;
        float4 v = src[u];
        const int o16 = u & 255, b = u >> 8;
        const int sw = o16 ^ ((o16 >> 3) & 7);
        *reinterpret_cast<float4*>(h_lds + 4 * (b * 256 + sw)) = v;
      }
    }
    __syncthreads();

#pragma unroll
    for (int hf = 0; hf < 2; ++hf) {
      const int bmine = bq * 8 + hf * 4 + lb;
      // word-part prefetch (independent of compute below)
      float wgv[4];
#pragma unroll
      for (int g = 0; g < 4; ++g)
        wgv[g] = bf2f(wg[((size_t)k * GD + g * HD + j) * 32 + bmine]);

      float acc[4][4];
#pragma unroll
      for (int g = 0; g < 4; ++g)
#pragma unroll
        for (int bi = 0; bi < 4; ++bi) acc[g][bi] = 0.f;

#pragma unroll
      for (int bi = 0; bi < 4; ++bi) {
        const int b = bq * 8 + hf * 4 + bi;
        float4 h4[4];
#pragma unroll
        for (int t = 0; t < 4; ++t) {
          const int o16 = 4 * lane + t;
          const int sw = o16 ^ ((o16 >> 3) & 7);
          h4[t] = *reinterpret_cast<const float4*>(h_lds + 4 * (b * 256 + sw));
        }
#pragma unroll
        for (int g = 0; g < 4; ++g) {
          float s = 0.f;
#pragma unroll
          for (int t = 0; t < 4; ++t) {
            float4 hv = h4[t], wv = Wr[g][t];
            s += hv.x*wv.x + hv.y*wv.y + hv.z*wv.z + hv.w*wv.w;
          }
          acc[g][bi] += s;
        }
      }
      // butterfly allreduce over 64 lanes (16 values)
#pragma unroll
      for (int o = 1; o < 64; o <<= 1)
#pragma unroll
        for (int g = 0; g < 4; ++g)
#pragma unroll
          for (int bi = 0; bi < 4; ++bi)
            acc[g][bi] += __shfl_xor(acc[g][bi], o);

      float s0 = sel4(acc[0][0], acc[0][1], acc[0][2], acc[0][3], lb) + wgv[0] + bs[0][hf];
      float s1 = sel4(acc[1][0], acc[1][1], acc[1][2], acc[1][3], lb) + wgv[1] + bs[1][hf];
      float s2 = sel4(acc[2][0], acc[2][1], acc[2][2], acc[2][3], lb) + wgv[2] + bs[2][hf];
      float s3 = sel4(acc[3][0], acc[3][1], acc[3][2], acc[3][3], lb) + wgv[3] + bs[3][hf];
      float ig = sigf(s0);
      float fg = sigf(s1);
      float gg = tanhf_fast(s2);
      float og = sigf(s3);
      float cr = (hf == 0) ? c0 : c1;
      cr = fg * cr + ig * gg;
      if (hf == 0) c0 = cr; else c1 = cr;
      if (lane < 4)
        cstf(hbuf + (size_t)(k + 1) * HSTEP + (size_t)bmine * HD + j,
             og * tanhf_fast(cr));
    }
    gbar(cnt, (unsigned)((k + 1) * 256));
  }
}

// ---------------- Phase B1: E[b][t][p] = sum_d H[t][d] C[p][d] ----------------
__global__ __launch_bounds__(256) void b1_energy(
    const float* __restrict__ ctxt, float* __restrict__ ws) {
  const int b = blockIdx.x & 31, pt = blockIdx.x >> 5;
  const int p0 = pt * 128;
  const int tid = threadIdx.x, tx = tid & 15, ty = tid >> 4;
  const float* hbuf = ws + HBUF_OFF;
  float* E = ws + E_OFF;
  __shared__ float Ht[128][18];
  __shared__ float CtT[16][132];
  float acc[8][8];
#pragma unroll
  for (int i = 0; i < 8; ++i)
#pragma unroll
    for (int jj = 0; jj < 8; ++jj) acc[i][jj] = 0.f;

  const int sr = tid >> 1, sc = (tid & 1) * 8;
  float4 a0, a1, c0, c1;
  {
    const float* hs = hbuf + (size_t)(sr + 1) * HSTEP + (size_t)b * HD + sc;
    a0 = *reinterpret_cast<const float4*>(hs);
    a1 = *reinterpret_cast<const float4*>(hs + 4);
    const float* cs = ctxt + ((size_t)b * TENC + p0 + sr) * HD + sc;
    c0 = *reinterpret_cast<const float4*>(cs);
    c1 = *reinterpret_cast<const float4*>(cs + 4);
  }
  for (int kt = 0; kt < 64; ++kt) {
    __syncthreads();
    *reinterpret_cast<float4*>(&Ht[sr][sc]) = a0;
    *reinterpret_cast<float4*>(&Ht[sr][sc + 4]) = a1;
    CtT[sc+0][sr] = c0.x; CtT[sc+1][sr] = c0.y; CtT[sc+2][sr] = c0.z; CtT[sc+3][sr] = c0.w;
    CtT[sc+4][sr] = c1.x; CtT[sc+5][sr] = c1.y; CtT[sc+6][sr] = c1.z; CtT[sc+7][sr] = c1.w;
    __syncthreads();
    if (kt < 63) {
      const int d0 = (kt + 1) * 16;
      const float* hs = hbuf + (size_t)(sr + 1) * HSTEP + (size_t)b * HD + d0 + sc;
      a0 = *reinterpret_cast<const float4*>(hs);
      a1 = *reinterpret_cast<const float4*>(hs + 4);
      const float* cs = ctxt + ((size_t)b * TENC + p0 + sr) * HD + d0 + sc;
      c0 = *reinterpret_cast<const float4*>(cs);
      c1 = *reinterpret_cast<const float4*>(cs + 4);
    }
#pragma unroll
    for (int kk2 = 0; kk2 < 8; ++kk2) {
      float2 av[8];
#pragma unroll
      for (int i = 0; i < 8; ++i)
        av[i] = *reinterpret_cast<const float2*>(&Ht[ty*8 + i][kk2*2]);
      float4 b00 = *reinterpret_cast<const float4*>(&CtT[kk2*2][tx*8]);
      float4 b01 = *reinterpret_cast<const float4*>(&CtT[kk2*2][tx*8 + 4]);
      float4 b10 = *reinterpret_cast<const float4*>(&CtT[kk2*2+1][tx*8]);
      float4 b11 = *reinterpret_cast<const float4*>(&CtT[kk2*2+1][tx*8 + 4]);
#pragma unroll
      for (int i = 0; i < 8; ++i) {
        acc[i][0] += av[i].x*b00.x + av[i].y*b10.x;
        acc[i][1] += av[i].x*b00.y + av[i].y*b10.y;
        acc[i][2] += av[i].x*b00.z + av[i].y*b10.z;
        acc[i][3] += av[i].x*b00.w + av[i].y*b10.w;
        acc[i][4] += av[i].x*b01.x + av[i].y*b11.x;
        acc[i][5] += av[i].x*b01.y + av[i].y*b11.y;
        acc[i][6] += av[i].x*b01.z + av[i].y*b11.z;
        acc[i][7] += av[i].x*b01.w + av[i].y*b11.w;
      }
    }
  }
#pragma unroll
  for (int i = 0; i < 8; ++i) {
    float* ep = E + ((size_t)b * LL + ty*8 + i) * TENC + p0 + tx*8;
    *reinterpret_cast<float4*>(ep)     = make_float4(acc[i][0], acc[i][1], acc[i][2], acc[i][3]);
    *reinterpret_cast<float4*>(ep + 4) = make_float4(acc[i][4], acc[i][5], acc[i][6], acc[i][7]);
  }
}

// ---------------- Phase B2: row softmax E -> P ----------------
__global__ __launch_bounds__(1024) void b2_softmax(float* __restrict__ ws) {
  const int b = blockIdx.x;
  const int w = threadIdx.x >> 6, lane = threadIdx.x & 63;
  const float* E = ws + E_OFF;
  float* P = ws + P_OFF;
#pragma unroll
  for (int rr = 0; rr < 8; ++rr) {
    const int t = w * 8 + rr;
    const float4* e4 = reinterpret_cast<const float4*>(E + ((size_t)b * LL + t) * TENC);
    float4 v[4];
#pragma unroll
    for (int c = 0; c < 4; ++c) v[c] = e4[c * 64 + lane];
    float m = fmaxf(fmaxf(fmaxf(v[0].x, v[0].y), fmaxf(v[0].z, v[0].w)),
                    fmaxf(fmaxf(v[1].x, v[1].y), fmaxf(v[1].z, v[1].w)));
    m = fmaxf(m, fmaxf(fmaxf(fmaxf(v[2].x, v[2].y), fmaxf(v[2].z, v[2].w)),
                       fmaxf(fmaxf(v[3].x, v[3].y), fmaxf(v[3].z, v[3].w))));
#pragma unroll
    for (int o = 32; o > 0; o >>= 1) m = fmaxf(m, __shfl_xor(m, o));
    float s = 0.f;
#pragma unroll
    for (int c = 0; c < 4; ++c) {
      v[c].x = __expf(v[c].x - m); v[c].y = __expf(v[c].y - m);
      v[c].z = __expf(v[c].z - m); v[c].w = __expf(v[c].w - m);
      s += v[c].x + v[c].y + v[c].z + v[c].w;
    }
#pragma unroll
    for (int o = 32; o > 0; o >>= 1) s += __shfl_xor(s, o);
    float inv = __builtin_amdgcn_rcpf(s);
    float4* p4 = reinterpret_cast<float4*>(P + ((size_t)b * LL + t) * TENC);
#pragma unroll
    for (int c = 0; c < 4; ++c) {
      float4 o4 = make_float4(v[c].x*inv, v[c].y*inv, v[c].z*inv, v[c].w*inv);
      p4[c * 64 + lane] = o4;
    }
  }
}

// ---------------- Phase B3: CTX[b][t][d] = sum_p P[t][p] C[p][d] ----------------
__global__ __launch_bounds__(256) void b3_ctx(
    const float* __restrict__ ctxt, float* __restrict__ ws) {
  const int b = blockIdx.x & 31, dt = blockIdx.x >> 5;
  const int d0 = dt * 128;
  const int tid = threadIdx.x, tx = tid & 15, ty = tid >> 4;
  const float* P = ws + P_OFF;
  float* CTX = ws + CTX_OFF;
  __shared__ float Pt[128][18];
  __shared__ float Cd[16][132];
  float acc[8][8];
#pragma unroll
  for (int i = 0; i < 8; ++i)
#pragma unroll
    for (int jj = 0; jj < 8; ++jj) acc[i][jj] = 0.f;

  const int sr = tid >> 1, sc = (tid & 1) * 8;
  const int cr = tid >> 4, cc = (tid & 15) * 8;
  float4 a0, a1, c0, c1;
  {
    const float* ps = P + ((size_t)b * LL + sr) * TENC + sc;
    a0 = *reinterpret_cast<const float4*>(ps);
    a1 = *reinterpret_cast<const float4*>(ps + 4);
    const float* cs = ctxt + ((size_t)b * TENC + cr) * HD + d0 + cc;
    c0 = *reinterpret_cast<const float4*>(cs);
    c1 = *reinterpret_cast<const float4*>(cs + 4);
  }
  for (int kt = 0; kt < 64; ++kt) {
    __syncthreads();
    *reinterpret_cast<float4*>(&Pt[sr][sc]) = a0;
    *reinterpret_cast<float4*>(&Pt[sr][sc + 4]) = a1;
    *reinterpret_cast<float4*>(&Cd[cr][cc]) = c0;
    *reinterpret_cast<float4*>(&Cd[cr][cc + 4]) = c1;
    __syncthreads();
    if (kt < 63) {
      const int p0k = (kt + 1) * 16;
      const float* ps = P + ((size_t)b * LL + sr) * TENC + p0k + sc;
      a0 = *reinterpret_cast<const float4*>(ps);
      a1 = *reinterpret_cast<const float4*>(ps + 4);
      const float* cs = ctxt + ((size_t)b * TENC + p0k + cr) * HD + d0 + cc;
      c0 = *reinterpret_cast<const float4*>(cs);
      c1 = *reinterpret_cast<const float4*>(cs + 4);
    }
#pragma unroll
    for (int kk2 = 0; kk2 < 8; ++kk2) {
      float2 av[8];
#pragma unroll
      for (int i = 0; i < 8; ++i)
        av[i] = *reinterpret_cast<const float2*>(&Pt[ty*8 + i][kk2*2]);
      float4 b00 = *reinterpret_cast<const float4*>(&Cd[kk2*2][tx*8]);
      float4 b01 = *reinterpret_cast<const float4*>(&Cd[kk2*2][tx*8 + 4]);
      float4 b10 = *reinterpret_cast<const float4*>(&Cd[kk2*2+1][tx*8]);
      float4 b11 = *reinterpret_cast<const float4*>(&Cd[kk2*2+1][tx*8 + 4]);
#pragma unroll
      for (int i = 0; i < 8; ++i) {
        acc[i][0] += av[i].x*b00.x + av[i].y*b10.x;
        acc[i][1] += av[i].x*b00.y + av[i].y*b10.y;
        acc[i][2] += av[i].x*b00.z + av[i].y*b10.z;
        acc[i][3] += av[i].x*b00.w + av[i].y*b10.w;
        acc[i][4] += av[i].x*b01.x + av[i].y*b11.x;
        acc[i][5] += av[i].x*b01.y + av[i].y*b11.y;
        acc[i][6] += av[i].x*b01.z + av[i].y*b11.z;
        acc[i][7] += av[i].x*b01.w + av[i].y*b11.w;
      }
    }
  }
#pragma unroll
  for (int i = 0; i < 8; ++i) {
    float* cp = CTX + ((size_t)b * LL + ty*8 + i) * HD + d0 + tx*8;
    *reinterpret_cast<float4*>(cp)     = make_float4(acc[i][0], acc[i][1], acc[i][2], acc[i][3]);
    *reinterpret_cast<float4*>(cp + 4) = make_float4(acc[i][4], acc[i][5], acc[i][6], acc[i][7]);
  }
}

// ---------------- Phase B4: logits + log-softmax ----------------
__global__ __launch_bounds__(256) void b4_logits(
    const float* __restrict__ Wout, const float* __restrict__ bout,
    const float* __restrict__ ws, float* __restrict__ out) {
  const int b = blockIdx.x & 31, tq = blockIdx.x >> 5;
  const int t0 = tq * 32;
  const int tid = threadIdx.x, tx = tid & 15, ty = tid >> 4;
  const float* hbuf = ws + HBUF_OFF;
  const float* CTX = ws + CTX_OFF;
  __shared__ float Ft[32][18];
  __shared__ float WtT[16][132];
  __shared__ float lg[32][130];
  float acc[2][8];
#pragma unroll
  for (int i = 0; i < 2; ++i)
#pragma unroll
    for (int jj = 0; jj < 8; ++jj) acc[i][jj] = 0.f;

  const int fr = tid >> 2, fc = (tid & 3) * 4;
  const int we = tid >> 1, wc = (tid & 1) * 8;
  for (int kt = 0; kt < 128; ++kt) {
    const int k0 = kt * 16;
    float4 fv = make_float4(0,0,0,0);
    if (tid < 128) {
      const int kk = k0 + fc;
      const float* src = (kk < 1024)
        ? hbuf + (size_t)(t0 + fr + 1) * HSTEP + (size_t)b * HD + kk
        : CTX + ((size_t)b * LL + t0 + fr) * HD + (kk - 1024);
      fv = *reinterpret_cast<const float4*>(src);
    }
    const float* wsrc = Wout + (size_t)we * (2*HD) + k0 + wc;
    float4 w0 = *reinterpret_cast<const float4*>(wsrc);
    float4 w1 = *reinterpret_cast<const float4*>(wsrc + 4);
    __syncthreads();
    if (tid < 128) *reinterpret_cast<float4*>(&Ft[fr][fc]) = fv;
    WtT[wc+0][we] = w0.x; WtT[wc+1][we] = w0.y; WtT[wc+2][we] = w0.z; WtT[wc+3][we] = w0.w;
    WtT[wc+4][we] = w1.x; WtT[wc+5][we] = w1.y; WtT[wc+6][we] = w1.z; WtT[wc+7][we] = w1.w;
    __syncthreads();
#pragma unroll
    for (int kk2 = 0; kk2 < 8; ++kk2) {
      float2 av[2];
      av[0] = *reinterpret_cast<const float2*>(&Ft[ty*2][kk2*2]);
      av[1] = *reinterpret_cast<const float2*>(&Ft[ty*2 + 1][kk2*2]);
      float4 b00 = *reinterpret_cast<const float4*>(&WtT[kk2*2][tx*8]);
      float4 b01 = *reinterpret_cast<const float4*>(&WtT[kk2*2][tx*8 + 4]);
      float4 b10 = *reinterpret_cast<const float4*>(&WtT[kk2*2+1][tx*8]);
      float4 b11 = *reinterpret_cast<const float4*>(&WtT[kk2*2+1][tx*8 + 4]);
#pragma unroll
      for (int i = 0; i < 2; ++i) {
        acc[i][0] += av[i].x*b00.x + av[i].y*b10.x;
        acc[i][1] += av[i].x*b00.y + av[i].y*b10.y;
        acc[i][2] += av[i].x*b00.z + av[i].y*b10.z;
        acc[i][3] += av[i].x*b00.w + av[i].y*b10.w;
        acc[i][4] += av[i].x*b01.x + av[i].y*b11.x;
        acc[i][5] += av[i].x*b01.y + av[i].y*b11.y;
        acc[i][6] += av[i].x*b01.z + av[i].y*b11.z;
        acc[i][7] += av[i].x*b01.w + av[i].y*b11.w;
      }
    }
  }
#pragma unroll
  for (int i = 0; i < 2; ++i)
#pragma unroll
    for (int jj = 0; jj < 8; ++jj)
      lg[ty*2 + i][tx*8 + jj] = acc[i][jj] + bout[tx*8 + jj];
  __syncthreads();
  const int w = tid >> 6, lane = tid & 63;
#pragma unroll
  for (int rr = 0; rr < 8; ++rr) {
    const int row = w * 8 + rr;
    float v0 = lg[row][lane], v1 = lg[row][lane + 64];
    float mx = fmaxf(v0, v1);
#pragma unroll
    for (int o = 32; o > 0; o >>= 1) mx = fmaxf(mx, __shfl_xor(mx, o));
    float sm = __expf(v0 - mx) + __expf(v1 - mx);
#pragma unroll
    for (int o = 32; o > 0; o >>= 1) sm += __shfl_xor(sm, o);
    float lse = mx + __logf(sm);
    float* op = out + ((size_t)b * LL + t0 + row) * ED;
    op[lane]      = v0 - lse;
    op[lane + 64] = v1 - lse;
  }
}

extern "C" void kernel_launch(void* const* d_in, const int* in_sizes, int n_in,
                              void* d_out, int out_size, void* d_ws, size_t ws_size,
                              hipStream_t stream) {
  (void)in_sizes; (void)n_in; (void)out_size; (void)ws_size;
  const float* ctxt = (const float*)d_in[0];
  const float* gt   = (const float*)d_in[1];
  const float* Wih  = (const float*)d_in[2];
  const float* Whh  = (const float*)d_in[3];
  const float* bih  = (const float*)d_in[4];
  const float* bhh  = (const float*)d_in[5];
  const float* Wout = (const float*)d_in[6];
  const float* bout = (const float*)d_in[7];
  float* out = (float*)d_out;
  float* ws  = (float*)d_ws;

  hipMemsetAsync(ws + HBUF_OFF, 0, (size_t)HSTEP * sizeof(float), stream); // h_0 = 0
  hipMemsetAsync(ws + CNT_OFF, 0, 256, stream);                            // barrier

  base_kernel<<<(BATCH * GD) / 256, 256, 0, stream>>>(ctxt, Wih, bih, bhh, ws);
  phase0_wordg<<<1024, 256, 0, stream>>>(gt, Wih, ws);

  static int smem_set = 0;
  if (!smem_set) {
    hipFuncSetAttribute((const void*)&phaseA,
                        hipFuncAttributeMaxDynamicSharedMemorySize, 131072);
    smem_set = 1;
  }
  void* argsA[] = { (void*)&Whh, (void*)&ws };
  hipLaunchCooperativeKernel((const void*)&phaseA, dim3(256), dim3(1024),
                             argsA, 131072, stream);

  b1_energy<<<256, 256, 0, stream>>>(ctxt, ws);
  b2_softmax<<<32, 1024, 0, stream>>>(ws);
  b3_ctx<<<256, 256, 0, stream>>>(ctxt, ws);
  b4_logits<<<128, 256, 0, stream>>>(Wout, bout, ws, out);
}

// Round 7
// 3595.784 us; speedup vs baseline: 6.8354x; 1.3119x over previous
//
#include <hip/hip_runtime.h>

#define BATCH 32
#define TENC  1024
#define HD    1024
#define ED    128
#define LL    128
#define GD    4096
#define IND   1152
#define HSTEP (BATCH*HD)

// ws float offsets
#define HBUF_OFF 131072                       // base: [0, 131072)
#define CNT_OFF  (HBUF_OFF + 129*HSTEP)       // h ring [129][32][1024]
#define E_OFF    (CNT_OFF + 64)
#define P_OFF    (E_OFF + BATCH*LL*TENC)
#define CTX_OFF  (P_OFF + BATCH*LL*TENC)
// wordg: bf16[128][4096][32] = 33.5 MB occupies [E_OFF, CTX_OFF) until B1 runs

__device__ __forceinline__ float sigf(float x) {
  return __builtin_amdgcn_rcpf(1.0f + __expf(-x));
}
__device__ __forceinline__ float tanhf_fast(float x) {
  return 1.0f - 2.0f * __builtin_amdgcn_rcpf(1.0f + __expf(2.0f * x));
}
__device__ __forceinline__ unsigned bfrne(float f) {       // f32 -> bf16 RNE
  unsigned v = __float_as_uint(f);
  return (v + 0x7fffu + ((v >> 16) & 1u)) >> 16;
}
__device__ __forceinline__ float bf2f(unsigned short u) {
  return __uint_as_float(((unsigned)u) << 16);
}
__device__ __forceinline__ void cstf(float* p, float v) {   // write-through, device-coherent
  __hip_atomic_store(p, v, __ATOMIC_RELAXED, __HIP_MEMORY_SCOPE_AGENT);
}
// grid barrier, no cache-flushing fences (R4/R5/R6-proven)
__device__ __forceinline__ void gbar(unsigned* cnt, unsigned target) {
  __syncthreads();
  if (threadIdx.x == 0) {
    __hip_atomic_fetch_add(cnt, 1u, __ATOMIC_RELAXED, __HIP_MEMORY_SCOPE_AGENT);
    while (__hip_atomic_load(cnt, __ATOMIC_RELAXED, __HIP_MEMORY_SCOPE_AGENT) < target)
      __builtin_amdgcn_s_sleep(2);
  }
  __syncthreads();
}
__device__ __forceinline__ float sel4(float a0, float a1, float a2, float a3, int i) {
  float r = a0;
  r = (i == 1) ? a1 : r;
  r = (i == 2) ? a2 : r;
  r = (i == 3) ? a3 : r;
  return r;
}

// base[b][g] = b_ih[g]+b_hh[g]+dot(ctx0[b], W_ih[g][E:])
__global__ __launch_bounds__(256) void base_kernel(
    const float* __restrict__ ctxt, const float* __restrict__ Wih,
    const float* __restrict__ bih, const float* __restrict__ bhh,
    float* __restrict__ base) {
  int id = blockIdx.x * 256 + threadIdx.x;
  int b = id & (BATCH - 1);
  int g = id >> 5;
  const float4* c4 = reinterpret_cast<const float4*>(ctxt + (size_t)b * TENC * HD);
  const float4* w4 = reinterpret_cast<const float4*>(Wih + (size_t)g * IND + ED);
  float a = 0.f;
#pragma unroll 8
  for (int kk = 0; kk < HD/4; ++kk) {
    float4 c = c4[kk], w = w4[kk];
    a += c.x*w.x + c.y*w.y + c.z*w.z + c.w*w.w;
  }
  base[(size_t)b * GD + g] = a + bih[g] + bhh[g];
}

// ---------------- Phase 0: wordg[t][row][b] = word_t[b] . Wih[row][0:128] (bf16) ----------------
__global__ __launch_bounds__(256) void phase0_wordg(
    const float* __restrict__ gt, const float* __restrict__ Wih,
    float* __restrict__ ws) {
  const int mt = blockIdx.x & 31, nt = blockIdx.x >> 5;
  const int r0 = mt * 128, n0 = nt * 128;
  const int tid = threadIdx.x, tx = tid & 15, ty = tid >> 4;
  unsigned short* wg = reinterpret_cast<unsigned short*>(ws + E_OFF);
  __shared__ float At[128][18];
  __shared__ float BtT[16][132];
  float acc[8][8];
#pragma unroll
  for (int i = 0; i < 8; ++i)
#pragma unroll
    for (int j = 0; j < 8; ++j) acc[i][j] = 0.f;

  const int sr = tid >> 1, sc = (tid & 1) * 8;
  for (int kt = 0; kt < 8; ++kt) {
    const int k0 = kt * 16;
    const float* ap = Wih + (size_t)(r0 + sr) * IND + k0 + sc;
    float4 a0 = *reinterpret_cast<const float4*>(ap);
    float4 a1 = *reinterpret_cast<const float4*>(ap + 4);
    const int n = n0 + sr, t = n >> 5, bb = n & 31;
    float4 b0, b1;
    if (t == 0) {
      b0 = make_float4((k0 + sc == 0) ? 1.f : 0.f, 0.f, 0.f, 0.f);
      b1 = make_float4(0.f, 0.f, 0.f, 0.f);
    } else {
      const float* bp = gt + ((size_t)bb * LL + (t - 1)) * ED + k0 + sc;
      b0 = *reinterpret_cast<const float4*>(bp);
      b1 = *reinterpret_cast<const float4*>(bp + 4);
    }
    __syncthreads();
    *reinterpret_cast<float4*>(&At[sr][sc]) = a0;
    *reinterpret_cast<float4*>(&At[sr][sc + 4]) = a1;
    BtT[sc+0][sr] = b0.x; BtT[sc+1][sr] = b0.y; BtT[sc+2][sr] = b0.z; BtT[sc+3][sr] = b0.w;
    BtT[sc+4][sr] = b1.x; BtT[sc+5][sr] = b1.y; BtT[sc+6][sr] = b1.z; BtT[sc+7][sr] = b1.w;
    __syncthreads();
#pragma unroll
    for (int kk2 = 0; kk2 < 8; ++kk2) {
      float2 av[8];
#pragma unroll
      for (int i = 0; i < 8; ++i)
        av[i] = *reinterpret_cast<const float2*>(&At[ty*8 + i][kk2*2]);
      float4 c00 = *reinterpret_cast<const float4*>(&BtT[kk2*2][tx*8]);
      float4 c01 = *reinterpret_cast<const float4*>(&BtT[kk2*2][tx*8 + 4]);
      float4 c10 = *reinterpret_cast<const float4*>(&BtT[kk2*2+1][tx*8]);
      float4 c11 = *reinterpret_cast<const float4*>(&BtT[kk2*2+1][tx*8 + 4]);
#pragma unroll
      for (int i = 0; i < 8; ++i) {
        acc[i][0] += av[i].x*c00.x + av[i].y*c10.x;
        acc[i][1] += av[i].x*c00.y + av[i].y*c10.y;
        acc[i][2] += av[i].x*c00.z + av[i].y*c10.z;
        acc[i][3] += av[i].x*c00.w + av[i].y*c10.w;
        acc[i][4] += av[i].x*c01.x + av[i].y*c11.x;
        acc[i][5] += av[i].x*c01.y + av[i].y*c11.y;
        acc[i][6] += av[i].x*c01.z + av[i].y*c11.z;
        acc[i][7] += av[i].x*c01.w + av[i].y*c11.w;
      }
    }
  }
  const int nb = n0 + tx * 8, t = nb >> 5, b0i = nb & 31;
#pragma unroll
  for (int i = 0; i < 8; ++i) {
    const int row = r0 + ty * 8 + i;
    uint4 pk;
    pk.x = bfrne(acc[i][0]) | (bfrne(acc[i][1]) << 16);
    pk.y = bfrne(acc[i][2]) | (bfrne(acc[i][3]) << 16);
    pk.z = bfrne(acc[i][4]) | (bfrne(acc[i][5]) << 16);
    pk.w = bfrne(acc[i][6]) | (bfrne(acc[i][7]) << 16);
    *reinterpret_cast<uint4*>(wg + ((size_t)t * GD + row) * 32 + b0i) = pk;
  }
}

// ---------------- Phase A: recurrence ----------------
// 256 blocks x 1024 thr. Block rg owns j = rg*4..rg*4+3 (x 4 gates = 16 rows).
// Wave w: rq=w&3 -> j, bq=w>>2 -> batches bq*8..+7 (2 halves of 4).
// Lane covers 16B units {lane + 64t, t=0..3} of each 1024-col row
// (= cols 4*(lane+64t)..+3) -> stride-1 across lanes: conflict-free LDS,
// coalesced Whh preload.
__global__ __launch_bounds__(1024, 4) void phaseA(
    const float* __restrict__ Whh, float* __restrict__ ws) {
  const int rg = blockIdx.x;
  const int tid = threadIdx.x;
  const int lane = tid & 63;
  const int w = tid >> 6;
  const int rq = w & 3, bq = w >> 2;
  const int j = rg * 4 + rq;
  const int lb = lane & 3;
  float* base = ws;
  float* hbuf = ws + HBUF_OFF;
  unsigned* cnt = reinterpret_cast<unsigned*>(ws + CNT_OFF);
  const unsigned short* wg = reinterpret_cast<const unsigned short*>(ws + E_OFF);

  extern __shared__ float h_lds[];   // [32][1024] linear, 128 KB

  // Whh register-resident: 4 gate-rows of j, unit slice lane+64t
  float4 Wr[4][4];
  const float4* Whh4 = reinterpret_cast<const float4*>(Whh);
#pragma unroll
  for (int g = 0; g < 4; ++g)
#pragma unroll
    for (int t = 0; t < 4; ++t)
      Wr[g][t] = Whh4[((size_t)(g * HD + j)) * 256 + lane + 64 * t];

  // base per (gate, half) for this lane's b
  float bs[4][2];
#pragma unroll
  for (int g = 0; g < 4; ++g)
#pragma unroll
    for (int hf = 0; hf < 2; ++hf)
      bs[g][hf] = base[(size_t)(bq * 8 + hf * 4 + lb) * GD + g * HD + j];

  float c0 = 0.f, c1 = 0.f;

  for (int k = 0; k < LL; ++k) {
    // stage h[k] -> LDS (linear; wave-contiguous units both sides)
    {
      const float4* src = reinterpret_cast<const float4*>(hbuf + (size_t)k * HSTEP);
      float4* dst = reinterpret_cast<float4*>(h_lds);
      float4 sv[8];
#pragma unroll
      for (int i = 0; i < 8; ++i) sv[i] = src[tid + 1024 * i];
#pragma unroll
      for (int i = 0; i < 8; ++i) dst[tid + 1024 * i] = sv[i];
    }
    __syncthreads();

#pragma unroll
    for (int hf = 0; hf < 2; ++hf) {
      float acc[4][4];
#pragma unroll
      for (int g = 0; g < 4; ++g)
#pragma unroll
        for (int bi = 0; bi < 4; ++bi) acc[g][bi] = 0.f;

#pragma unroll
      for (int bi = 0; bi < 4; ++bi) {
        const int b = bq * 8 + hf * 4 + bi;
        const float4* hb = reinterpret_cast<const float4*>(h_lds) + b * 256;
        float4 h0 = hb[lane], h1 = hb[lane + 64];
        float4 h2 = hb[lane + 128], h3 = hb[lane + 192];
#pragma unroll
        for (int g = 0; g < 4; ++g) {
          float4 w0 = Wr[g][0], w1 = Wr[g][1], w2 = Wr[g][2], w3 = Wr[g][3];
          float s = h0.x*w0.x + h0.y*w0.y + h0.z*w0.z + h0.w*w0.w;
          s += h1.x*w1.x + h1.y*w1.y + h1.z*w1.z + h1.w*w1.w;
          s += h2.x*w2.x + h2.y*w2.y + h2.z*w2.z + h2.w*w2.w;
          s += h3.x*w3.x + h3.y*w3.y + h3.z*w3.z + h3.w*w3.w;
          acc[g][bi] += s;
        }
      }
      // word-part (bf16, precomputed) for this lane's b
      const int bmine = bq * 8 + hf * 4 + lb;
      float wgv[4];
#pragma unroll
      for (int g = 0; g < 4; ++g)
        wgv[g] = bf2f(wg[((size_t)k * GD + g * HD + j) * 32 + bmine]);

      // butterfly allreduce over 64 lanes (16 values)
#pragma unroll
      for (int o = 1; o < 64; o <<= 1)
#pragma unroll
        for (int g = 0; g < 4; ++g)
#pragma unroll
          for (int bi = 0; bi < 4; ++bi)
            acc[g][bi] += __shfl_xor(acc[g][bi], o);

      float s0 = sel4(acc[0][0], acc[0][1], acc[0][2], acc[0][3], lb) + wgv[0] + bs[0][hf];
      float s1 = sel4(acc[1][0], acc[1][1], acc[1][2], acc[1][3], lb) + wgv[1] + bs[1][hf];
      float s2 = sel4(acc[2][0], acc[2][1], acc[2][2], acc[2][3], lb) + wgv[2] + bs[2][hf];
      float s3 = sel4(acc[3][0], acc[3][1], acc[3][2], acc[3][3], lb) + wgv[3] + bs[3][hf];
      float ig = sigf(s0);
      float fg = sigf(s1);
      float gg = tanhf_fast(s2);
      float og = sigf(s3);
      float cr = (hf == 0) ? c0 : c1;
      cr = fg * cr + ig * gg;
      if (hf == 0) c0 = cr; else c1 = cr;
      if (lane < 4)
        cstf(hbuf + (size_t)(k + 1) * HSTEP + (size_t)bmine * HD + j,
             og * tanhf_fast(cr));
    }
    if (k < LL - 1) gbar(cnt, (unsigned)((k + 1) * 256));
  }
}

// ---------------- Phase B1: E[b][t][p] = sum_d H[t][d] C[p][d] ----------------
__global__ __launch_bounds__(256) void b1_energy(
    const float* __restrict__ ctxt, float* __restrict__ ws) {
  const int b = blockIdx.x & 31, pt = blockIdx.x >> 5;
  const int p0 = pt * 128;
  const int tid = threadIdx.x, tx = tid & 15, ty = tid >> 4;
  const float* hbuf = ws + HBUF_OFF;
  float* E = ws + E_OFF;
  __shared__ float Ht[128][18];
  __shared__ float CtT[16][132];
  float acc[8][8];
#pragma unroll
  for (int i = 0; i < 8; ++i)
#pragma unroll
    for (int jj = 0; jj < 8; ++jj) acc[i][jj] = 0.f;

  const int sr = tid >> 1, sc = (tid & 1) * 8;
  float4 a0, a1, c0, c1;
  {
    const float* hs = hbuf + (size_t)(sr + 1) * HSTEP + (size_t)b * HD + sc;
    a0 = *reinterpret_cast<const float4*>(hs);
    a1 = *reinterpret_cast<const float4*>(hs + 4);
    const float* cs = ctxt + ((size_t)b * TENC + p0 + sr) * HD + sc;
    c0 = *reinterpret_cast<const float4*>(cs);
    c1 = *reinterpret_cast<const float4*>(cs + 4);
  }
  for (int kt = 0; kt < 64; ++kt) {
    __syncthreads();
    *reinterpret_cast<float4*>(&Ht[sr][sc]) = a0;
    *reinterpret_cast<float4*>(&Ht[sr][sc + 4]) = a1;
    CtT[sc+0][sr] = c0.x; CtT[sc+1][sr] = c0.y; CtT[sc+2][sr] = c0.z; CtT[sc+3][sr] = c0.w;
    CtT[sc+4][sr] = c1.x; CtT[sc+5][sr] = c1.y; CtT[sc+6][sr] = c1.z; CtT[sc+7][sr] = c1.w;
    __syncthreads();
    if (kt < 63) {
      const int d0 = (kt + 1) * 16;
      const float* hs = hbuf + (size_t)(sr + 1) * HSTEP + (size_t)b * HD + d0 + sc;
      a0 = *reinterpret_cast<const float4*>(hs);
      a1 = *reinterpret_cast<const float4*>(hs + 4);
      const float* cs = ctxt + ((size_t)b * TENC + p0 + sr) * HD + d0 + sc;
      c0 = *reinterpret_cast<const float4*>(cs);
      c1 = *reinterpret_cast<const float4*>(cs + 4);
    }
#pragma unroll
    for (int kk2 = 0; kk2 < 8; ++kk2) {
      float2 av[8];
#pragma unroll
      for (int i = 0; i < 8; ++i)
        av[i] = *reinterpret_cast<const float2*>(&Ht[ty*8 + i][kk2*2]);
      float4 b00 = *reinterpret_cast<const float4*>(&CtT[kk2*2][tx*8]);
      float4 b01 = *reinterpret_cast<const float4*>(&CtT[kk2*2][tx*8 + 4]);
      float4 b10 = *reinterpret_cast<const float4*>(&CtT[kk2*2+1][tx*8]);
      float4 b11 = *reinterpret_cast<const float4*>(&CtT[kk2*2+1][tx*8 + 4]);
#pragma unroll
      for (int i = 0; i < 8; ++i) {
        acc[i][0] += av[i].x*b00.x + av[i].y*b10.x;
        acc[i][1] += av[i].x*b00.y + av[i].y*b10.y;
        acc[i][2] += av[i].x*b00.z + av[i].y*b10.z;
        acc[i][3] += av[i].x*b00.w + av[i].y*b10.w;
        acc[i][4] += av[i].x*b01.x + av[i].y*b11.x;
        acc[i][5] += av[i].x*b01.y + av[i].y*b11.y;
        acc[i][6] += av[i].x*b01.z + av[i].y*b11.z;
        acc[i][7] += av[i].x*b01.w + av[i].y*b11.w;
      }
    }
  }
#pragma unroll
  for (int i = 0; i < 8; ++i) {
    float* ep = E + ((size_t)b * LL + ty*8 + i) * TENC + p0 + tx*8;
    *reinterpret_cast<float4*>(ep)     = make_float4(acc[i][0], acc[i][1], acc[i][2], acc[i][3]);
    *reinterpret_cast<float4*>(ep + 4) = make_float4(acc[i][4], acc[i][5], acc[i][6], acc[i][7]);
  }
}

// ---------------- Phase B2: row softmax E -> P ----------------
__global__ __launch_bounds__(1024) void b2_softmax(float* __restrict__ ws) {
  const int b = blockIdx.x;
  const int w = threadIdx.x >> 6, lane = threadIdx.x & 63;
  const float* E = ws + E_OFF;
  float* P = ws + P_OFF;
#pragma unroll
  for (int rr = 0; rr < 8; ++rr) {
    const int t = w * 8 + rr;
    const float4* e4 = reinterpret_cast<const float4*>(E + ((size_t)b * LL + t) * TENC);
    float4 v[4];
#pragma unroll
    for (int c = 0; c < 4; ++c) v[c] = e4[c * 64 + lane];
    float m = fmaxf(fmaxf(fmaxf(v[0].x, v[0].y), fmaxf(v[0].z, v[0].w)),
                    fmaxf(fmaxf(v[1].x, v[1].y), fmaxf(v[1].z, v[1].w)));
    m = fmaxf(m, fmaxf(fmaxf(fmaxf(v[2].x, v[2].y), fmaxf(v[2].z, v[2].w)),
                       fmaxf(fmaxf(v[3].x, v[3].y), fmaxf(v[3].z, v[3].w))));
#pragma unroll
    for (int o = 32; o > 0; o >>= 1) m = fmaxf(m, __shfl_xor(m, o));
    float s = 0.f;
#pragma unroll
    for (int c = 0; c < 4; ++c) {
      v[c].x = __expf(v[c].x - m); v[c].y = __expf(v[c].y - m);
      v[c].z = __expf(v[c].z - m); v[c].w = __expf(v[c].w - m);
      s += v[c].x + v[c].y + v[c].z + v[c].w;
    }
#pragma unroll
    for (int o = 32; o > 0; o >>= 1) s += __shfl_xor(s, o);
    float inv = __builtin_amdgcn_rcpf(s);
    float4* p4 = reinterpret_cast<float4*>(P + ((size_t)b * LL + t) * TENC);
#pragma unroll
    for (int c = 0; c < 4; ++c) {
      float4 o4 = make_float4(v[c].x*inv, v[c].y*inv, v[c].z*inv, v[c].w*inv);
      p4[c * 64 + lane] = o4;
    }
  }
}

// ---------------- Phase B3: CTX[b][t][d] = sum_p P[t][p] C[p][d] ----------------
__global__ __launch_bounds__(256) void b3_ctx(
    const float* __restrict__ ctxt, float* __restrict__ ws) {
  const int b = blockIdx.x & 31, dt = blockIdx.x >> 5;
  const int d0 = dt * 128;
  const int tid = threadIdx.x, tx = tid & 15, ty = tid >> 4;
  const float* P = ws + P_OFF;
  float* CTX = ws + CTX_OFF;
  __shared__ float Pt[128][18];
  __shared__ float Cd[16][132];
  float acc[8][8];
#pragma unroll
  for (int i = 0; i < 8; ++i)
#pragma unroll
    for (int jj = 0; jj < 8; ++jj) acc[i][jj] = 0.f;

  const int sr = tid >> 1, sc = (tid & 1) * 8;
  const int cr = tid >> 4, cc = (tid & 15) * 8;
  float4 a0, a1, c0, c1;
  {
    const float* ps = P + ((size_t)b * LL + sr) * TENC + sc;
    a0 = *reinterpret_cast<const float4*>(ps);
    a1 = *reinterpret_cast<const float4*>(ps + 4);
    const float* cs = ctxt + ((size_t)b * TENC + cr) * HD + d0 + cc;
    c0 = *reinterpret_cast<const float4*>(cs);
    c1 = *reinterpret_cast<const float4*>(cs + 4);
  }
  for (int kt = 0; kt < 64; ++kt) {
    __syncthreads();
    *reinterpret_cast<float4*>(&Pt[sr][sc]) = a0;
    *reinterpret_cast<float4*>(&Pt[sr][sc + 4]) = a1;
    *reinterpret_cast<float4*>(&Cd[cr][cc]) = c0;
    *reinterpret_cast<float4*>(&Cd[cr][cc + 4]) = c1;
    __syncthreads();
    if (kt < 63) {
      const int p0k = (kt + 1) * 16;
      const float* ps = P + ((size_t)b * LL + sr) * TENC + p0k + sc;
      a0 = *reinterpret_cast<const float4*>(ps);
      a1 = *reinterpret_cast<const float4*>(ps + 4);
      const float* cs = ctxt + ((size_t)b * TENC + p0k + cr) * HD + d0 + cc;
      c0 = *reinterpret_cast<const float4*>(cs);
      c1 = *reinterpret_cast<const float4*>(cs + 4);
    }
#pragma unroll
    for (int kk2 = 0; kk2 < 8; ++kk2) {
      float2 av[8];
#pragma unroll
      for (int i = 0; i < 8; ++i)
        av[i] = *reinterpret_cast<const float2*>(&Pt[ty*8 + i][kk2*2]);
      float4 b00 = *reinterpret_cast<const float4*>(&Cd[kk2*2][tx*8]);
      float4 b01 = *reinterpret_cast<const float4*>(&Cd[kk2*2][tx*8 + 4]);
      float4 b10 = *reinterpret_cast<const float4*>(&Cd[kk2*2+1][tx*8]);
      float4 b11 = *reinterpret_cast<const float4*>(&Cd[kk2*2+1][tx*8 + 4]);
#pragma unroll
      for (int i = 0; i < 8; ++i) {
        acc[i][0] += av[i].x*b00.x + av[i].y*b10.x;
        acc[i][1] += av[i].x*b00.y + av[i].y*b10.y;
        acc[i][2] += av[i].x*b00.z + av[i].y*b10.z;
        acc[i][3] += av[i].x*b00.w + av[i].y*b10.w;
        acc[i][4] += av[i].x*b01.x + av[i].y*b11.x;
        acc[i][5] += av[i].x*b01.y + av[i].y*b11.y;
        acc[i][6] += av[i].x*b01.z + av[i].y*b11.z;
        acc[i][7] += av[i].x*b01.w + av[i].y*b11.w;
      }
    }
  }
#pragma unroll
  for (int i = 0; i < 8; ++i) {
    float* cp = CTX + ((size_t)b * LL + ty*8 + i) * HD + d0 + tx*8;
    *reinterpret_cast<float4*>(cp)     = make_float4(acc[i][0], acc[i][1], acc[i][2], acc[i][3]);
    *reinterpret_cast<float4*>(cp + 4) = make_float4(acc[i][4], acc[i][5], acc[i][6], acc[i][7]);
  }
}

// ---------------- Phase B4: logits + log-softmax ----------------
__global__ __launch_bounds__(256) void b4_logits(
    const float* __restrict__ Wout, const float* __restrict__ bout,
    const float* __restrict__ ws, float* __restrict__ out) {
  const int b = blockIdx.x & 31, tq = blockIdx.x >> 5;
  const int t0 = tq * 32;
  const int tid = threadIdx.x, tx = tid & 15, ty = tid >> 4;
  const float* hbuf = ws + HBUF_OFF;
  const float* CTX = ws + CTX_OFF;
  __shared__ float Ft[32][18];
  __shared__ float WtT[16][132];
  __shared__ float lg[32][130];
  float acc[2][8];
#pragma unroll
  for (int i = 0; i < 2; ++i)
#pragma unroll
    for (int jj = 0; jj < 8; ++jj) acc[i][jj] = 0.f;

  const int fr = tid >> 2, fc = (tid & 3) * 4;
  const int we = tid >> 1, wc = (tid & 1) * 8;
  for (int kt = 0; kt < 128; ++kt) {
    const int k0 = kt * 16;
    float4 fv = make_float4(0,0,0,0);
    if (tid < 128) {
      const int kk = k0 + fc;
      const float* src = (kk < 1024)
        ? hbuf + (size_t)(t0 + fr + 1) * HSTEP + (size_t)b * HD + kk
        : CTX + ((size_t)b * LL + t0 + fr) * HD + (kk - 1024);
      fv = *reinterpret_cast<const float4*>(src);
    }
    const float* wsrc = Wout + (size_t)we * (2*HD) + k0 + wc;
    float4 w0 = *reinterpret_cast<const float4*>(wsrc);
    float4 w1 = *reinterpret_cast<const float4*>(wsrc + 4);
    __syncthreads();
    if (tid < 128) *reinterpret_cast<float4*>(&Ft[fr][fc]) = fv;
    WtT[wc+0][we] = w0.x; WtT[wc+1][we] = w0.y; WtT[wc+2][we] = w0.z; WtT[wc+3][we] = w0.w;
    WtT[wc+4][we] = w1.x; WtT[wc+5][we] = w1.y; WtT[wc+6][we] = w1.z; WtT[wc+7][we] = w1.w;
    __syncthreads();
#pragma unroll
    for (int kk2 = 0; kk2 < 8; ++kk2) {
      float2 av[2];
      av[0] = *reinterpret_cast<const float2*>(&Ft[ty*2][kk2*2]);
      av[1] = *reinterpret_cast<const float2*>(&Ft[ty*2 + 1][kk2*2]);
      float4 b00 = *reinterpret_cast<const float4*>(&WtT[kk2*2][tx*8]);
      float4 b01 = *reinterpret_cast<const float4*>(&WtT[kk2*2][tx*8 + 4]);
      float4 b10 = *reinterpret_cast<const float4*>(&WtT[kk2*2+1][tx*8]);
      float4 b11 = *reinterpret_cast<const float4*>(&WtT[kk2*2+1][tx*8 + 4]);
#pragma unroll
      for (int i = 0; i < 2; ++i) {
        acc[i][0] += av[i].x*b00.x + av[i].y*b10.x;
        acc[i][1] += av[i].x*b00.y + av[i].y*b10.y;
        acc[i][2] += av[i].x*b00.z + av[i].y*b10.z;
        acc[i][3] += av[i].x*b00.w + av[i].y*b10.w;
        acc[i][4] += av[i].x*b01.x + av[i].y*b11.x;
        acc[i][5] += av[i].x*b01.y + av[i].y*b11.y;
        acc[i][6] += av[i].x*b01.z + av[i].y*b11.z;
        acc[i][7] += av[i].x*b01.w + av[i].y*b11.w;
      }
    }
  }
#pragma unroll
  for (int i = 0; i < 2; ++i)
#pragma unroll
    for (int jj = 0; jj < 8; ++jj)
      lg[ty*2 + i][tx*8 + jj] = acc[i][jj] + bout[tx*8 + jj];
  __syncthreads();
  const int w = tid >> 6, lane = tid & 63;
#pragma unroll
  for (int rr = 0; rr < 8; ++rr) {
    const int row = w * 8 + rr;
    float v0 = lg[row][lane], v1 = lg[row][lane + 64];
    float mx = fmaxf(v0, v1);
#pragma unroll
    for (int o = 32; o > 0; o >>= 1) mx = fmaxf(mx, __shfl_xor(mx, o));
    float sm = __expf(v0 - mx) + __expf(v1 - mx);
#pragma unroll
    for (int o = 32; o > 0; o >>= 1) sm += __shfl_xor(sm, o);
    float lse = mx + __logf(sm);
    float* op = out + ((size_t)b * LL + t0 + row) * ED;
    op[lane]      = v0 - lse;
    op[lane + 64] = v1 - lse;
  }
}

extern "C" void kernel_launch(void* const* d_in, const int* in_sizes, int n_in,
                              void* d_out, int out_size, void* d_ws, size_t ws_size,
                              hipStream_t stream) {
  (void)in_sizes; (void)n_in; (void)out_size; (void)ws_size;
  const float* ctxt = (const float*)d_in[0];
  const float* gt   = (const float*)d_in[1];
  const float* Wih  = (const float*)d_in[2];
  const float* Whh  = (const float*)d_in[3];
  const float* bih  = (const float*)d_in[4];
  const float* bhh  = (const float*)d_in[5];
  const float* Wout = (const float*)d_in[6];
  const float* bout = (const float*)d_in[7];
  float* out = (float*)d_out;
  float* ws  = (float*)d_ws;

  hipMemsetAsync(ws + HBUF_OFF, 0, (size_t)HSTEP * sizeof(float), stream); // h_0 = 0
  hipMemsetAsync(ws + CNT_OFF, 0, 256, stream);                            // barrier

  base_kernel<<<(BATCH * GD) / 256, 256, 0, stream>>>(ctxt, Wih, bih, bhh, ws);
  phase0_wordg<<<1024, 256, 0, stream>>>(gt, Wih, ws);

  static int smem_set = 0;
  if (!smem_set) {
    hipFuncSetAttribute((const void*)&phaseA,
                        hipFuncAttributeMaxDynamicSharedMemorySize, 131072);
    smem_set = 1;
  }
  void* argsA[] = { (void*)&Whh, (void*)&ws };
  hipLaunchCooperativeKernel((const void*)&phaseA, dim3(256), dim3(1024),
                             argsA, 131072, stream);

  b1_energy<<<256, 256, 0, stream>>>(ctxt, ws);
  b2_softmax<<<32, 1024, 0, stream>>>(ws);
  b3_ctx<<<256, 256, 0, stream>>>(ctxt, ws);
  b4_logits<<<128, 256, 0, stream>>>(Wout, bout, ws, out);
}

// Round 9
// 1780.307 us; speedup vs baseline: 13.8057x; 2.0198x over previous
//
#include <hip/hip_runtime.h>

#define BATCH 32
#define TENC  1024
#define HD    1024
#define ED    128
#define LL    128
#define GD    4096
#define IND   1152
#define HSTEP (BATCH*HD)

// ws float offsets
#define HBUF_OFF 131072                       // base: [0, 131072)
#define ARR_OFF  (HBUF_OFF + 129*HSTEP)       // h ring [129][32][1024] f32
#define REL_OFF  (ARR_OFF + 8192)             // arrival flags: 256 x 128B
#define E_OFF    (REL_OFF + 64)               // release word (padded)
#define P_OFF    (E_OFF + BATCH*LL*TENC)
#define CTX_OFF  (P_OFF + BATCH*LL*TENC)
#define W16_OFF  CTX_OFF                      // Whh f16 (8.4MB) in dead CTX region
// wordg: bf16[128][4096][32] = 33.5 MB occupies [E_OFF, CTX_OFF) until B1 runs

typedef _Float16 h16x2 __attribute__((ext_vector_type(2)));   // for fdot2
typedef __fp16   f16x2 __attribute__((ext_vector_type(2)));   // cvt_pkrtz result
union CVT { f16x2 f; h16x2 h; unsigned u; };

__device__ __forceinline__ unsigned pk16(float x, float y) {
  CVT c; c.f = __builtin_amdgcn_cvt_pkrtz(x, y); return c.u;
}
__device__ __forceinline__ float sigf(float x) {
  return __builtin_amdgcn_rcpf(1.0f + __expf(-x));
}
__device__ __forceinline__ float tanhf_fast(float x) {
  return 1.0f - 2.0f * __builtin_amdgcn_rcpf(1.0f + __expf(2.0f * x));
}
__device__ __forceinline__ unsigned bfrne(float f) {       // f32 -> bf16 RNE
  unsigned v = __float_as_uint(f);
  return (v + 0x7fffu + ((v >> 16) & 1u)) >> 16;
}
__device__ __forceinline__ float bf2f(unsigned short u) {
  return __uint_as_float(((unsigned)u) << 16);
}
__device__ __forceinline__ void cstf(float* p, float v) {   // write-through, device-coherent
  __hip_atomic_store(p, v, __ATOMIC_RELAXED, __HIP_MEMORY_SCOPE_AGENT);
}
__device__ __forceinline__ void cstu(unsigned* p, unsigned v) {
  __hip_atomic_store(p, v, __ATOMIC_RELAXED, __HIP_MEMORY_SCOPE_AGENT);
}
__device__ __forceinline__ unsigned cldu(const unsigned* p) {
  return __hip_atomic_load(p, __ATOMIC_RELAXED, __HIP_MEMORY_SCOPE_AGENT);
}
__device__ __forceinline__ float dot4h(uint2 hv, uint2 wv, float a) {
  CVT hx{.u = hv.x}, hy{.u = hv.y}, wx{.u = wv.x}, wy{.u = wv.y};
  a = __builtin_amdgcn_fdot2(hx.h, wx.h, a, false);
  a = __builtin_amdgcn_fdot2(hy.h, wy.h, a, false);
  return a;
}

// base[b][g] = b_ih[g]+b_hh[g]+dot(ctx0[b], W_ih[g][E:])
__global__ __launch_bounds__(256) void base_kernel(
    const float* __restrict__ ctxt, const float* __restrict__ Wih,
    const float* __restrict__ bih, const float* __restrict__ bhh,
    float* __restrict__ base) {
  int id = blockIdx.x * 256 + threadIdx.x;
  int b = id & (BATCH - 1);
  int g = id >> 5;
  const float4* c4 = reinterpret_cast<const float4*>(ctxt + (size_t)b * TENC * HD);
  const float4* w4 = reinterpret_cast<const float4*>(Wih + (size_t)g * IND + ED);
  float a = 0.f;
#pragma unroll 8
  for (int kk = 0; kk < HD/4; ++kk) {
    float4 c = c4[kk], w = w4[kk];
    a += c.x*w.x + c.y*w.y + c.z*w.z + c.w*w.w;
  }
  base[(size_t)b * GD + g] = a + bih[g] + bhh[g];
}

// Whh f32 -> f16 (RTZ pack), 8 elements/thread
__global__ __launch_bounds__(256) void whh16_kernel(
    const float* __restrict__ Whh, float* __restrict__ ws) {
  unsigned short* W16 = reinterpret_cast<unsigned short*>(ws + W16_OFF);
  size_t i = ((size_t)blockIdx.x * 256 + threadIdx.x) * 8;
  float4 a = *reinterpret_cast<const float4*>(Whh + i);
  float4 b = *reinterpret_cast<const float4*>(Whh + i + 4);
  uint4 o;
  o.x = pk16(a.x, a.y);
  o.y = pk16(a.z, a.w);
  o.z = pk16(b.x, b.y);
  o.w = pk16(b.z, b.w);
  *reinterpret_cast<uint4*>(W16 + i) = o;
}

// ---------------- Phase 0: wordg[t][row][b] = word_t[b] . Wih[row][0:128] (bf16) ----------------
__global__ __launch_bounds__(256) void phase0_wordg(
    const float* __restrict__ gt, const float* __restrict__ Wih,
    float* __restrict__ ws) {
  const int mt = blockIdx.x & 31, nt = blockIdx.x >> 5;
  const int r0 = mt * 128, n0 = nt * 128;
  const int tid = threadIdx.x, tx = tid & 15, ty = tid >> 4;
  unsigned short* wg = reinterpret_cast<unsigned short*>(ws + E_OFF);
  __shared__ float At[128][18];
  __shared__ float BtT[16][132];
  float acc[8][8];
#pragma unroll
  for (int i = 0; i < 8; ++i)
#pragma unroll
    for (int j = 0; j < 8; ++j) acc[i][j] = 0.f;

  const int sr = tid >> 1, sc = (tid & 1) * 8;
  for (int kt = 0; kt < 8; ++kt) {
    const int k0 = kt * 16;
    const float* ap = Wih + (size_t)(r0 + sr) * IND + k0 + sc;
    float4 a0 = *reinterpret_cast<const float4*>(ap);
    float4 a1 = *reinterpret_cast<const float4*>(ap + 4);
    const int n = n0 + sr, t = n >> 5, bb = n & 31;
    float4 b0, b1;
    if (t == 0) {
      b0 = make_float4((k0 + sc == 0) ? 1.f : 0.f, 0.f, 0.f, 0.f);
      b1 = make_float4(0.f, 0.f, 0.f, 0.f);
    } else {
      const float* bp = gt + ((size_t)bb * LL + (t - 1)) * ED + k0 + sc;
      b0 = *reinterpret_cast<const float4*>(bp);
      b1 = *reinterpret_cast<const float4*>(bp + 4);
    }
    __syncthreads();
    *reinterpret_cast<float4*>(&At[sr][sc]) = a0;
    *reinterpret_cast<float4*>(&At[sr][sc + 4]) = a1;
    BtT[sc+0][sr] = b0.x; BtT[sc+1][sr] = b0.y; BtT[sc+2][sr] = b0.z; BtT[sc+3][sr] = b0.w;
    BtT[sc+4][sr] = b1.x; BtT[sc+5][sr] = b1.y; BtT[sc+6][sr] = b1.z; BtT[sc+7][sr] = b1.w;
    __syncthreads();
#pragma unroll
    for (int kk2 = 0; kk2 < 8; ++kk2) {
      float2 av[8];
#pragma unroll
      for (int i = 0; i < 8; ++i)
        av[i] = *reinterpret_cast<const float2*>(&At[ty*8 + i][kk2*2]);
      float4 c00 = *reinterpret_cast<const float4*>(&BtT[kk2*2][tx*8]);
      float4 c01 = *reinterpret_cast<const float4*>(&BtT[kk2*2][tx*8 + 4]);
      float4 c10 = *reinterpret_cast<const float4*>(&BtT[kk2*2+1][tx*8]);
      float4 c11 = *reinterpret_cast<const float4*>(&BtT[kk2*2+1][tx*8 + 4]);
#pragma unroll
      for (int i = 0; i < 8; ++i) {
        acc[i][0] += av[i].x*c00.x + av[i].y*c10.x;
        acc[i][1] += av[i].x*c00.y + av[i].y*c10.y;
        acc[i][2] += av[i].x*c00.z + av[i].y*c10.z;
        acc[i][3] += av[i].x*c00.w + av[i].y*c10.w;
        acc[i][4] += av[i].x*c01.x + av[i].y*c11.x;
        acc[i][5] += av[i].x*c01.y + av[i].y*c11.y;
        acc[i][6] += av[i].x*c01.z + av[i].y*c11.z;
        acc[i][7] += av[i].x*c01.w + av[i].y*c11.w;
      }
    }
  }
  const int nb = n0 + tx * 8, t = nb >> 5, b0i = nb & 31;
#pragma unroll
  for (int i = 0; i < 8; ++i) {
    const int row = r0 + ty * 8 + i;
    uint4 pk;
    pk.x = bfrne(acc[i][0]) | (bfrne(acc[i][1]) << 16);
    pk.y = bfrne(acc[i][2]) | (bfrne(acc[i][3]) << 16);
    pk.z = bfrne(acc[i][4]) | (bfrne(acc[i][5]) << 16);
    pk.w = bfrne(acc[i][6]) | (bfrne(acc[i][7]) << 16);
    *reinterpret_cast<uint4*>(wg + ((size_t)t * GD + row) * 32 + b0i) = pk;
  }
}

// ---------------- Phase A: recurrence (f16 dot2, flag barrier) ----------------
// 256 blocks x 1024 thr. Block rg owns j = rg*4..rg*4+3 (x 4 gates).
// Wave w: rq=w&3 -> j, bq=w>>2 -> 8 batches (2 halves of 4).
// Lane covers cols 4*(lane+64t), t=0..3 (8B f16 units, stride-1 lanes).
__global__ __launch_bounds__(1024, 4) void phaseA(float* __restrict__ ws) {
  const int rg = blockIdx.x;
  const int tid = threadIdx.x;
  const int lane = tid & 63;
  const int w = tid >> 6;
  const int rq = w & 3, bq = w >> 2;
  const int j = rg * 4 + rq;
  const int lb = lane & 3;
  float* base = ws;
  float* hbuf = ws + HBUF_OFF;
  unsigned* arr = reinterpret_cast<unsigned*>(ws + ARR_OFF);
  unsigned* rel = reinterpret_cast<unsigned*>(ws + REL_OFF);
  const unsigned short* wg = reinterpret_cast<const unsigned short*>(ws + E_OFF);
  const uint2* W16 = reinterpret_cast<const uint2*>(ws + W16_OFF);

  extern __shared__ uint2 h_lds[];   // 8192 uint2 = 64 KB: h[k] as f16[32][1024]

  // Whh f16 register-resident: 4 gate-rows of j, units lane+64t
  uint2 Wr[4][4];
#pragma unroll
  for (int g = 0; g < 4; ++g)
#pragma unroll
    for (int t = 0; t < 4; ++t)
      Wr[g][t] = W16[(size_t)(g * HD + j) * 256 + lane + 64 * t];

  // base per (gate, half) for this lane's b
  float bs[4][2];
#pragma unroll
  for (int g = 0; g < 4; ++g)
#pragma unroll
    for (int hf = 0; hf < 2; ++hf)
      bs[g][hf] = base[(size_t)(bq * 8 + hf * 4 + lb) * GD + g * HD + j];

  float c0 = 0.f, c1 = 0.f;

  for (int k = 0; k < LL; ++k) {
    // stage h[k] f32 -> LDS f16 (lane-contiguous units both sides)
    {
      const float4* src = reinterpret_cast<const float4*>(hbuf + (size_t)k * HSTEP);
      float4 sv[8];
#pragma unroll
      for (int i = 0; i < 8; ++i) sv[i] = src[tid + 1024 * i];
#pragma unroll
      for (int i = 0; i < 8; ++i) {
        uint2 c;
        c.x = pk16(sv[i].x, sv[i].y);
        c.y = pk16(sv[i].z, sv[i].w);
        h_lds[tid + 1024 * i] = c;
      }
    }
    __syncthreads();

#pragma unroll
    for (int hf = 0; hf < 2; ++hf) {
      float acc[4][4];
#pragma unroll
      for (int g = 0; g < 4; ++g)
#pragma unroll
        for (int bi = 0; bi < 4; ++bi) acc[g][bi] = 0.f;

#pragma unroll
      for (int bi = 0; bi < 4; ++bi) {
        const int b = bq * 8 + hf * 4 + bi;
        const uint2* hb = h_lds + b * 256;
        uint2 h0 = hb[lane], h1 = hb[lane + 64];
        uint2 h2 = hb[lane + 128], h3 = hb[lane + 192];
#pragma unroll
        for (int g = 0; g < 4; ++g) {
          float a = acc[g][bi];
          a = dot4h(h0, Wr[g][0], a);
          a = dot4h(h1, Wr[g][1], a);
          a = dot4h(h2, Wr[g][2], a);
          a = dot4h(h3, Wr[g][3], a);
          acc[g][bi] = a;
        }
      }
      // split-exchange reduce: s[g] = total acc[g][lane&3]
      const bool p1 = (lane & 1), p2 = (lane & 2);
      float s[4];
#pragma unroll
      for (int g = 0; g < 4; ++g) {
        float send0 = p1 ? acc[g][0] : acc[g][1];
        float keep0 = p1 ? acc[g][1] : acc[g][0];
        float r0 = keep0 + __shfl_xor(send0, 1);
        float send1 = p1 ? acc[g][2] : acc[g][3];
        float keep1 = p1 ? acc[g][3] : acc[g][2];
        float r1 = keep1 + __shfl_xor(send1, 1);
        float send2 = p2 ? r0 : r1;
        float keep2 = p2 ? r1 : r0;
        float sg = keep2 + __shfl_xor(send2, 2);
        sg += __shfl_xor(sg, 4);
        sg += __shfl_xor(sg, 8);
        sg += __shfl_xor(sg, 16);
        sg += __shfl_xor(sg, 32);
        s[g] = sg;
      }
      const int bmine = bq * 8 + hf * 4 + lb;
      float wv0 = bf2f(wg[((size_t)k * GD + 0 * HD + j) * 32 + bmine]);
      float wv1 = bf2f(wg[((size_t)k * GD + 1 * HD + j) * 32 + bmine]);
      float wv2 = bf2f(wg[((size_t)k * GD + 2 * HD + j) * 32 + bmine]);
      float wv3 = bf2f(wg[((size_t)k * GD + 3 * HD + j) * 32 + bmine]);
      float ig = sigf(s[0] + wv0 + bs[0][hf]);
      float fg = sigf(s[1] + wv1 + bs[1][hf]);
      float gg = tanhf_fast(s[2] + wv2 + bs[2][hf]);
      float og = sigf(s[3] + wv3 + bs[3][hf]);
      float cr = hf ? c1 : c0;
      cr = fg * cr + ig * gg;
      if (hf) c1 = cr; else c0 = cr;
      if (lane < 4)
        cstf(hbuf + (size_t)(k + 1) * HSTEP + (size_t)bmine * HD + j,
             og * tanhf_fast(cr));
    }

    if (k < LL - 1) {
      // flag barrier: parallel arrival stores, master aggregates, broadcast release
      __syncthreads();                       // drains all waves' h stores (vmcnt)
      const unsigned tgt = (unsigned)(k + 1);
      if (tid == 0) cstu(arr + rg * 32, tgt);
      if (rg == 0 && tid < 64) {
        int ok;
        do {
          ok = 1;
#pragma unroll
          for (int q = 0; q < 4; ++q) {
            unsigned v = cldu(arr + (lane * 4 + q) * 32);
            ok &= (v >= tgt);
          }
        } while (!__all(ok));
        if (tid == 0) cstu(rel, tgt);
      } else if (rg != 0 && tid == 0) {
        while (cldu(rel) < tgt) __builtin_amdgcn_s_sleep(1);
      }
      __syncthreads();
    }
  }
}

// ---------------- Phase B1: E[b][t][p] = sum_d H[t][d] C[p][d] ----------------
__global__ __launch_bounds__(256) void b1_energy(
    const float* __restrict__ ctxt, float* __restrict__ ws) {
  const int b = blockIdx.x & 31, pt = blockIdx.x >> 5;
  const int p0 = pt * 128;
  const int tid = threadIdx.x, tx = tid & 15, ty = tid >> 4;
  const float* hbuf = ws + HBUF_OFF;
  float* E = ws + E_OFF;
  __shared__ float Ht[128][18];
  __shared__ float CtT[16][132];
  float acc[8][8];
#pragma unroll
  for (int i = 0; i < 8; ++i)
#pragma unroll
    for (int jj = 0; jj < 8; ++jj) acc[i][jj] = 0.f;

  const int sr = tid >> 1, sc = (tid & 1) * 8;
  float4 a0, a1, c0, c1;
  {
    const float* hs = hbuf + (size_t)(sr + 1) * HSTEP + (size_t)b * HD + sc;
    a0 = *reinterpret_cast<const float4*>(hs);
    a1 = *reinterpret_cast<const float4*>(hs + 4);
    const float* cs = ctxt + ((size_t)b * TENC + p0 + sr) * HD + sc;
    c0 = *reinterpret_cast<const float4*>(cs);
    c1 = *reinterpret_cast<const float4*>(cs + 4);
  }
  for (int kt = 0; kt < 64; ++kt) {
    __syncthreads();
    *reinterpret_cast<float4*>(&Ht[sr][sc]) = a0;
    *reinterpret_cast<float4*>(&Ht[sr][sc + 4]) = a1;
    CtT[sc+0][sr] = c0.x; CtT[sc+1][sr] = c0.y; CtT[sc+2][sr] = c0.z; CtT[sc+3][sr] = c0.w;
    CtT[sc+4][sr] = c1.x; CtT[sc+5][sr] = c1.y; CtT[sc+6][sr] = c1.z; CtT[sc+7][sr] = c1.w;
    __syncthreads();
    if (kt < 63) {
      const int d0 = (kt + 1) * 16;
      const float* hs = hbuf + (size_t)(sr + 1) * HSTEP + (size_t)b * HD + d0 + sc;
      a0 = *reinterpret_cast<const float4*>(hs);
      a1 = *reinterpret_cast<const float4*>(hs + 4);
      const float* cs = ctxt + ((size_t)b * TENC + p0 + sr) * HD + d0 + sc;
      c0 = *reinterpret_cast<const float4*>(cs);
      c1 = *reinterpret_cast<const float4*>(cs + 4);
    }
#pragma unroll
    for (int kk2 = 0; kk2 < 8; ++kk2) {
      float2 av[8];
#pragma unroll
      for (int i = 0; i < 8; ++i)
        av[i] = *reinterpret_cast<const float2*>(&Ht[ty*8 + i][kk2*2]);
      float4 b00 = *reinterpret_cast<const float4*>(&CtT[kk2*2][tx*8]);
      float4 b01 = *reinterpret_cast<const float4*>(&CtT[kk2*2][tx*8 + 4]);
      float4 b10 = *reinterpret_cast<const float4*>(&CtT[kk2*2+1][tx*8]);
      float4 b11 = *reinterpret_cast<const float4*>(&CtT[kk2*2+1][tx*8 + 4]);
#pragma unroll
      for (int i = 0; i < 8; ++i) {
        acc[i][0] += av[i].x*b00.x + av[i].y*b10.x;
        acc[i][1] += av[i].x*b00.y + av[i].y*b10.y;
        acc[i][2] += av[i].x*b00.z + av[i].y*b10.z;
        acc[i][3] += av[i].x*b00.w + av[i].y*b10.w;
        acc[i][4] += av[i].x*b01.x + av[i].y*b11.x;
        acc[i][5] += av[i].x*b01.y + av[i].y*b11.y;
        acc[i][6] += av[i].x*b01.z + av[i].y*b11.z;
        acc[i][7] += av[i].x*b01.w + av[i].y*b11.w;
      }
    }
  }
#pragma unroll
  for (int i = 0; i < 8; ++i) {
    float* ep = E + ((size_t)b * LL + ty*8 + i) * TENC + p0 + tx*8;
    *reinterpret_cast<float4*>(ep)     = make_float4(acc[i][0], acc[i][1], acc[i][2], acc[i][3]);
    *reinterpret_cast<float4*>(ep + 4) = make_float4(acc[i][4], acc[i][5], acc[i][6], acc[i][7]);
  }
}

// ---------------- Phase B2: row softmax E -> P ----------------
__global__ __launch_bounds__(1024) void b2_softmax(float* __restrict__ ws) {
  const int b = blockIdx.x;
  const int w = threadIdx.x >> 6, lane = threadIdx.x & 63;
  const float* E = ws + E_OFF;
  float* P = ws + P_OFF;
#pragma unroll
  for (int rr = 0; rr < 8; ++rr) {
    const int t = w * 8 + rr;
    const float4* e4 = reinterpret_cast<const float4*>(E + ((size_t)b * LL + t) * TENC);
    float4 v[4];
#pragma unroll
    for (int c = 0; c < 4; ++c) v[c] = e4[c * 64 + lane];
    float m = fmaxf(fmaxf(fmaxf(v[0].x, v[0].y), fmaxf(v[0].z, v[0].w)),
                    fmaxf(fmaxf(v[1].x, v[1].y), fmaxf(v[1].z, v[1].w)));
    m = fmaxf(m, fmaxf(fmaxf(fmaxf(v[2].x, v[2].y), fmaxf(v[2].z, v[2].w)),
                       fmaxf(fmaxf(v[3].x, v[3].y), fmaxf(v[3].z, v[3].w))));
#pragma unroll
    for (int o = 32; o > 0; o >>= 1) m = fmaxf(m, __shfl_xor(m, o));
    float s = 0.f;
#pragma unroll
    for (int c = 0; c < 4; ++c) {
      v[c].x = __expf(v[c].x - m); v[c].y = __expf(v[c].y - m);
      v[c].z = __expf(v[c].z - m); v[c].w = __expf(v[c].w - m);
      s += v[c].x + v[c].y + v[c].z + v[c].w;
    }
#pragma unroll
    for (int o = 32; o > 0; o >>= 1) s += __shfl_xor(s, o);
    float inv = __builtin_amdgcn_rcpf(s);
    float4* p4 = reinterpret_cast<float4*>(P + ((size_t)b * LL + t) * TENC);
#pragma unroll
    for (int c = 0; c < 4; ++c) {
      float4 o4 = make_float4(v[c].x*inv, v[c].y*inv, v[c].z*inv, v[c].w*inv);
      p4[c * 64 + lane] = o4;
    }
  }
}

// ---------------- Phase B3: CTX[b][t][d] = sum_p P[t][p] C[p][d] ----------------
__global__ __launch_bounds__(256) void b3_ctx(
    const float* __restrict__ ctxt, float* __restrict__ ws) {
  const int b = blockIdx.x & 31, dt = blockIdx.x >> 5;
  const int d0 = dt * 128;
  const int tid = threadIdx.x, tx = tid & 15, ty = tid >> 4;
  const float* P = ws + P_OFF;
  float* CTX = ws + CTX_OFF;
  __shared__ float Pt[128][18];
  __shared__ float Cd[16][132];
  float acc[8][8];
#pragma unroll
  for (int i = 0; i < 8; ++i)
#pragma unroll
    for (int jj = 0; jj < 8; ++jj) acc[i][jj] = 0.f;

  const int sr = tid >> 1, sc = (tid & 1) * 8;
  const int cr = tid >> 4, cc = (tid & 15) * 8;
  float4 a0, a1, c0, c1;
  {
    const float* ps = P + ((size_t)b * LL + sr) * TENC + sc;
    a0 = *reinterpret_cast<const float4*>(ps);
    a1 = *reinterpret_cast<const float4*>(ps + 4);
    const float* cs = ctxt + ((size_t)b * TENC + cr) * HD + d0 + cc;
    c0 = *reinterpret_cast<const float4*>(cs);
    c1 = *reinterpret_cast<const float4*>(cs + 4);
  }
  for (int kt = 0; kt < 64; ++kt) {
    __syncthreads();
    *reinterpret_cast<float4*>(&Pt[sr][sc]) = a0;
    *reinterpret_cast<float4*>(&Pt[sr][sc + 4]) = a1;
    *reinterpret_cast<float4*>(&Cd[cr][cc]) = c0;
    *reinterpret_cast<float4*>(&Cd[cr][cc + 4]) = c1;
    __syncthreads();
    if (kt < 63) {
      const int p0k = (kt + 1) * 16;
      const float* ps = P + ((size_t)b * LL + sr) * TENC + p0k + sc;
      a0 = *reinterpret_cast<const float4*>(ps);
      a1 = *reinterpret_cast<const float4*>(ps + 4);
      const float* cs = ctxt + ((size_t)b * TENC + p0k + cr) * HD + d0 + cc;
      c0 = *reinterpret_cast<const float4*>(cs);
      c1 = *reinterpret_cast<const float4*>(cs + 4);
    }
#pragma unroll
    for (int kk2 = 0; kk2 < 8; ++kk2) {
      float2 av[8];
#pragma unroll
      for (int i = 0; i < 8; ++i)
        av[i] = *reinterpret_cast<const float2*>(&Pt[ty*8 + i][kk2*2]);
      float4 b00 = *reinterpret_cast<const float4*>(&Cd[kk2*2][tx*8]);
      float4 b01 = *reinterpret_cast<const float4*>(&Cd[kk2*2][tx*8 + 4]);
      float4 b10 = *reinterpret_cast<const float4*>(&Cd[kk2*2+1][tx*8]);
      float4 b11 = *reinterpret_cast<const float4*>(&Cd[kk2*2+1][tx*8 + 4]);
#pragma unroll
      for (int i = 0; i < 8; ++i) {
        acc[i][0] += av[i].x*b00.x + av[i].y*b10.x;
        acc[i][1] += av[i].x*b00.y + av[i].y*b10.y;
        acc[i][2] += av[i].x*b00.z + av[i].y*b10.z;
        acc[i][3] += av[i].x*b00.w + av[i].y*b10.w;
        acc[i][4] += av[i].x*b01.x + av[i].y*b11.x;
        acc[i][5] += av[i].x*b01.y + av[i].y*b11.y;
        acc[i][6] += av[i].x*b01.z + av[i].y*b11.z;
        acc[i][7] += av[i].x*b01.w + av[i].y*b11.w;
      }
    }
  }
#pragma unroll
  for (int i = 0; i < 8; ++i) {
    float* cp = CTX + ((size_t)b * LL + ty*8 + i) * HD + d0 + tx*8;
    *reinterpret_cast<float4*>(cp)     = make_float4(acc[i][0], acc[i][1], acc[i][2], acc[i][3]);
    *reinterpret_cast<float4*>(cp + 4) = make_float4(acc[i][4], acc[i][5], acc[i][6], acc[i][7]);
  }
}

// ---------------- Phase B4: logits + log-softmax ----------------
__global__ __launch_bounds__(256) void b4_logits(
    const float* __restrict__ Wout, const float* __restrict__ bout,
    const float* __restrict__ ws, float* __restrict__ out) {
  const int b = blockIdx.x & 31, tq = blockIdx.x >> 5;
  const int t0 = tq * 32;
  const int tid = threadIdx.x, tx = tid & 15, ty = tid >> 4;
  const float* hbuf = ws + HBUF_OFF;
  const float* CTX = ws + CTX_OFF;
  __shared__ float Ft[32][18];
  __shared__ float WtT[16][132];
  __shared__ float lg[32][130];
  float acc[2][8];
#pragma unroll
  for (int i = 0; i < 2; ++i)
#pragma unroll
    for (int jj = 0; jj < 8; ++jj) acc[i][jj] = 0.f;

  const int fr = tid >> 2, fc = (tid & 3) * 4;
  const int we = tid >> 1, wc = (tid & 1) * 8;
  for (int kt = 0; kt < 128; ++kt) {
    const int k0 = kt * 16;
    float4 fv = make_float4(0,0,0,0);
    if (tid < 128) {
      const int kk = k0 + fc;
      const float* src = (kk < 1024)
        ? hbuf + (size_t)(t0 + fr + 1) * HSTEP + (size_t)b * HD + kk
        : CTX + ((size_t)b * LL + t0 + fr) * HD + (kk - 1024);
      fv = *reinterpret_cast<const float4*>(src);
    }
    const float* wsrc = Wout + (size_t)we * (2*HD) + k0 + wc;
    float4 w0 = *reinterpret_cast<const float4*>(wsrc);
    float4 w1 = *reinterpret_cast<const float4*>(wsrc + 4);
    __syncthreads();
    if (tid < 128) *reinterpret_cast<float4*>(&Ft[fr][fc]) = fv;
    WtT[wc+0][we] = w0.x; WtT[wc+1][we] = w0.y; WtT[wc+2][we] = w0.z; WtT[wc+3][we] = w0.w;
    WtT[wc+4][we] = w1.x; WtT[wc+5][we] = w1.y; WtT[wc+6][we] = w1.z; WtT[wc+7][we] = w1.w;
    __syncthreads();
#pragma unroll
    for (int kk2 = 0; kk2 < 8; ++kk2) {
      float2 av[2];
      av[0] = *reinterpret_cast<const float2*>(&Ft[ty*2][kk2*2]);
      av[1] = *reinterpret_cast<const float2*>(&Ft[ty*2 + 1][kk2*2]);
      float4 b00 = *reinterpret_cast<const float4*>(&WtT[kk2*2][tx*8]);
      float4 b01 = *reinterpret_cast<const float4*>(&WtT[kk2*2][tx*8 + 4]);
      float4 b10 = *reinterpret_cast<const float4*>(&WtT[kk2*2+1][tx*8]);
      float4 b11 = *reinterpret_cast<const float4*>(&WtT[kk2*2+1][tx*8 + 4]);
#pragma unroll
      for (int i = 0; i < 2; ++i) {
        acc[i][0] += av[i].x*b00.x + av[i].y*b10.x;
        acc[i][1] += av[i].x*b00.y + av[i].y*b10.y;
        acc[i][2] += av[i].x*b00.z + av[i].y*b10.z;
        acc[i][3] += av[i].x*b00.w + av[i].y*b10.w;
        acc[i][4] += av[i].x*b01.x + av[i].y*b11.x;
        acc[i][5] += av[i].x*b01.y + av[i].y*b11.y;
        acc[i][6] += av[i].x*b01.z + av[i].y*b11.z;
        acc[i][7] += av[i].x*b01.w + av[i].y*b11.w;
      }
    }
  }
#pragma unroll
  for (int i = 0; i < 2; ++i)
#pragma unroll
    for (int jj = 0; jj < 8; ++jj)
      lg[ty*2 + i][tx*8 + jj] = acc[i][jj] + bout[tx*8 + jj];
  __syncthreads();
  const int w = tid >> 6, lane = tid & 63;
#pragma unroll
  for (int rr = 0; rr < 8; ++rr) {
    const int row = w * 8 + rr;
    float v0 = lg[row][lane], v1 = lg[row][lane + 64];
    float mx = fmaxf(v0, v1);
#pragma unroll
    for (int o = 32; o > 0; o >>= 1) mx = fmaxf(mx, __shfl_xor(mx, o));
    float sm = __expf(v0 - mx) + __expf(v1 - mx);
#pragma unroll
    for (int o = 32; o > 0; o >>= 1) sm += __shfl_xor(sm, o);
    float lse = mx + __logf(sm);
    float* op = out + ((size_t)b * LL + t0 + row) * ED;
    op[lane]      = v0 - lse;
    op[lane + 64] = v1 - lse;
  }
}

extern "C" void kernel_launch(void* const* d_in, const int* in_sizes, int n_in,
                              void* d_out, int out_size, void* d_ws, size_t ws_size,
                              hipStream_t stream) {
  (void)in_sizes; (void)n_in; (void)out_size; (void)ws_size;
  const float* ctxt = (const float*)d_in[0];
  const float* gt   = (const float*)d_in[1];
  const float* Wih  = (const float*)d_in[2];
  const float* Whh  = (const float*)d_in[3];
  const float* bih  = (const float*)d_in[4];
  const float* bhh  = (const float*)d_in[5];
  const float* Wout = (const float*)d_in[6];
  const float* bout = (const float*)d_in[7];
  float* out = (float*)d_out;
  float* ws  = (float*)d_ws;

  hipMemsetAsync(ws + HBUF_OFF, 0, (size_t)HSTEP * sizeof(float), stream);     // h_0 = 0
  hipMemsetAsync(ws + ARR_OFF, 0, (8192 + 64) * sizeof(float), stream);        // arr + rel

  base_kernel<<<(BATCH * GD) / 256, 256, 0, stream>>>(ctxt, Wih, bih, bhh, ws);
  phase0_wordg<<<1024, 256, 0, stream>>>(gt, Wih, ws);
  whh16_kernel<<<(GD * HD / 8) / 256, 256, 0, stream>>>(Whh, ws);

  static int smem_set = 0;
  if (!smem_set) {
    (void)hipFuncSetAttribute((const void*)&phaseA,
                              hipFuncAttributeMaxDynamicSharedMemorySize, 65536);
    smem_set = 1;
  }
  void* argsA[] = { (void*)&ws };
  (void)hipLaunchCooperativeKernel((const void*)&phaseA, dim3(256), dim3(1024),
                                   argsA, 65536, stream);

  b1_energy<<<256, 256, 0, stream>>>(ctxt, ws);
  b2_softmax<<<32, 1024, 0, stream>>>(ws);
  b3_ctx<<<256, 256, 0, stream>>>(ctxt, ws);
  b4_logits<<<128, 256, 0, stream>>>(Wout, bout, ws, out);
}

// Round 10
// 1537.123 us; speedup vs baseline: 15.9899x; 1.1582x over previous
//
#include <hip/hip_runtime.h>

#define BATCH 32
#define TENC  1024
#define HD    1024
#define ED    128
#define LL    128
#define GD    4096
#define IND   1152
#define HSTEP (BATCH*HD)

// ws float offsets
#define HBUF_OFF 131072                       // base: [0, 131072)
#define ARR_OFF  (HBUF_OFF + 129*HSTEP)       // h ring [129][32][1024] f32
#define REL_OFF  (ARR_OFF + 8192)             // arrival flags: 256 x 128B
#define E_OFF    (REL_OFF + 64)               // release word (padded)
#define P_OFF    (E_OFF + BATCH*LL*TENC)
#define CTX_OFF  (P_OFF + BATCH*LL*TENC)
#define W16_OFF  CTX_OFF                      // Whh f16 (8.4MB), dead after phaseA
// wordg bf16 (16.8MB) occupies [E_OFF, E_OFF+8.4M fl) until phaseA ends.
// After phaseA: E f32 at E_OFF, P16 at P_OFF, ctx16 at CTX_OFF (overlays W16).

typedef _Float16 h16x2 __attribute__((ext_vector_type(2)));   // for fdot2
typedef __fp16   f16x2 __attribute__((ext_vector_type(2)));   // cvt_pkrtz result
union CVT { f16x2 f; h16x2 h; unsigned u; };

__device__ __forceinline__ unsigned pk16(float x, float y) {
  CVT c; c.f = __builtin_amdgcn_cvt_pkrtz(x, y); return c.u;
}
__device__ __forceinline__ float dd2(unsigned a, unsigned b, float c) {
  CVT x{.u = a}, y{.u = b};
  return __builtin_amdgcn_fdot2(x.h, y.h, c, false);
}
__device__ __forceinline__ float sigf(float x) {
  return __builtin_amdgcn_rcpf(1.0f + __expf(-x));
}
__device__ __forceinline__ float tanhf_fast(float x) {
  return 1.0f - 2.0f * __builtin_amdgcn_rcpf(1.0f + __expf(2.0f * x));
}
__device__ __forceinline__ unsigned bfrne(float f) {       // f32 -> bf16 RNE
  unsigned v = __float_as_uint(f);
  return (v + 0x7fffu + ((v >> 16) & 1u)) >> 16;
}
__device__ __forceinline__ float bf2f(unsigned short u) {
  return __uint_as_float(((unsigned)u) << 16);
}
__device__ __forceinline__ void cstf(float* p, float v) {
  __hip_atomic_store(p, v, __ATOMIC_RELAXED, __HIP_MEMORY_SCOPE_AGENT);
}
__device__ __forceinline__ void cstu(unsigned* p, unsigned v) {
  __hip_atomic_store(p, v, __ATOMIC_RELAXED, __HIP_MEMORY_SCOPE_AGENT);
}
__device__ __forceinline__ unsigned cldu(const unsigned* p) {
  return __hip_atomic_load(p, __ATOMIC_RELAXED, __HIP_MEMORY_SCOPE_AGENT);
}
__device__ __forceinline__ float dot4h(uint2 hv, uint2 wv, float a) {
  a = dd2(hv.x, wv.x, a);
  a = dd2(hv.y, wv.y, a);
  return a;
}

// base[b][g] = b_ih[g]+b_hh[g]+dot(ctx0[b], W_ih[g][E:])
__global__ __launch_bounds__(256) void base_kernel(
    const float* __restrict__ ctxt, const float* __restrict__ Wih,
    const float* __restrict__ bih, const float* __restrict__ bhh,
    float* __restrict__ base) {
  int id = blockIdx.x * 256 + threadIdx.x;
  int b = id & (BATCH - 1);
  int g = id >> 5;
  const float4* c4 = reinterpret_cast<const float4*>(ctxt + (size_t)b * TENC * HD);
  const float4* w4 = reinterpret_cast<const float4*>(Wih + (size_t)g * IND + ED);
  float a = 0.f;
#pragma unroll 8
  for (int kk = 0; kk < HD/4; ++kk) {
    float4 c = c4[kk], w = w4[kk];
    a += c.x*w.x + c.y*w.y + c.z*w.z + c.w*w.w;
  }
  base[(size_t)b * GD + g] = a + bih[g] + bhh[g];
}

// Whh f32 -> f16 (RTZ pack), 8 elements/thread
__global__ __launch_bounds__(256) void whh16_kernel(
    const float* __restrict__ Whh, float* __restrict__ ws) {
  unsigned short* W16 = reinterpret_cast<unsigned short*>(ws + W16_OFF);
  size_t i = ((size_t)blockIdx.x * 256 + threadIdx.x) * 8;
  float4 a = *reinterpret_cast<const float4*>(Whh + i);
  float4 b = *reinterpret_cast<const float4*>(Whh + i + 4);
  uint4 o;
  o.x = pk16(a.x, a.y);
  o.y = pk16(a.z, a.w);
  o.z = pk16(b.x, b.y);
  o.w = pk16(b.z, b.w);
  *reinterpret_cast<uint4*>(W16 + i) = o;
}

// ---------------- Phase 0: wordg[t][row][b] = word_t[b] . Wih[row][0:128] (bf16) ----------------
__global__ __launch_bounds__(256) void phase0_wordg(
    const float* __restrict__ gt, const float* __restrict__ Wih,
    float* __restrict__ ws) {
  const int mt = blockIdx.x & 31, nt = blockIdx.x >> 5;
  const int r0 = mt * 128, n0 = nt * 128;
  const int tid = threadIdx.x, tx = tid & 15, ty = tid >> 4;
  unsigned short* wg = reinterpret_cast<unsigned short*>(ws + E_OFF);
  __shared__ float At[128][18];
  __shared__ float BtT[16][132];
  float acc[8][8];
#pragma unroll
  for (int i = 0; i < 8; ++i)
#pragma unroll
    for (int j = 0; j < 8; ++j) acc[i][j] = 0.f;

  const int sr = tid >> 1, sc = (tid & 1) * 8;
  for (int kt = 0; kt < 8; ++kt) {
    const int k0 = kt * 16;
    const float* ap = Wih + (size_t)(r0 + sr) * IND + k0 + sc;
    float4 a0 = *reinterpret_cast<const float4*>(ap);
    float4 a1 = *reinterpret_cast<const float4*>(ap + 4);
    const int n = n0 + sr, t = n >> 5, bb = n & 31;
    float4 b0, b1;
    if (t == 0) {
      b0 = make_float4((k0 + sc == 0) ? 1.f : 0.f, 0.f, 0.f, 0.f);
      b1 = make_float4(0.f, 0.f, 0.f, 0.f);
    } else {
      const float* bp = gt + ((size_t)bb * LL + (t - 1)) * ED + k0 + sc;
      b0 = *reinterpret_cast<const float4*>(bp);
      b1 = *reinterpret_cast<const float4*>(bp + 4);
    }
    __syncthreads();
    *reinterpret_cast<float4*>(&At[sr][sc]) = a0;
    *reinterpret_cast<float4*>(&At[sr][sc + 4]) = a1;
    BtT[sc+0][sr] = b0.x; BtT[sc+1][sr] = b0.y; BtT[sc+2][sr] = b0.z; BtT[sc+3][sr] = b0.w;
    BtT[sc+4][sr] = b1.x; BtT[sc+5][sr] = b1.y; BtT[sc+6][sr] = b1.z; BtT[sc+7][sr] = b1.w;
    __syncthreads();
#pragma unroll
    for (int kk2 = 0; kk2 < 8; ++kk2) {
      float2 av[8];
#pragma unroll
      for (int i = 0; i < 8; ++i)
        av[i] = *reinterpret_cast<const float2*>(&At[ty*8 + i][kk2*2]);
      float4 c00 = *reinterpret_cast<const float4*>(&BtT[kk2*2][tx*8]);
      float4 c01 = *reinterpret_cast<const float4*>(&BtT[kk2*2][tx*8 + 4]);
      float4 c10 = *reinterpret_cast<const float4*>(&BtT[kk2*2+1][tx*8]);
      float4 c11 = *reinterpret_cast<const float4*>(&BtT[kk2*2+1][tx*8 + 4]);
#pragma unroll
      for (int i = 0; i < 8; ++i) {
        acc[i][0] += av[i].x*c00.x + av[i].y*c10.x;
        acc[i][1] += av[i].x*c00.y + av[i].y*c10.y;
        acc[i][2] += av[i].x*c00.z + av[i].y*c10.z;
        acc[i][3] += av[i].x*c00.w + av[i].y*c10.w;
        acc[i][4] += av[i].x*c01.x + av[i].y*c11.x;
        acc[i][5] += av[i].x*c01.y + av[i].y*c11.y;
        acc[i][6] += av[i].x*c01.z + av[i].y*c11.z;
        acc[i][7] += av[i].x*c01.w + av[i].y*c11.w;
      }
    }
  }
  const int nb = n0 + tx * 8, t = nb >> 5, b0i = nb & 31;
#pragma unroll
  for (int i = 0; i < 8; ++i) {
    const int row = r0 + ty * 8 + i;
    uint4 pk;
    pk.x = bfrne(acc[i][0]) | (bfrne(acc[i][1]) << 16);
    pk.y = bfrne(acc[i][2]) | (bfrne(acc[i][3]) << 16);
    pk.z = bfrne(acc[i][4]) | (bfrne(acc[i][5]) << 16);
    pk.w = bfrne(acc[i][6]) | (bfrne(acc[i][7]) << 16);
    *reinterpret_cast<uint4*>(wg + ((size_t)t * GD + row) * 32 + b0i) = pk;
  }
}

// ---------------- Phase A: recurrence (f16 dot2, flag barrier) — unchanged from R9 ----------------
__global__ __launch_bounds__(1024, 4) void phaseA(float* __restrict__ ws) {
  const int rg = blockIdx.x;
  const int tid = threadIdx.x;
  const int lane = tid & 63;
  const int w = tid >> 6;
  const int rq = w & 3, bq = w >> 2;
  const int j = rg * 4 + rq;
  const int lb = lane & 3;
  float* base = ws;
  float* hbuf = ws + HBUF_OFF;
  unsigned* arr = reinterpret_cast<unsigned*>(ws + ARR_OFF);
  unsigned* rel = reinterpret_cast<unsigned*>(ws + REL_OFF);
  const unsigned short* wg = reinterpret_cast<const unsigned short*>(ws + E_OFF);
  const uint2* W16 = reinterpret_cast<const uint2*>(ws + W16_OFF);

  extern __shared__ uint2 h_lds[];   // 64 KB: h[k] as f16[32][1024]

  uint2 Wr[4][4];
#pragma unroll
  for (int g = 0; g < 4; ++g)
#pragma unroll
    for (int t = 0; t < 4; ++t)
      Wr[g][t] = W16[(size_t)(g * HD + j) * 256 + lane + 64 * t];

  float bs[4][2];
#pragma unroll
  for (int g = 0; g < 4; ++g)
#pragma unroll
    for (int hf = 0; hf < 2; ++hf)
      bs[g][hf] = base[(size_t)(bq * 8 + hf * 4 + lb) * GD + g * HD + j];

  float c0 = 0.f, c1 = 0.f;

  for (int k = 0; k < LL; ++k) {
    {
      const float4* src = reinterpret_cast<const float4*>(hbuf + (size_t)k * HSTEP);
      float4 sv[8];
#pragma unroll
      for (int i = 0; i < 8; ++i) sv[i] = src[tid + 1024 * i];
#pragma unroll
      for (int i = 0; i < 8; ++i) {
        uint2 c;
        c.x = pk16(sv[i].x, sv[i].y);
        c.y = pk16(sv[i].z, sv[i].w);
        h_lds[tid + 1024 * i] = c;
      }
    }
    __syncthreads();

#pragma unroll
    for (int hf = 0; hf < 2; ++hf) {
      float acc[4][4];
#pragma unroll
      for (int g = 0; g < 4; ++g)
#pragma unroll
        for (int bi = 0; bi < 4; ++bi) acc[g][bi] = 0.f;

#pragma unroll
      for (int bi = 0; bi < 4; ++bi) {
        const int b = bq * 8 + hf * 4 + bi;
        const uint2* hb = h_lds + b * 256;
        uint2 h0 = hb[lane], h1 = hb[lane + 64];
        uint2 h2 = hb[lane + 128], h3 = hb[lane + 192];
#pragma unroll
        for (int g = 0; g < 4; ++g) {
          float a = acc[g][bi];
          a = dot4h(h0, Wr[g][0], a);
          a = dot4h(h1, Wr[g][1], a);
          a = dot4h(h2, Wr[g][2], a);
          a = dot4h(h3, Wr[g][3], a);
          acc[g][bi] = a;
        }
      }
      const bool p1 = (lane & 1), p2 = (lane & 2);
      float s[4];
#pragma unroll
      for (int g = 0; g < 4; ++g) {
        float send0 = p1 ? acc[g][0] : acc[g][1];
        float keep0 = p1 ? acc[g][1] : acc[g][0];
        float r0 = keep0 + __shfl_xor(send0, 1);
        float send1 = p1 ? acc[g][2] : acc[g][3];
        float keep1 = p1 ? acc[g][3] : acc[g][2];
        float r1 = keep1 + __shfl_xor(send1, 1);
        float send2 = p2 ? r0 : r1;
        float keep2 = p2 ? r1 : r0;
        float sg = keep2 + __shfl_xor(send2, 2);
        sg += __shfl_xor(sg, 4);
        sg += __shfl_xor(sg, 8);
        sg += __shfl_xor(sg, 16);
        sg += __shfl_xor(sg, 32);
        s[g] = sg;
      }
      const int bmine = bq * 8 + hf * 4 + lb;
      float wv0 = bf2f(wg[((size_t)k * GD + 0 * HD + j) * 32 + bmine]);
      float wv1 = bf2f(wg[((size_t)k * GD + 1 * HD + j) * 32 + bmine]);
      float wv2 = bf2f(wg[((size_t)k * GD + 2 * HD + j) * 32 + bmine]);
      float wv3 = bf2f(wg[((size_t)k * GD + 3 * HD + j) * 32 + bmine]);
      float ig = sigf(s[0] + wv0 + bs[0][hf]);
      float fg = sigf(s[1] + wv1 + bs[1][hf]);
      float gg = tanhf_fast(s[2] + wv2 + bs[2][hf]);
      float og = sigf(s[3] + wv3 + bs[3][hf]);
      float cr = hf ? c1 : c0;
      cr = fg * cr + ig * gg;
      if (hf) c1 = cr; else c0 = cr;
      if (lane < 4)
        cstf(hbuf + (size_t)(k + 1) * HSTEP + (size_t)bmine * HD + j,
             og * tanhf_fast(cr));
    }

    if (k < LL - 1) {
      __syncthreads();
      const unsigned tgt = (unsigned)(k + 1);
      if (tid == 0) cstu(arr + rg * 32, tgt);
      if (rg == 0 && tid < 64) {
        int ok;
        do {
          ok = 1;
#pragma unroll
          for (int q = 0; q < 4; ++q) {
            unsigned v = cldu(arr + (lane * 4 + q) * 32);
            ok &= (v >= tgt);
          }
        } while (!__all(ok));
        if (tid == 0) cstu(rel, tgt);
      } else if (rg != 0 && tid == 0) {
        while (cldu(rel) < tgt) __builtin_amdgcn_s_sleep(1);
      }
      __syncthreads();
    }
  }
}

// ---------------- Phase B1: E[b][t][p] = sum_d H[t][d] C[p][d] (f16 dot2) ----------------
// 512 blocks: b = blk>>4, pt = blk&15 (64-p tile). 256 thr: acc[8 t][4 p].
__global__ __launch_bounds__(256) void b1_energy(
    const float* __restrict__ ctxt, float* __restrict__ ws) {
  const int b = blockIdx.x >> 4, pt = blockIdx.x & 15;
  const int p0 = pt * 64;
  const int tid = threadIdx.x, tx = tid & 15, ty = tid >> 4;
  const float* hbuf = ws + HBUF_OFF;
  float* E = ws + E_OFF;
  __shared__ unsigned At[128][8];    // A pairs along d
  __shared__ unsigned CtT[8][64];    // B^T: [d-pair][p]
  float acc[8][4];
#pragma unroll
  for (int i = 0; i < 8; ++i)
#pragma unroll
    for (int j = 0; j < 4; ++j) acc[i][j] = 0.f;

  const int ar = tid >> 1, ah = tid & 1;
  const int cr = tid >> 2, cq = tid & 3;
  for (int kt = 0; kt < 64; ++kt) {
    const int k0 = kt * 16;
    const float* hs = hbuf + (size_t)(ar + 1) * HSTEP + (size_t)b * HD + k0 + ah * 8;
    float4 f0 = *reinterpret_cast<const float4*>(hs);
    float4 f1 = *reinterpret_cast<const float4*>(hs + 4);
    const float* cs = ctxt + ((size_t)b * TENC + p0 + cr) * HD + k0 + cq * 4;
    float4 g = *reinterpret_cast<const float4*>(cs);
    __syncthreads();
    uint4 u;
    u.x = pk16(f0.x, f0.y); u.y = pk16(f0.z, f0.w);
    u.z = pk16(f1.x, f1.y); u.w = pk16(f1.z, f1.w);
    *reinterpret_cast<uint4*>(&At[ar][ah * 4]) = u;
    CtT[2*cq][cr]   = pk16(g.x, g.y);
    CtT[2*cq+1][cr] = pk16(g.z, g.w);
    __syncthreads();
#pragma unroll
    for (int kk2 = 0; kk2 < 4; ++kk2) {
      uint2 av[8];
#pragma unroll
      for (int i = 0; i < 8; ++i)
        av[i] = *reinterpret_cast<const uint2*>(&At[ty*8 + i][kk2*2]);
      uint4 cA = *reinterpret_cast<const uint4*>(&CtT[2*kk2][tx*4]);
      uint4 cB = *reinterpret_cast<const uint4*>(&CtT[2*kk2+1][tx*4]);
#pragma unroll
      for (int i = 0; i < 8; ++i) {
        acc[i][0] = dd2(av[i].y, cB.x, dd2(av[i].x, cA.x, acc[i][0]));
        acc[i][1] = dd2(av[i].y, cB.y, dd2(av[i].x, cA.y, acc[i][1]));
        acc[i][2] = dd2(av[i].y, cB.z, dd2(av[i].x, cA.z, acc[i][2]));
        acc[i][3] = dd2(av[i].y, cB.w, dd2(av[i].x, cA.w, acc[i][3]));
      }
    }
  }
#pragma unroll
  for (int i = 0; i < 8; ++i) {
    float* ep = E + ((size_t)b * LL + ty*8 + i) * TENC + p0 + tx*4;
    *reinterpret_cast<float4*>(ep) = make_float4(acc[i][0], acc[i][1], acc[i][2], acc[i][3]);
  }
}

// ---------------- Phase B2: row softmax E(f32) -> P16 ----------------
// 256 blocks: b = blk>>3, tc = blk&7; 16 waves, 1 row each.
__global__ __launch_bounds__(1024) void b2_softmax(float* __restrict__ ws) {
  const int b = blockIdx.x >> 3, tc = blockIdx.x & 7;
  const int w = threadIdx.x >> 6, lane = threadIdx.x & 63;
  const int t = tc * 16 + w;
  const float* E = ws + E_OFF;
  unsigned* P16 = reinterpret_cast<unsigned*>(ws + P_OFF);
  const float4* e4 = reinterpret_cast<const float4*>(E + ((size_t)b * LL + t) * TENC);
  float4 v[4];
#pragma unroll
  for (int c = 0; c < 4; ++c) v[c] = e4[c * 64 + lane];
  float m = fmaxf(fmaxf(fmaxf(v[0].x, v[0].y), fmaxf(v[0].z, v[0].w)),
                  fmaxf(fmaxf(v[1].x, v[1].y), fmaxf(v[1].z, v[1].w)));
  m = fmaxf(m, fmaxf(fmaxf(fmaxf(v[2].x, v[2].y), fmaxf(v[2].z, v[2].w)),
                     fmaxf(fmaxf(v[3].x, v[3].y), fmaxf(v[3].z, v[3].w))));
#pragma unroll
  for (int o = 32; o > 0; o >>= 1) m = fmaxf(m, __shfl_xor(m, o));
  float s = 0.f;
#pragma unroll
  for (int c = 0; c < 4; ++c) {
    v[c].x = __expf(v[c].x - m); v[c].y = __expf(v[c].y - m);
    v[c].z = __expf(v[c].z - m); v[c].w = __expf(v[c].w - m);
    s += v[c].x + v[c].y + v[c].z + v[c].w;
  }
#pragma unroll
  for (int o = 32; o > 0; o >>= 1) s += __shfl_xor(s, o);
  float inv = __builtin_amdgcn_rcpf(s);
  uint2* p2 = reinterpret_cast<uint2*>(P16 + ((size_t)b * LL + t) * 512);
#pragma unroll
  for (int c = 0; c < 4; ++c) {
    uint2 o2;
    o2.x = pk16(v[c].x * inv, v[c].y * inv);
    o2.y = pk16(v[c].z * inv, v[c].w * inv);
    p2[c * 64 + lane] = o2;
  }
}

// ---------------- Phase B3: CTX16[b][t][d] = sum_p P[t][p] C[p][d] (f16 dot2) ----------------
// 512 blocks: b = blk>>4, dt = blk&15 (64-d tile). acc[8 t][4 d].
__global__ __launch_bounds__(256) void b3_ctx(
    const float* __restrict__ ctxt, float* __restrict__ ws) {
  const int b = blockIdx.x >> 4, dt = blockIdx.x & 15;
  const int d0 = dt * 64;
  const int tid = threadIdx.x, tx = tid & 15, ty = tid >> 4;
  const unsigned* P16 = reinterpret_cast<const unsigned*>(ws + P_OFF);
  unsigned* ctx16 = reinterpret_cast<unsigned*>(ws + CTX_OFF);
  __shared__ unsigned At[128][8];    // P pairs along p
  __shared__ unsigned CdT[8][64];    // [p-pair][d]
  float acc[8][4];
#pragma unroll
  for (int i = 0; i < 8; ++i)
#pragma unroll
    for (int j = 0; j < 4; ++j) acc[i][j] = 0.f;

  const int ar = tid >> 1, ah = tid & 1;
  const int cq = tid >> 5, cd = (tid & 31) * 2;
  for (int kt = 0; kt < 64; ++kt) {
    const int k0 = kt * 16;
    uint4 pa = *reinterpret_cast<const uint4*>(
        P16 + ((size_t)b * LL + ar) * 512 + kt * 8 + ah * 4);
    float2 r0 = *reinterpret_cast<const float2*>(
        ctxt + ((size_t)b * TENC + k0 + 2*cq) * HD + d0 + cd);
    float2 r1 = *reinterpret_cast<const float2*>(
        ctxt + ((size_t)b * TENC + k0 + 2*cq + 1) * HD + d0 + cd);
    __syncthreads();
    *reinterpret_cast<uint4*>(&At[ar][ah * 4]) = pa;
    uint2 w2;
    w2.x = pk16(r0.x, r1.x);
    w2.y = pk16(r0.y, r1.y);
    *reinterpret_cast<uint2*>(&CdT[cq][cd]) = w2;
    __syncthreads();
#pragma unroll
    for (int kk2 = 0; kk2 < 4; ++kk2) {
      uint2 av[8];
#pragma unroll
      for (int i = 0; i < 8; ++i)
        av[i] = *reinterpret_cast<const uint2*>(&At[ty*8 + i][kk2*2]);
      uint4 cA = *reinterpret_cast<const uint4*>(&CdT[2*kk2][tx*4]);
      uint4 cB = *reinterpret_cast<const uint4*>(&CdT[2*kk2+1][tx*4]);
#pragma unroll
      for (int i = 0; i < 8; ++i) {
        acc[i][0] = dd2(av[i].y, cB.x, dd2(av[i].x, cA.x, acc[i][0]));
        acc[i][1] = dd2(av[i].y, cB.y, dd2(av[i].x, cA.y, acc[i][1]));
        acc[i][2] = dd2(av[i].y, cB.z, dd2(av[i].x, cA.z, acc[i][2]));
        acc[i][3] = dd2(av[i].y, cB.w, dd2(av[i].x, cA.w, acc[i][3]));
      }
    }
  }
#pragma unroll
  for (int i = 0; i < 8; ++i) {
    uint2 o2;
    o2.x = pk16(acc[i][0], acc[i][1]);
    o2.y = pk16(acc[i][2], acc[i][3]);
    *reinterpret_cast<uint2*>(
        ctx16 + ((size_t)b * LL + ty*8 + i) * 512 + (d0 + tx*4) / 2) = o2;
  }
}

// ---------------- Phase B4: logits + log-softmax (f16 dot2) ----------------
// 256 blocks: b = blk>>3, tq = blk&7 (16-t tile). acc[2 t][4 e], tx 0..31.
__global__ __launch_bounds__(256) void b4_logits(
    const float* __restrict__ Wout, const float* __restrict__ bout,
    const float* __restrict__ ws, float* __restrict__ out) {
  const int b = blockIdx.x >> 3, tq = blockIdx.x & 7;
  const int t0 = tq * 16;
  const int tid = threadIdx.x, tx = tid & 31, ty = tid >> 5;
  const float* hbuf = ws + HBUF_OFF;
  const unsigned* ctx16 = reinterpret_cast<const unsigned*>(ws + CTX_OFF);
  __shared__ unsigned At[16][8];
  __shared__ unsigned WtT[8][128];
  __shared__ float lg[16][132];
  float acc[2][4];
#pragma unroll
  for (int i = 0; i < 2; ++i)
#pragma unroll
    for (int j = 0; j < 4; ++j) acc[i][j] = 0.f;

  const int wr = tid >> 1, wh = tid & 1;
  for (int kt = 0; kt < 128; ++kt) {
    const int k0 = kt * 16;
    unsigned au = 0;
    if (tid < 128) {
      const int r = tid >> 3, k = k0 + (tid & 7) * 2;
      if (k < 1024) {
        float2 f = *reinterpret_cast<const float2*>(
            hbuf + (size_t)(t0 + r + 1) * HSTEP + (size_t)b * HD + k);
        au = pk16(f.x, f.y);
      } else {
        au = ctx16[((size_t)b * LL + t0 + r) * 512 + (k - 1024) / 2];
      }
    }
    const float* wsrc = Wout + (size_t)wr * (2*HD) + k0 + wh * 8;
    float4 w0 = *reinterpret_cast<const float4*>(wsrc);
    float4 w1 = *reinterpret_cast<const float4*>(wsrc + 4);
    __syncthreads();
    if (tid < 128) At[tid >> 3][tid & 7] = au;
    WtT[wh*4+0][wr] = pk16(w0.x, w0.y);
    WtT[wh*4+1][wr] = pk16(w0.z, w0.w);
    WtT[wh*4+2][wr] = pk16(w1.x, w1.y);
    WtT[wh*4+3][wr] = pk16(w1.z, w1.w);
    __syncthreads();
#pragma unroll
    for (int kk2 = 0; kk2 < 4; ++kk2) {
      uint2 av[2];
#pragma unroll
      for (int i = 0; i < 2; ++i)
        av[i] = *reinterpret_cast<const uint2*>(&At[ty*2 + i][kk2*2]);
      uint4 cA = *reinterpret_cast<const uint4*>(&WtT[2*kk2][tx*4]);
      uint4 cB = *reinterpret_cast<const uint4*>(&WtT[2*kk2+1][tx*4]);
#pragma unroll
      for (int i = 0; i < 2; ++i) {
        acc[i][0] = dd2(av[i].y, cB.x, dd2(av[i].x, cA.x, acc[i][0]));
        acc[i][1] = dd2(av[i].y, cB.y, dd2(av[i].x, cA.y, acc[i][1]));
        acc[i][2] = dd2(av[i].y, cB.z, dd2(av[i].x, cA.z, acc[i][2]));
        acc[i][3] = dd2(av[i].y, cB.w, dd2(av[i].x, cA.w, acc[i][3]));
      }
    }
  }
#pragma unroll
  for (int i = 0; i < 2; ++i)
#pragma unroll
    for (int j = 0; j < 4; ++j)
      lg[ty*2 + i][tx*4 + j] = acc[i][j] + bout[tx*4 + j];
  __syncthreads();
  const int w = tid >> 6, lane = tid & 63;
#pragma unroll
  for (int rr = 0; rr < 4; ++rr) {
    const int row = w * 4 + rr;
    float v0 = lg[row][lane], v1 = lg[row][lane + 64];
    float mx = fmaxf(v0, v1);
#pragma unroll
    for (int o = 32; o > 0; o >>= 1) mx = fmaxf(mx, __shfl_xor(mx, o));
    float sm = __expf(v0 - mx) + __expf(v1 - mx);
#pragma unroll
    for (int o = 32; o > 0; o >>= 1) sm += __shfl_xor(sm, o);
    float lse = mx + __logf(sm);
    float* op = out + ((size_t)b * LL + t0 + row) * ED;
    op[lane]      = v0 - lse;
    op[lane + 64] = v1 - lse;
  }
}

extern "C" void kernel_launch(void* const* d_in, const int* in_sizes, int n_in,
                              void* d_out, int out_size, void* d_ws, size_t ws_size,
                              hipStream_t stream) {
  (void)in_sizes; (void)n_in; (void)out_size; (void)ws_size;
  const float* ctxt = (const float*)d_in[0];
  const float* gt   = (const float*)d_in[1];
  const float* Wih  = (const float*)d_in[2];
  const float* Whh  = (const float*)d_in[3];
  const float* bih  = (const float*)d_in[4];
  const float* bhh  = (const float*)d_in[5];
  const float* Wout = (const float*)d_in[6];
  const float* bout = (const float*)d_in[7];
  float* out = (float*)d_out;
  float* ws  = (float*)d_ws;

  hipMemsetAsync(ws + HBUF_OFF, 0, (size_t)HSTEP * sizeof(float), stream);     // h_0 = 0
  hipMemsetAsync(ws + ARR_OFF, 0, (8192 + 64) * sizeof(float), stream);        // arr + rel

  base_kernel<<<(BATCH * GD) / 256, 256, 0, stream>>>(ctxt, Wih, bih, bhh, ws);
  phase0_wordg<<<1024, 256, 0, stream>>>(gt, Wih, ws);
  whh16_kernel<<<(GD * HD / 8) / 256, 256, 0, stream>>>(Whh, ws);

  static int smem_set = 0;
  if (!smem_set) {
    (void)hipFuncSetAttribute((const void*)&phaseA,
                              hipFuncAttributeMaxDynamicSharedMemorySize, 65536);
    smem_set = 1;
  }
  void* argsA[] = { (void*)&ws };
  (void)hipLaunchCooperativeKernel((const void*)&phaseA, dim3(256), dim3(1024),
                                   argsA, 65536, stream);

  b1_energy<<<512, 256, 0, stream>>>(ctxt, ws);
  b2_softmax<<<256, 1024, 0, stream>>>(ws);
  b3_ctx<<<512, 256, 0, stream>>>(ctxt, ws);
  b4_logits<<<256, 256, 0, stream>>>(Wout, bout, ws, out);
}

// Round 11
// 1501.253 us; speedup vs baseline: 16.3720x; 1.0239x over previous
//
#include <hip/hip_runtime.h>

#define BATCH 32
#define TENC  1024
#define HD    1024
#define ED    128
#define LL    128
#define GD    4096
#define IND   1152
#define HSTEP (BATCH*HD)

// ws float offsets
#define HBUF_OFF 131072                       // base: [0, 131072)
#define ARR_OFF  (HBUF_OFF + 129*HSTEP)       // h ring [129][32][1024] f16 (uses half)
#define REL_OFF  (ARR_OFF + 8192)             // arrival flags: 256 x 128B
#define E_OFF    (REL_OFF + 64)               // (release word unused now)
#define P_OFF    (E_OFF + BATCH*LL*TENC)
#define CTX_OFF  (P_OFF + BATCH*LL*TENC)
#define W16_OFF  CTX_OFF                      // Whh f16 (8.4MB), dead after phaseA
// wordg bf16 (16.8MB) occupies [E_OFF, ...) until phaseA ends.
// After phaseA: E f32 at E_OFF, P16 at P_OFF, ctx16 at CTX_OFF (overlays W16).

typedef _Float16 h16x2 __attribute__((ext_vector_type(2)));   // for fdot2
typedef __fp16   f16x2 __attribute__((ext_vector_type(2)));   // cvt_pkrtz result
union CVT { f16x2 f; h16x2 h; unsigned u; };

__device__ __forceinline__ unsigned pk16(float x, float y) {
  CVT c; c.f = __builtin_amdgcn_cvt_pkrtz(x, y); return c.u;
}
__device__ __forceinline__ float dd2(unsigned a, unsigned b, float c) {
  CVT x{.u = a}, y{.u = b};
  return __builtin_amdgcn_fdot2(x.h, y.h, c, false);
}
__device__ __forceinline__ float sigf(float x) {
  return __builtin_amdgcn_rcpf(1.0f + __expf(-x));
}
__device__ __forceinline__ float tanhf_fast(float x) {
  return 1.0f - 2.0f * __builtin_amdgcn_rcpf(1.0f + __expf(2.0f * x));
}
__device__ __forceinline__ unsigned bfrne(float f) {       // f32 -> bf16 RNE
  unsigned v = __float_as_uint(f);
  return (v + 0x7fffu + ((v >> 16) & 1u)) >> 16;
}
__device__ __forceinline__ float bf2f(unsigned short u) {
  return __uint_as_float(((unsigned)u) << 16);
}
__device__ __forceinline__ void csth(unsigned short* p, unsigned short v) {
  __hip_atomic_store(p, v, __ATOMIC_RELAXED, __HIP_MEMORY_SCOPE_AGENT);
}
__device__ __forceinline__ void cstu(unsigned* p, unsigned v) {
  __hip_atomic_store(p, v, __ATOMIC_RELAXED, __HIP_MEMORY_SCOPE_AGENT);
}
__device__ __forceinline__ unsigned cldu(const unsigned* p) {
  return __hip_atomic_load(p, __ATOMIC_RELAXED, __HIP_MEMORY_SCOPE_AGENT);
}
__device__ __forceinline__ float dot4h(uint2 hv, uint2 wv, float a) {
  a = dd2(hv.x, wv.x, a);
  a = dd2(hv.y, wv.y, a);
  return a;
}

// base[b][g] = b_ih[g]+b_hh[g]+dot(ctx0[b], W_ih[g][E:])
__global__ __launch_bounds__(256) void base_kernel(
    const float* __restrict__ ctxt, const float* __restrict__ Wih,
    const float* __restrict__ bih, const float* __restrict__ bhh,
    float* __restrict__ base) {
  int id = blockIdx.x * 256 + threadIdx.x;
  int b = id & (BATCH - 1);
  int g = id >> 5;
  const float4* c4 = reinterpret_cast<const float4*>(ctxt + (size_t)b * TENC * HD);
  const float4* w4 = reinterpret_cast<const float4*>(Wih + (size_t)g * IND + ED);
  float a = 0.f;
#pragma unroll 8
  for (int kk = 0; kk < HD/4; ++kk) {
    float4 c = c4[kk], w = w4[kk];
    a += c.x*w.x + c.y*w.y + c.z*w.z + c.w*w.w;
  }
  base[(size_t)b * GD + g] = a + bih[g] + bhh[g];
}

// Whh f32 -> f16 (RTZ pack), 8 elements/thread
__global__ __launch_bounds__(256) void whh16_kernel(
    const float* __restrict__ Whh, float* __restrict__ ws) {
  unsigned short* W16 = reinterpret_cast<unsigned short*>(ws + W16_OFF);
  size_t i = ((size_t)blockIdx.x * 256 + threadIdx.x) * 8;
  float4 a = *reinterpret_cast<const float4*>(Whh + i);
  float4 b = *reinterpret_cast<const float4*>(Whh + i + 4);
  uint4 o;
  o.x = pk16(a.x, a.y);
  o.y = pk16(a.z, a.w);
  o.z = pk16(b.x, b.y);
  o.w = pk16(b.z, b.w);
  *reinterpret_cast<uint4*>(W16 + i) = o;
}

// ---------------- Phase 0: wordg[t][row][b] = word_t[b] . Wih[row][0:128] (bf16) ----------------
__global__ __launch_bounds__(256) void phase0_wordg(
    const float* __restrict__ gt, const float* __restrict__ Wih,
    float* __restrict__ ws) {
  const int mt = blockIdx.x & 31, nt = blockIdx.x >> 5;
  const int r0 = mt * 128, n0 = nt * 128;
  const int tid = threadIdx.x, tx = tid & 15, ty = tid >> 4;
  unsigned short* wg = reinterpret_cast<unsigned short*>(ws + E_OFF);
  __shared__ float At[128][18];
  __shared__ float BtT[16][132];
  float acc[8][8];
#pragma unroll
  for (int i = 0; i < 8; ++i)
#pragma unroll
    for (int j = 0; j < 8; ++j) acc[i][j] = 0.f;

  const int sr = tid >> 1, sc = (tid & 1) * 8;
  for (int kt = 0; kt < 8; ++kt) {
    const int k0 = kt * 16;
    const float* ap = Wih + (size_t)(r0 + sr) * IND + k0 + sc;
    float4 a0 = *reinterpret_cast<const float4*>(ap);
    float4 a1 = *reinterpret_cast<const float4*>(ap + 4);
    const int n = n0 + sr, t = n >> 5, bb = n & 31;
    float4 b0, b1;
    if (t == 0) {
      b0 = make_float4((k0 + sc == 0) ? 1.f : 0.f, 0.f, 0.f, 0.f);
      b1 = make_float4(0.f, 0.f, 0.f, 0.f);
    } else {
      const float* bp = gt + ((size_t)bb * LL + (t - 1)) * ED + k0 + sc;
      b0 = *reinterpret_cast<const float4*>(bp);
      b1 = *reinterpret_cast<const float4*>(bp + 4);
    }
    __syncthreads();
    *reinterpret_cast<float4*>(&At[sr][sc]) = a0;
    *reinterpret_cast<float4*>(&At[sr][sc + 4]) = a1;
    BtT[sc+0][sr] = b0.x; BtT[sc+1][sr] = b0.y; BtT[sc+2][sr] = b0.z; BtT[sc+3][sr] = b0.w;
    BtT[sc+4][sr] = b1.x; BtT[sc+5][sr] = b1.y; BtT[sc+6][sr] = b1.z; BtT[sc+7][sr] = b1.w;
    __syncthreads();
#pragma unroll
    for (int kk2 = 0; kk2 < 8; ++kk2) {
      float2 av[8];
#pragma unroll
      for (int i = 0; i < 8; ++i)
        av[i] = *reinterpret_cast<const float2*>(&At[ty*8 + i][kk2*2]);
      float4 c00 = *reinterpret_cast<const float4*>(&BtT[kk2*2][tx*8]);
      float4 c01 = *reinterpret_cast<const float4*>(&BtT[kk2*2][tx*8 + 4]);
      float4 c10 = *reinterpret_cast<const float4*>(&BtT[kk2*2+1][tx*8]);
      float4 c11 = *reinterpret_cast<const float4*>(&BtT[kk2*2+1][tx*8 + 4]);
#pragma unroll
      for (int i = 0; i < 8; ++i) {
        acc[i][0] += av[i].x*c00.x + av[i].y*c10.x;
        acc[i][1] += av[i].x*c00.y + av[i].y*c10.y;
        acc[i][2] += av[i].x*c00.z + av[i].y*c10.z;
        acc[i][3] += av[i].x*c00.w + av[i].y*c10.w;
        acc[i][4] += av[i].x*c01.x + av[i].y*c11.x;
        acc[i][5] += av[i].x*c01.y + av[i].y*c11.y;
        acc[i][6] += av[i].x*c01.z + av[i].y*c11.z;
        acc[i][7] += av[i].x*c01.w + av[i].y*c11.w;
      }
    }
  }
  const int nb = n0 + tx * 8, t = nb >> 5, b0i = nb & 31;
#pragma unroll
  for (int i = 0; i < 8; ++i) {
    const int row = r0 + ty * 8 + i;
    uint4 pk;
    pk.x = bfrne(acc[i][0]) | (bfrne(acc[i][1]) << 16);
    pk.y = bfrne(acc[i][2]) | (bfrne(acc[i][3]) << 16);
    pk.z = bfrne(acc[i][4]) | (bfrne(acc[i][5]) << 16);
    pk.w = bfrne(acc[i][6]) | (bfrne(acc[i][7]) << 16);
    *reinterpret_cast<uint4*>(wg + ((size_t)t * GD + row) * 32 + b0i) = pk;
  }
}

// ---------------- Phase A: recurrence (f16 dot2, f16 h-ring, all-to-all flag barrier) ----------------
__global__ __launch_bounds__(1024, 4) void phaseA(float* __restrict__ ws) {
  const int rg = blockIdx.x;
  const int tid = threadIdx.x;
  const int lane = tid & 63;
  const int w = tid >> 6;
  const int rq = w & 3, bq = w >> 2;
  const int j = rg * 4 + rq;
  const int lb = lane & 3;
  float* base = ws;
  unsigned short* h16 = reinterpret_cast<unsigned short*>(ws + HBUF_OFF);
  unsigned* arr = reinterpret_cast<unsigned*>(ws + ARR_OFF);
  const unsigned short* wg = reinterpret_cast<const unsigned short*>(ws + E_OFF);
  const uint2* W16 = reinterpret_cast<const uint2*>(ws + W16_OFF);

  extern __shared__ uint2 h_lds[];   // 64 KB: h[k] as f16[32][1024]

  uint2 Wr[4][4];
#pragma unroll
  for (int g = 0; g < 4; ++g)
#pragma unroll
    for (int t = 0; t < 4; ++t)
      Wr[g][t] = W16[(size_t)(g * HD + j) * 256 + lane + 64 * t];

  float bs[4][2];
#pragma unroll
  for (int g = 0; g < 4; ++g)
#pragma unroll
    for (int hf = 0; hf < 2; ++hf)
      bs[g][hf] = base[(size_t)(bq * 8 + hf * 4 + lb) * GD + g * HD + j];

  float c0 = 0.f, c1 = 0.f;

  for (int k = 0; k < LL; ++k) {
    // stage h[k] (f16 ring) -> LDS, lane-contiguous 16B units
    {
      const uint4* src = reinterpret_cast<const uint4*>(h16 + (size_t)k * HSTEP);
      uint4* dst = reinterpret_cast<uint4*>(h_lds);
      uint4 sv[4];
#pragma unroll
      for (int i = 0; i < 4; ++i) sv[i] = src[tid + 1024 * i];
#pragma unroll
      for (int i = 0; i < 4; ++i) dst[tid + 1024 * i] = sv[i];
    }
    __syncthreads();

#pragma unroll
    for (int hf = 0; hf < 2; ++hf) {
      float acc[4][4];
#pragma unroll
      for (int g = 0; g < 4; ++g)
#pragma unroll
        for (int bi = 0; bi < 4; ++bi) acc[g][bi] = 0.f;

#pragma unroll
      for (int bi = 0; bi < 4; ++bi) {
        const int b = bq * 8 + hf * 4 + bi;
        const uint2* hb = h_lds + b * 256;
        uint2 h0 = hb[lane], h1 = hb[lane + 64];
        uint2 h2 = hb[lane + 128], h3 = hb[lane + 192];
#pragma unroll
        for (int g = 0; g < 4; ++g) {
          float a = acc[g][bi];
          a = dot4h(h0, Wr[g][0], a);
          a = dot4h(h1, Wr[g][1], a);
          a = dot4h(h2, Wr[g][2], a);
          a = dot4h(h3, Wr[g][3], a);
          acc[g][bi] = a;
        }
      }
      const bool p1 = (lane & 1), p2 = (lane & 2);
      float s[4];
#pragma unroll
      for (int g = 0; g < 4; ++g) {
        float send0 = p1 ? acc[g][0] : acc[g][1];
        float keep0 = p1 ? acc[g][1] : acc[g][0];
        float r0 = keep0 + __shfl_xor(send0, 1);
        float send1 = p1 ? acc[g][2] : acc[g][3];
        float keep1 = p1 ? acc[g][3] : acc[g][2];
        float r1 = keep1 + __shfl_xor(send1, 1);
        float send2 = p2 ? r0 : r1;
        float keep2 = p2 ? r1 : r0;
        float sg = keep2 + __shfl_xor(send2, 2);
        sg += __shfl_xor(sg, 4);
        sg += __shfl_xor(sg, 8);
        sg += __shfl_xor(sg, 16);
        sg += __shfl_xor(sg, 32);
        s[g] = sg;
      }
      const int bmine = bq * 8 + hf * 4 + lb;
      float wv0 = bf2f(wg[((size_t)k * GD + 0 * HD + j) * 32 + bmine]);
      float wv1 = bf2f(wg[((size_t)k * GD + 1 * HD + j) * 32 + bmine]);
      float wv2 = bf2f(wg[((size_t)k * GD + 2 * HD + j) * 32 + bmine]);
      float wv3 = bf2f(wg[((size_t)k * GD + 3 * HD + j) * 32 + bmine]);
      float ig = sigf(s[0] + wv0 + bs[0][hf]);
      float fg = sigf(s[1] + wv1 + bs[1][hf]);
      float gg = tanhf_fast(s[2] + wv2 + bs[2][hf]);
      float og = sigf(s[3] + wv3 + bs[3][hf]);
      float cr = hf ? c1 : c0;
      cr = fg * cr + ig * gg;
      if (hf) c1 = cr; else c0 = cr;
      if (lane < 4) {
        float hv = og * tanhf_fast(cr);
        csth(h16 + (size_t)(k + 1) * HSTEP + (size_t)bmine * HD + j,
             (unsigned short)(pk16(hv, hv) & 0xffffu));
      }
    }

    if (k < LL - 1) {
      // all-to-all flag barrier: store own flag, every block polls all 256
      __syncthreads();                       // drains h stores (vmcnt) of all waves
      const unsigned tgt = (unsigned)(k + 1);
      if (tid == 0) cstu(arr + rg * 32, tgt);
      if (tid < 64) {
        int ok;
        do {
          ok = 1;
#pragma unroll
          for (int q = 0; q < 4; ++q) {
            unsigned v = cldu(arr + (lane * 4 + q) * 32);
            ok &= (v >= tgt);
          }
        } while (!__all(ok));
      }
      __syncthreads();
    }
  }
}

// ---------------- Phase B1: E[b][t][p] = sum_d H[t][d] C[p][d] (f16 dot2) ----------------
// 512 blocks: b = blk>>4, pt = blk&15 (64-p tile). 256 thr: acc[8 t][4 p].
__global__ __launch_bounds__(256) void b1_energy(
    const float* __restrict__ ctxt, float* __restrict__ ws) {
  const int b = blockIdx.x >> 4, pt = blockIdx.x & 15;
  const int p0 = pt * 64;
  const int tid = threadIdx.x, tx = tid & 15, ty = tid >> 4;
  const unsigned short* h16 = reinterpret_cast<const unsigned short*>(ws + HBUF_OFF);
  float* E = ws + E_OFF;
  __shared__ unsigned At[128][8];    // A pairs along d
  __shared__ unsigned CtT[8][64];    // B^T: [d-pair][p]
  float acc[8][4];
#pragma unroll
  for (int i = 0; i < 8; ++i)
#pragma unroll
    for (int j = 0; j < 4; ++j) acc[i][j] = 0.f;

  const int ar = tid >> 1, ah = tid & 1;
  const int cr = tid >> 2, cq = tid & 3;
  for (int kt = 0; kt < 64; ++kt) {
    const int k0 = kt * 16;
    uint4 u = *reinterpret_cast<const uint4*>(
        h16 + (size_t)(ar + 1) * HSTEP + (size_t)b * HD + k0 + ah * 8);
    const float* cs = ctxt + ((size_t)b * TENC + p0 + cr) * HD + k0 + cq * 4;
    float4 g = *reinterpret_cast<const float4*>(cs);
    __syncthreads();
    *reinterpret_cast<uint4*>(&At[ar][ah * 4]) = u;
    CtT[2*cq][cr]   = pk16(g.x, g.y);
    CtT[2*cq+1][cr] = pk16(g.z, g.w);
    __syncthreads();
#pragma unroll
    for (int kk2 = 0; kk2 < 4; ++kk2) {
      uint2 av[8];
#pragma unroll
      for (int i = 0; i < 8; ++i)
        av[i] = *reinterpret_cast<const uint2*>(&At[ty*8 + i][kk2*2]);
      uint4 cA = *reinterpret_cast<const uint4*>(&CtT[2*kk2][tx*4]);
      uint4 cB = *reinterpret_cast<const uint4*>(&CtT[2*kk2+1][tx*4]);
#pragma unroll
      for (int i = 0; i < 8; ++i) {
        acc[i][0] = dd2(av[i].y, cB.x, dd2(av[i].x, cA.x, acc[i][0]));
        acc[i][1] = dd2(av[i].y, cB.y, dd2(av[i].x, cA.y, acc[i][1]));
        acc[i][2] = dd2(av[i].y, cB.z, dd2(av[i].x, cA.z, acc[i][2]));
        acc[i][3] = dd2(av[i].y, cB.w, dd2(av[i].x, cA.w, acc[i][3]));
      }
    }
  }
#pragma unroll
  for (int i = 0; i < 8; ++i) {
    float* ep = E + ((size_t)b * LL + ty*8 + i) * TENC + p0 + tx*4;
    *reinterpret_cast<float4*>(ep) = make_float4(acc[i][0], acc[i][1], acc[i][2], acc[i][3]);
  }
}

// ---------------- Phase B2: row softmax E(f32) -> P16 ----------------
// 256 blocks: b = blk>>3, tc = blk&7; 16 waves, 1 row each.
__global__ __launch_bounds__(1024) void b2_softmax(float* __restrict__ ws) {
  const int b = blockIdx.x >> 3, tc = blockIdx.x & 7;
  const int w = threadIdx.x >> 6, lane = threadIdx.x & 63;
  const int t = tc * 16 + w;
  const float* E = ws + E_OFF;
  unsigned* P16 = reinterpret_cast<unsigned*>(ws + P_OFF);
  const float4* e4 = reinterpret_cast<const float4*>(E + ((size_t)b * LL + t) * TENC);
  float4 v[4];
#pragma unroll
  for (int c = 0; c < 4; ++c) v[c] = e4[c * 64 + lane];
  float m = fmaxf(fmaxf(fmaxf(v[0].x, v[0].y), fmaxf(v[0].z, v[0].w)),
                  fmaxf(fmaxf(v[1].x, v[1].y), fmaxf(v[1].z, v[1].w)));
  m = fmaxf(m, fmaxf(fmaxf(fmaxf(v[2].x, v[2].y), fmaxf(v[2].z, v[2].w)),
                     fmaxf(fmaxf(v[3].x, v[3].y), fmaxf(v[3].z, v[3].w))));
#pragma unroll
  for (int o = 32; o > 0; o >>= 1) m = fmaxf(m, __shfl_xor(m, o));
  float s = 0.f;
#pragma unroll
  for (int c = 0; c < 4; ++c) {
    v[c].x = __expf(v[c].x - m); v[c].y = __expf(v[c].y - m);
    v[c].z = __expf(v[c].z - m); v[c].w = __expf(v[c].w - m);
    s += v[c].x + v[c].y + v[c].z + v[c].w;
  }
#pragma unroll
  for (int o = 32; o > 0; o >>= 1) s += __shfl_xor(s, o);
  float inv = __builtin_amdgcn_rcpf(s);
  uint2* p2 = reinterpret_cast<uint2*>(P16 + ((size_t)b * LL + t) * 512);
#pragma unroll
  for (int c = 0; c < 4; ++c) {
    uint2 o2;
    o2.x = pk16(v[c].x * inv, v[c].y * inv);
    o2.y = pk16(v[c].z * inv, v[c].w * inv);
    p2[c * 64 + lane] = o2;
  }
}

// ---------------- Phase B3: CTX16[b][t][d] = sum_p P[t][p] C[p][d] (f16 dot2) ----------------
// 512 blocks: b = blk>>4, dt = blk&15 (64-d tile). acc[8 t][4 d].
__global__ __launch_bounds__(256) void b3_ctx(
    const float* __restrict__ ctxt, float* __restrict__ ws) {
  const int b = blockIdx.x >> 4, dt = blockIdx.x & 15;
  const int d0 = dt * 64;
  const int tid = threadIdx.x, tx = tid & 15, ty = tid >> 4;
  const unsigned* P16 = reinterpret_cast<const unsigned*>(ws + P_OFF);
  unsigned* ctx16 = reinterpret_cast<unsigned*>(ws + CTX_OFF);
  __shared__ unsigned At[128][8];    // P pairs along p
  __shared__ unsigned CdT[8][64];    // [p-pair][d]
  float acc[8][4];
#pragma unroll
  for (int i = 0; i < 8; ++i)
#pragma unroll
    for (int j = 0; j < 4; ++j) acc[i][j] = 0.f;

  const int ar = tid >> 1, ah = tid & 1;
  const int cq = tid >> 5, cd = (tid & 31) * 2;
  for (int kt = 0; kt < 64; ++kt) {
    const int k0 = kt * 16;
    uint4 pa = *reinterpret_cast<const uint4*>(
        P16 + ((size_t)b * LL + ar) * 512 + kt * 8 + ah * 4);
    float2 r0 = *reinterpret_cast<const float2*>(
        ctxt + ((size_t)b * TENC + k0 + 2*cq) * HD + d0 + cd);
    float2 r1 = *reinterpret_cast<const float2*>(
        ctxt + ((size_t)b * TENC + k0 + 2*cq + 1) * HD + d0 + cd);
    __syncthreads();
    *reinterpret_cast<uint4*>(&At[ar][ah * 4]) = pa;
    uint2 w2;
    w2.x = pk16(r0.x, r1.x);
    w2.y = pk16(r0.y, r1.y);
    *reinterpret_cast<uint2*>(&CdT[cq][cd]) = w2;
    __syncthreads();
#pragma unroll
    for (int kk2 = 0; kk2 < 4; ++kk2) {
      uint2 av[8];
#pragma unroll
      for (int i = 0; i < 8; ++i)
        av[i] = *reinterpret_cast<const uint2*>(&At[ty*8 + i][kk2*2]);
      uint4 cA = *reinterpret_cast<const uint4*>(&CdT[2*kk2][tx*4]);
      uint4 cB = *reinterpret_cast<const uint4*>(&CdT[2*kk2+1][tx*4]);
#pragma unroll
      for (int i = 0; i < 8; ++i) {
        acc[i][0] = dd2(av[i].y, cB.x, dd2(av[i].x, cA.x, acc[i][0]));
        acc[i][1] = dd2(av[i].y, cB.y, dd2(av[i].x, cA.y, acc[i][1]));
        acc[i][2] = dd2(av[i].y, cB.z, dd2(av[i].x, cA.z, acc[i][2]));
        acc[i][3] = dd2(av[i].y, cB.w, dd2(av[i].x, cA.w, acc[i][3]));
      }
    }
  }
#pragma unroll
  for (int i = 0; i < 8; ++i) {
    uint2 o2;
    o2.x = pk16(acc[i][0], acc[i][1]);
    o2.y = pk16(acc[i][2], acc[i][3]);
    *reinterpret_cast<uint2*>(
        ctx16 + ((size_t)b * LL + ty*8 + i) * 512 + (d0 + tx*4) / 2) = o2;
  }
}

// ---------------- Phase B4: logits + log-softmax (f16 dot2) ----------------
// 256 blocks: b = blk>>3, tq = blk&7 (16-t tile). acc[2 t][4 e], tx 0..31.
__global__ __launch_bounds__(256) void b4_logits(
    const float* __restrict__ Wout, const float* __restrict__ bout,
    const float* __restrict__ ws, float* __restrict__ out) {
  const int b = blockIdx.x >> 3, tq = blockIdx.x & 7;
  const int t0 = tq * 16;
  const int tid = threadIdx.x, tx = tid & 31, ty = tid >> 5;
  const unsigned short* h16 = reinterpret_cast<const unsigned short*>(ws + HBUF_OFF);
  const unsigned* ctx16 = reinterpret_cast<const unsigned*>(ws + CTX_OFF);
  __shared__ unsigned At[16][8];
  __shared__ unsigned WtT[8][128];
  __shared__ float lg[16][132];
  float acc[2][4];
#pragma unroll
  for (int i = 0; i < 2; ++i)
#pragma unroll
    for (int j = 0; j < 4; ++j) acc[i][j] = 0.f;

  const int wr = tid >> 1, wh = tid & 1;
  for (int kt = 0; kt < 128; ++kt) {
    const int k0 = kt * 16;
    unsigned au = 0;
    if (tid < 128) {
      const int r = tid >> 3, k = k0 + (tid & 7) * 2;
      if (k < 1024) {
        au = *reinterpret_cast<const unsigned*>(
            h16 + (size_t)(t0 + r + 1) * HSTEP + (size_t)b * HD + k);
      } else {
        au = ctx16[((size_t)b * LL + t0 + r) * 512 + (k - 1024) / 2];
      }
    }
    const float* wsrc = Wout + (size_t)wr * (2*HD) + k0 + wh * 8;
    float4 w0 = *reinterpret_cast<const float4*>(wsrc);
    float4 w1 = *reinterpret_cast<const float4*>(wsrc + 4);
    __syncthreads();
    if (tid < 128) At[tid >> 3][tid & 7] = au;
    WtT[wh*4+0][wr] = pk16(w0.x, w0.y);
    WtT[wh*4+1][wr] = pk16(w0.z, w0.w);
    WtT[wh*4+2][wr] = pk16(w1.x, w1.y);
    WtT[wh*4+3][wr] = pk16(w1.z, w1.w);
    __syncthreads();
#pragma unroll
    for (int kk2 = 0; kk2 < 4; ++kk2) {
      uint2 av[2];
#pragma unroll
      for (int i = 0; i < 2; ++i)
        av[i] = *reinterpret_cast<const uint2*>(&At[ty*2 + i][kk2*2]);
      uint4 cA = *reinterpret_cast<const uint4*>(&WtT[2*kk2][tx*4]);
      uint4 cB = *reinterpret_cast<const uint4*>(&WtT[2*kk2+1][tx*4]);
#pragma unroll
      for (int i = 0; i < 2; ++i) {
        acc[i][0] = dd2(av[i].y, cB.x, dd2(av[i].x, cA.x, acc[i][0]));
        acc[i][1] = dd2(av[i].y, cB.y, dd2(av[i].x, cA.y, acc[i][1]));
        acc[i][2] = dd2(av[i].y, cB.z, dd2(av[i].x, cA.z, acc[i][2]));
        acc[i][3] = dd2(av[i].y, cB.w, dd2(av[i].x, cA.w, acc[i][3]));
      }
    }
  }
#pragma unroll
  for (int i = 0; i < 2; ++i)
#pragma unroll
    for (int j = 0; j < 4; ++j)
      lg[ty*2 + i][tx*4 + j] = acc[i][j] + bout[tx*4 + j];
  __syncthreads();
  const int w = tid >> 6, lane = tid & 63;
#pragma unroll
  for (int rr = 0; rr < 4; ++rr) {
    const int row = w * 4 + rr;
    float v0 = lg[row][lane], v1 = lg[row][lane + 64];
    float mx = fmaxf(v0, v1);
#pragma unroll
    for (int o = 32; o > 0; o >>= 1) mx = fmaxf(mx, __shfl_xor(mx, o));
    float sm = __expf(v0 - mx) + __expf(v1 - mx);
#pragma unroll
    for (int o = 32; o > 0; o >>= 1) sm += __shfl_xor(sm, o);
    float lse = mx + __logf(sm);
    float* op = out + ((size_t)b * LL + t0 + row) * ED;
    op[lane]      = v0 - lse;
    op[lane + 64] = v1 - lse;
  }
}

extern "C" void kernel_launch(void* const* d_in, const int* in_sizes, int n_in,
                              void* d_out, int out_size, void* d_ws, size_t ws_size,
                              hipStream_t stream) {
  (void)in_sizes; (void)n_in; (void)out_size; (void)ws_size;
  const float* ctxt = (const float*)d_in[0];
  const float* gt   = (const float*)d_in[1];
  const float* Wih  = (const float*)d_in[2];
  const float* Whh  = (const float*)d_in[3];
  const float* bih  = (const float*)d_in[4];
  const float* bhh  = (const float*)d_in[5];
  const float* Wout = (const float*)d_in[6];
  const float* bout = (const float*)d_in[7];
  float* out = (float*)d_out;
  float* ws  = (float*)d_ws;

  hipMemsetAsync(ws + HBUF_OFF, 0, (size_t)HSTEP * 2, stream);                 // h_0 = 0 (f16)
  hipMemsetAsync(ws + ARR_OFF, 0, (8192 + 64) * sizeof(float), stream);        // arr flags

  base_kernel<<<(BATCH * GD) / 256, 256, 0, stream>>>(ctxt, Wih, bih, bhh, ws);
  phase0_wordg<<<1024, 256, 0, stream>>>(gt, Wih, ws);
  whh16_kernel<<<(GD * HD / 8) / 256, 256, 0, stream>>>(Whh, ws);

  static int smem_set = 0;
  if (!smem_set) {
    (void)hipFuncSetAttribute((const void*)&phaseA,
                              hipFuncAttributeMaxDynamicSharedMemorySize, 65536);
    smem_set = 1;
  }
  void* argsA[] = { (void*)&ws };
  (void)hipLaunchCooperativeKernel((const void*)&phaseA, dim3(256), dim3(1024),
                                   argsA, 65536, stream);

  b1_energy<<<512, 256, 0, stream>>>(ctxt, ws);
  b2_softmax<<<256, 1024, 0, stream>>>(ws);
  b3_ctx<<<512, 256, 0, stream>>>(ctxt, ws);
  b4_logits<<<256, 256, 0, stream>>>(Wout, bout, ws, out);
}

// Round 12
// 989.817 us; speedup vs baseline: 24.8313x; 1.5167x over previous
//
#include <hip/hip_runtime.h>

#define BATCH 32
#define TENC  1024
#define HD    1024
#define ED    128
#define LL    128
#define GD    4096
#define IND   1152
#define HSTEP (BATCH*HD)

// ws float offsets
#define HBUF_OFF 131072                       // base: [0, 131072)
#define ARR_OFF  (HBUF_OFF + 129*HSTEP)       // h ring [129][32][1024] f16 (uses half)
#define REL_OFF  (ARR_OFF + 8192)             // arrival flags: 256 x 128B
#define E_OFF    (REL_OFF + 64)
#define P_OFF    (E_OFF + BATCH*LL*TENC)
#define CTX_OFF  (P_OFF + BATCH*LL*TENC)
#define W16_OFF  CTX_OFF                      // WA: packed Whh A-frags f16 (8.4MB), dead after phaseA
// wordg bf16 (16.8MB) occupies [E_OFF, ...) until phaseA ends.
// After phaseA: E f32 at E_OFF, P16 at P_OFF, ctx16 at CTX_OFF (overlays WA).

typedef _Float16 h16x2 __attribute__((ext_vector_type(2)));
typedef __fp16   f16x2 __attribute__((ext_vector_type(2)));
typedef _Float16 f16x8v __attribute__((ext_vector_type(8)));
typedef float    f32x4v __attribute__((ext_vector_type(4)));
union CVT { f16x2 f; h16x2 h; unsigned u; };
union U4H8 { uint4 u; f16x8v h; };

__device__ __forceinline__ unsigned pk16(float x, float y) {
  CVT c; c.f = __builtin_amdgcn_cvt_pkrtz(x, y); return c.u;
}
__device__ __forceinline__ float dd2(unsigned a, unsigned b, float c) {
  CVT x{.u = a}, y{.u = b};
  return __builtin_amdgcn_fdot2(x.h, y.h, c, false);
}
__device__ __forceinline__ float sigf(float x) {
  return __builtin_amdgcn_rcpf(1.0f + __expf(-x));
}
__device__ __forceinline__ float tanhf_fast(float x) {
  return 1.0f - 2.0f * __builtin_amdgcn_rcpf(1.0f + __expf(2.0f * x));
}
__device__ __forceinline__ unsigned bfrne(float f) {       // f32 -> bf16 RNE
  unsigned v = __float_as_uint(f);
  return (v + 0x7fffu + ((v >> 16) & 1u)) >> 16;
}
__device__ __forceinline__ float bf2f(unsigned short u) {
  return __uint_as_float(((unsigned)u) << 16);
}
__device__ __forceinline__ void csth(unsigned short* p, unsigned short v) {
  __hip_atomic_store(p, v, __ATOMIC_RELAXED, __HIP_MEMORY_SCOPE_AGENT);
}
__device__ __forceinline__ void cstu(unsigned* p, unsigned v) {
  __hip_atomic_store(p, v, __ATOMIC_RELAXED, __HIP_MEMORY_SCOPE_AGENT);
}
__device__ __forceinline__ unsigned cldu(const unsigned* p) {
  return __hip_atomic_load(p, __ATOMIC_RELAXED, __HIP_MEMORY_SCOPE_AGENT);
}

// base[b][g] = b_ih[g]+b_hh[g]+dot(ctx0[b], W_ih[g][E:])
__global__ __launch_bounds__(256) void base_kernel(
    const float* __restrict__ ctxt, const float* __restrict__ Wih,
    const float* __restrict__ bih, const float* __restrict__ bhh,
    float* __restrict__ base) {
  int id = blockIdx.x * 256 + threadIdx.x;
  int b = id & (BATCH - 1);
  int g = id >> 5;
  const float4* c4 = reinterpret_cast<const float4*>(ctxt + (size_t)b * TENC * HD);
  const float4* w4 = reinterpret_cast<const float4*>(Wih + (size_t)g * IND + ED);
  float a = 0.f;
#pragma unroll 8
  for (int kk = 0; kk < HD/4; ++kk) {
    float4 c = c4[kk], w = w4[kk];
    a += c.x*w.x + c.y*w.y + c.z*w.z + c.w*w.w;
  }
  base[(size_t)b * GD + g] = a + bih[g] + bhh[g];
}

// Pack Whh into per-wave MFMA A-fragments (f16).
// WA[((rg*32 + w*2 + s)*64 + l)] = 8 f16: A[m = l&15][k = 64w+32s+(l>>4)*8 + 0..7]
// where row m -> (jloc = m>>2, gate = m&3), Whh row = gate*1024 + rg*4 + jloc.
__global__ __launch_bounds__(256) void packA_kernel(
    const float* __restrict__ Whh, float* __restrict__ ws) {
  uint4* WA = reinterpret_cast<uint4*>(ws + W16_OFF);
  const int t = blockIdx.x * 256 + threadIdx.x;   // 524288 total
  const int l = t & 63;
  const int s = (t >> 6) & 1;
  const int w = (t >> 7) & 15;
  const int rg = t >> 11;
  const int m = l & 15;
  const int row = (m & 3) * 1024 + rg * 4 + (m >> 2);
  const int kb = 64 * w + 32 * s + (l >> 4) * 8;
  const float* src = Whh + (size_t)row * 1024 + kb;
  float4 a = *reinterpret_cast<const float4*>(src);
  float4 b = *reinterpret_cast<const float4*>(src + 4);
  uint4 o;
  o.x = pk16(a.x, a.y); o.y = pk16(a.z, a.w);
  o.z = pk16(b.x, b.y); o.w = pk16(b.z, b.w);
  WA[t] = o;
}

// ---------------- Phase 0: wordg[t][row][b] = word_t[b] . Wih[row][0:128] (bf16) ----------------
__global__ __launch_bounds__(256) void phase0_wordg(
    const float* __restrict__ gt, const float* __restrict__ Wih,
    float* __restrict__ ws) {
  const int mt = blockIdx.x & 31, nt = blockIdx.x >> 5;
  const int r0 = mt * 128, n0 = nt * 128;
  const int tid = threadIdx.x, tx = tid & 15, ty = tid >> 4;
  unsigned short* wg = reinterpret_cast<unsigned short*>(ws + E_OFF);
  __shared__ float At[128][18];
  __shared__ float BtT[16][132];
  float acc[8][8];
#pragma unroll
  for (int i = 0; i < 8; ++i)
#pragma unroll
    for (int j = 0; j < 8; ++j) acc[i][j] = 0.f;

  const int sr = tid >> 1, sc = (tid & 1) * 8;
  for (int kt = 0; kt < 8; ++kt) {
    const int k0 = kt * 16;
    const float* ap = Wih + (size_t)(r0 + sr) * IND + k0 + sc;
    float4 a0 = *reinterpret_cast<const float4*>(ap);
    float4 a1 = *reinterpret_cast<const float4*>(ap + 4);
    const int n = n0 + sr, t = n >> 5, bb = n & 31;
    float4 b0, b1;
    if (t == 0) {
      b0 = make_float4((k0 + sc == 0) ? 1.f : 0.f, 0.f, 0.f, 0.f);
      b1 = make_float4(0.f, 0.f, 0.f, 0.f);
    } else {
      const float* bp = gt + ((size_t)bb * LL + (t - 1)) * ED + k0 + sc;
      b0 = *reinterpret_cast<const float4*>(bp);
      b1 = *reinterpret_cast<const float4*>(bp + 4);
    }
    __syncthreads();
    *reinterpret_cast<float4*>(&At[sr][sc]) = a0;
    *reinterpret_cast<float4*>(&At[sr][sc + 4]) = a1;
    BtT[sc+0][sr] = b0.x; BtT[sc+1][sr] = b0.y; BtT[sc+2][sr] = b0.z; BtT[sc+3][sr] = b0.w;
    BtT[sc+4][sr] = b1.x; BtT[sc+5][sr] = b1.y; BtT[sc+6][sr] = b1.z; BtT[sc+7][sr] = b1.w;
    __syncthreads();
#pragma unroll
    for (int kk2 = 0; kk2 < 8; ++kk2) {
      float2 av[8];
#pragma unroll
      for (int i = 0; i < 8; ++i)
        av[i] = *reinterpret_cast<const float2*>(&At[ty*8 + i][kk2*2]);
      float4 c00 = *reinterpret_cast<const float4*>(&BtT[kk2*2][tx*8]);
      float4 c01 = *reinterpret_cast<const float4*>(&BtT[kk2*2][tx*8 + 4]);
      float4 c10 = *reinterpret_cast<const float4*>(&BtT[kk2*2+1][tx*8]);
      float4 c11 = *reinterpret_cast<const float4*>(&BtT[kk2*2+1][tx*8 + 4]);
#pragma unroll
      for (int i = 0; i < 8; ++i) {
        acc[i][0] += av[i].x*c00.x + av[i].y*c10.x;
        acc[i][1] += av[i].x*c00.y + av[i].y*c10.y;
        acc[i][2] += av[i].x*c00.z + av[i].y*c10.z;
        acc[i][3] += av[i].x*c00.w + av[i].y*c10.w;
        acc[i][4] += av[i].x*c01.x + av[i].y*c11.x;
        acc[i][5] += av[i].x*c01.y + av[i].y*c11.y;
        acc[i][6] += av[i].x*c01.z + av[i].y*c11.z;
        acc[i][7] += av[i].x*c01.w + av[i].y*c11.w;
      }
    }
  }
  const int nb = n0 + tx * 8, t = nb >> 5, b0i = nb & 31;
#pragma unroll
  for (int i = 0; i < 8; ++i) {
    const int row = r0 + ty * 8 + i;
    uint4 pk;
    pk.x = bfrne(acc[i][0]) | (bfrne(acc[i][1]) << 16);
    pk.y = bfrne(acc[i][2]) | (bfrne(acc[i][3]) << 16);
    pk.z = bfrne(acc[i][4]) | (bfrne(acc[i][5]) << 16);
    pk.w = bfrne(acc[i][6]) | (bfrne(acc[i][7]) << 16);
    *reinterpret_cast<uint4*>(wg + ((size_t)t * GD + row) * 32 + b0i) = pk;
  }
}

// ---------------- Phase A: recurrence via MFMA ----------------
// Block rg: output rows m = 4*jloc + gate (16) x 32 b = two 16x16 tiles.
// Wave w: K-slice [64w, 64w+64), 2 ksubs x 2 tiles = 4 MFMA/step.
// LDS: h (f16, XOR-swizzled, 64KB) | part[2][16][16][16] f32 | red[16][32] f32.
__global__ __launch_bounds__(1024, 4) void phaseA(float* __restrict__ ws) {
  const int rg = blockIdx.x;
  const int tid = threadIdx.x;
  const int lane = tid & 63;
  const int w = tid >> 6;
  float* base = ws;
  unsigned short* h16 = reinterpret_cast<unsigned short*>(ws + HBUF_OFF);
  unsigned* arr = reinterpret_cast<unsigned*>(ws + ARR_OFF);
  const unsigned short* wg = reinterpret_cast<const unsigned short*>(ws + E_OFF);
  const uint4* WA = reinterpret_cast<const uint4*>(ws + W16_OFF);

  extern __shared__ float smem[];
  uint4* h_lds = reinterpret_cast<uint4*>(smem);   // 4096 16B units
  float* part = smem + 16384;                      // [T][m][w][b]
  float* red  = smem + 24576;                      // [m][b_glob]

  // A-fragments for this wave's K-slice (persistent)
  U4H8 afr0, afr1;
  afr0.u = WA[((size_t)rg * 32 + w * 2 + 0) * 64 + lane];
  afr1.u = WA[((size_t)rg * 32 + w * 2 + 1) * 64 + lane];

  // reduce-thread constants (tid < 512): output (T, m, b)
  const int rT = tid >> 8, rm = (tid >> 4) & 15, rb = tid & 15;
  const int rbg = rT * 16 + rb;
  const int rrow = (rm & 3) * 1024 + rg * 4 + (rm >> 2);
  float base_r = (tid < 512) ? base[(size_t)rbg * GD + rrow] : 0.f;

  // cell-thread state (tid < 128): (jloc, b)
  const int cjl = tid >> 5, cb = tid & 31;
  float c_reg = 0.f;

  for (int k = 0; k < LL; ++k) {
    // stage h[k] -> LDS swizzled; prefetch wordg for this step
    uint4 sv[4];
    const uint4* src = reinterpret_cast<const uint4*>(h16 + (size_t)k * HSTEP);
#pragma unroll
    for (int i = 0; i < 4; ++i) sv[i] = src[tid + 1024 * i];
    float wgv = 0.f;
    if (tid < 512) wgv = bf2f(wg[((size_t)k * GD + rrow) * 32 + rbg]);
#pragma unroll
    for (int i = 0; i < 4; ++i) {
      const int u = tid + 1024 * i;
      h_lds[u ^ ((u >> 7) & 15)] = sv[i];
    }
    __syncthreads();

    // 4 MFMA: 2 tiles (b 0-15 / 16-31) x 2 ksubs
    f32x4v acc0 = {0.f, 0.f, 0.f, 0.f}, acc1 = acc0;
    {
      const int b0 = lane & 15, b1 = 16 + (lane & 15);
      const int k0u = 8 * w + (lane >> 4);
      U4H8 bf00, bf01, bf10, bf11;
      bf00.u = h_lds[(b0 * 128 + k0u) ^ (b0 & 15)];
      bf10.u = h_lds[(b1 * 128 + k0u) ^ (b1 & 15)];
      bf01.u = h_lds[(b0 * 128 + k0u + 4) ^ (b0 & 15)];
      bf11.u = h_lds[(b1 * 128 + k0u + 4) ^ (b1 & 15)];
      acc0 = __builtin_amdgcn_mfma_f32_16x16x32_f16(afr0.h, bf00.h, acc0, 0, 0, 0);
      acc1 = __builtin_amdgcn_mfma_f32_16x16x32_f16(afr0.h, bf10.h, acc1, 0, 0, 0);
      acc0 = __builtin_amdgcn_mfma_f32_16x16x32_f16(afr1.h, bf01.h, acc0, 0, 0, 0);
      acc1 = __builtin_amdgcn_mfma_f32_16x16x32_f16(afr1.h, bf11.h, acc1, 0, 0, 0);
    }
    // partials: part[T][m][w][b], C/D map m=(lane>>4)*4+q, b=lane&15 (verified)
#pragma unroll
    for (int q = 0; q < 4; ++q) {
      const int m = (lane >> 4) * 4 + q;
      part[(m * 16 + w) * 16 + (lane & 15)] = acc0[q];
      part[((16 + m) * 16 + w) * 16 + (lane & 15)] = acc1[q];
    }
    __syncthreads();

    // 16-way cross-wave reduce + bias/word add
    if (tid < 512) {
      float s = 0.f;
#pragma unroll
      for (int ww = 0; ww < 16; ++ww)
        s += part[((rT * 16 + rm) * 16 + ww) * 16 + rb];
      red[rm * 32 + rbg] = s + wgv + base_r;
    }
    __syncthreads();

    // cell + h write
    if (tid < 128) {
      float ig = sigf(red[(4 * cjl + 0) * 32 + cb]);
      float fg = sigf(red[(4 * cjl + 1) * 32 + cb]);
      float gg = tanhf_fast(red[(4 * cjl + 2) * 32 + cb]);
      float og = sigf(red[(4 * cjl + 3) * 32 + cb]);
      c_reg = fg * c_reg + ig * gg;
      float hv = og * tanhf_fast(c_reg);
      csth(h16 + (size_t)(k + 1) * HSTEP + (size_t)cb * HD + (rg * 4 + cjl),
           (unsigned short)(pk16(hv, hv) & 0xffffu));
    }

    if (k < LL - 1) {
      // all-to-all flag barrier (R11-proven)
      __syncthreads();
      const unsigned tgt = (unsigned)(k + 1);
      if (tid == 0) cstu(arr + rg * 32, tgt);
      if (tid < 64) {
        int ok;
        do {
          ok = 1;
#pragma unroll
          for (int q = 0; q < 4; ++q)
            ok &= (cldu(arr + (lane * 4 + q) * 32) >= (unsigned)tgt);
        } while (!__all(ok));
      }
      __syncthreads();
    }
  }
}

// ---------------- Phase B1: E[b][t][p] = sum_d H[t][d] C[p][d] (f16 dot2) ----------------
__global__ __launch_bounds__(256) void b1_energy(
    const float* __restrict__ ctxt, float* __restrict__ ws) {
  const int b = blockIdx.x >> 4, pt = blockIdx.x & 15;
  const int p0 = pt * 64;
  const int tid = threadIdx.x, tx = tid & 15, ty = tid >> 4;
  const unsigned short* h16 = reinterpret_cast<const unsigned short*>(ws + HBUF_OFF);
  float* E = ws + E_OFF;
  __shared__ unsigned At[128][8];
  __shared__ unsigned CtT[8][64];
  float acc[8][4];
#pragma unroll
  for (int i = 0; i < 8; ++i)
#pragma unroll
    for (int j = 0; j < 4; ++j) acc[i][j] = 0.f;

  const int ar = tid >> 1, ah = tid & 1;
  const int cr = tid >> 2, cq = tid & 3;
  for (int kt = 0; kt < 64; ++kt) {
    const int k0 = kt * 16;
    uint4 u = *reinterpret_cast<const uint4*>(
        h16 + (size_t)(ar + 1) * HSTEP + (size_t)b * HD + k0 + ah * 8);
    const float* cs = ctxt + ((size_t)b * TENC + p0 + cr) * HD + k0 + cq * 4;
    float4 g = *reinterpret_cast<const float4*>(cs);
    __syncthreads();
    *reinterpret_cast<uint4*>(&At[ar][ah * 4]) = u;
    CtT[2*cq][cr]   = pk16(g.x, g.y);
    CtT[2*cq+1][cr] = pk16(g.z, g.w);
    __syncthreads();
#pragma unroll
    for (int kk2 = 0; kk2 < 4; ++kk2) {
      uint2 av[8];
#pragma unroll
      for (int i = 0; i < 8; ++i)
        av[i] = *reinterpret_cast<const uint2*>(&At[ty*8 + i][kk2*2]);
      uint4 cA = *reinterpret_cast<const uint4*>(&CtT[2*kk2][tx*4]);
      uint4 cB = *reinterpret_cast<const uint4*>(&CtT[2*kk2+1][tx*4]);
#pragma unroll
      for (int i = 0; i < 8; ++i) {
        acc[i][0] = dd2(av[i].y, cB.x, dd2(av[i].x, cA.x, acc[i][0]));
        acc[i][1] = dd2(av[i].y, cB.y, dd2(av[i].x, cA.y, acc[i][1]));
        acc[i][2] = dd2(av[i].y, cB.z, dd2(av[i].x, cA.z, acc[i][2]));
        acc[i][3] = dd2(av[i].y, cB.w, dd2(av[i].x, cA.w, acc[i][3]));
      }
    }
  }
#pragma unroll
  for (int i = 0; i < 8; ++i) {
    float* ep = E + ((size_t)b * LL + ty*8 + i) * TENC + p0 + tx*4;
    *reinterpret_cast<float4*>(ep) = make_float4(acc[i][0], acc[i][1], acc[i][2], acc[i][3]);
  }
}

// ---------------- Phase B2: row softmax E(f32) -> P16 ----------------
__global__ __launch_bounds__(1024) void b2_softmax(float* __restrict__ ws) {
  const int b = blockIdx.x >> 3, tc = blockIdx.x & 7;
  const int w = threadIdx.x >> 6, lane = threadIdx.x & 63;
  const int t = tc * 16 + w;
  const float* E = ws + E_OFF;
  unsigned* P16 = reinterpret_cast<unsigned*>(ws + P_OFF);
  const float4* e4 = reinterpret_cast<const float4*>(E + ((size_t)b * LL + t) * TENC);
  float4 v[4];
#pragma unroll
  for (int c = 0; c < 4; ++c) v[c] = e4[c * 64 + lane];
  float m = fmaxf(fmaxf(fmaxf(v[0].x, v[0].y), fmaxf(v[0].z, v[0].w)),
                  fmaxf(fmaxf(v[1].x, v[1].y), fmaxf(v[1].z, v[1].w)));
  m = fmaxf(m, fmaxf(fmaxf(fmaxf(v[2].x, v[2].y), fmaxf(v[2].z, v[2].w)),
                     fmaxf(fmaxf(v[3].x, v[3].y), fmaxf(v[3].z, v[3].w))));
#pragma unroll
  for (int o = 32; o > 0; o >>= 1) m = fmaxf(m, __shfl_xor(m, o));
  float s = 0.f;
#pragma unroll
  for (int c = 0; c < 4; ++c) {
    v[c].x = __expf(v[c].x - m); v[c].y = __expf(v[c].y - m);
    v[c].z = __expf(v[c].z - m); v[c].w = __expf(v[c].w - m);
    s += v[c].x + v[c].y + v[c].z + v[c].w;
  }
#pragma unroll
  for (int o = 32; o > 0; o >>= 1) s += __shfl_xor(s, o);
  float inv = __builtin_amdgcn_rcpf(s);
  uint2* p2 = reinterpret_cast<uint2*>(P16 + ((size_t)b * LL + t) * 512);
#pragma unroll
  for (int c = 0; c < 4; ++c) {
    uint2 o2;
    o2.x = pk16(v[c].x * inv, v[c].y * inv);
    o2.y = pk16(v[c].z * inv, v[c].w * inv);
    p2[c * 64 + lane] = o2;
  }
}

// ---------------- Phase B3: CTX16[b][t][d] = sum_p P[t][p] C[p][d] (f16 dot2) ----------------
__global__ __launch_bounds__(256) void b3_ctx(
    const float* __restrict__ ctxt, float* __restrict__ ws) {
  const int b = blockIdx.x >> 4, dt = blockIdx.x & 15;
  const int d0 = dt * 64;
  const int tid = threadIdx.x, tx = tid & 15, ty = tid >> 4;
  const unsigned* P16 = reinterpret_cast<const unsigned*>(ws + P_OFF);
  unsigned* ctx16 = reinterpret_cast<unsigned*>(ws + CTX_OFF);
  __shared__ unsigned At[128][8];
  __shared__ unsigned CdT[8][64];
  float acc[8][4];
#pragma unroll
  for (int i = 0; i < 8; ++i)
#pragma unroll
    for (int j = 0; j < 4; ++j) acc[i][j] = 0.f;

  const int ar = tid >> 1, ah = tid & 1;
  const int cq = tid >> 5, cd = (tid & 31) * 2;
  for (int kt = 0; kt < 64; ++kt) {
    const int k0 = kt * 16;
    uint4 pa = *reinterpret_cast<const uint4*>(
        P16 + ((size_t)b * LL + ar) * 512 + kt * 8 + ah * 4);
    float2 r0 = *reinterpret_cast<const float2*>(
        ctxt + ((size_t)b * TENC + k0 + 2*cq) * HD + d0 + cd);
    float2 r1 = *reinterpret_cast<const float2*>(
        ctxt + ((size_t)b * TENC + k0 + 2*cq + 1) * HD + d0 + cd);
    __syncthreads();
    *reinterpret_cast<uint4*>(&At[ar][ah * 4]) = pa;
    uint2 w2;
    w2.x = pk16(r0.x, r1.x);
    w2.y = pk16(r0.y, r1.y);
    *reinterpret_cast<uint2*>(&CdT[cq][cd]) = w2;
    __syncthreads();
#pragma unroll
    for (int kk2 = 0; kk2 < 4; ++kk2) {
      uint2 av[8];
#pragma unroll
      for (int i = 0; i < 8; ++i)
        av[i] = *reinterpret_cast<const uint2*>(&At[ty*8 + i][kk2*2]);
      uint4 cA = *reinterpret_cast<const uint4*>(&CdT[2*kk2][tx*4]);
      uint4 cB = *reinterpret_cast<const uint4*>(&CdT[2*kk2+1][tx*4]);
#pragma unroll
      for (int i = 0; i < 8; ++i) {
        acc[i][0] = dd2(av[i].y, cB.x, dd2(av[i].x, cA.x, acc[i][0]));
        acc[i][1] = dd2(av[i].y, cB.y, dd2(av[i].x, cA.y, acc[i][1]));
        acc[i][2] = dd2(av[i].y, cB.z, dd2(av[i].x, cA.z, acc[i][2]));
        acc[i][3] = dd2(av[i].y, cB.w, dd2(av[i].x, cA.w, acc[i][3]));
      }
    }
  }
#pragma unroll
  for (int i = 0; i < 8; ++i) {
    uint2 o2;
    o2.x = pk16(acc[i][0], acc[i][1]);
    o2.y = pk16(acc[i][2], acc[i][3]);
    *reinterpret_cast<uint2*>(
        ctx16 + ((size_t)b * LL + ty*8 + i) * 512 + (d0 + tx*4) / 2) = o2;
  }
}

// ---------------- Phase B4: logits + log-softmax (f16 dot2) ----------------
__global__ __launch_bounds__(256) void b4_logits(
    const float* __restrict__ Wout, const float* __restrict__ bout,
    const float* __restrict__ ws, float* __restrict__ out) {
  const int b = blockIdx.x >> 3, tq = blockIdx.x & 7;
  const int t0 = tq * 16;
  const int tid = threadIdx.x, tx = tid & 31, ty = tid >> 5;
  const unsigned short* h16 = reinterpret_cast<const unsigned short*>(ws + HBUF_OFF);
  const unsigned* ctx16 = reinterpret_cast<const unsigned*>(ws + CTX_OFF);
  __shared__ unsigned At[16][8];
  __shared__ unsigned WtT[8][128];
  __shared__ float lg[16][132];
  float acc[2][4];
#pragma unroll
  for (int i = 0; i < 2; ++i)
#pragma unroll
    for (int j = 0; j < 4; ++j) acc[i][j] = 0.f;

  const int wr = tid >> 1, wh = tid & 1;
  for (int kt = 0; kt < 128; ++kt) {
    const int k0 = kt * 16;
    unsigned au = 0;
    if (tid < 128) {
      const int r = tid >> 3, k = k0 + (tid & 7) * 2;
      if (k < 1024) {
        au = *reinterpret_cast<const unsigned*>(
            h16 + (size_t)(t0 + r + 1) * HSTEP + (size_t)b * HD + k);
      } else {
        au = ctx16[((size_t)b * LL + t0 + r) * 512 + (k - 1024) / 2];
      }
    }
    const float* wsrc = Wout + (size_t)wr * (2*HD) + k0 + wh * 8;
    float4 w0 = *reinterpret_cast<const float4*>(wsrc);
    float4 w1 = *reinterpret_cast<const float4*>(wsrc + 4);
    __syncthreads();
    if (tid < 128) At[tid >> 3][tid & 7] = au;
    WtT[wh*4+0][wr] = pk16(w0.x, w0.y);
    WtT[wh*4+1][wr] = pk16(w0.z, w0.w);
    WtT[wh*4+2][wr] = pk16(w1.x, w1.y);
    WtT[wh*4+3][wr] = pk16(w1.z, w1.w);
    __syncthreads();
#pragma unroll
    for (int kk2 = 0; kk2 < 4; ++kk2) {
      uint2 av[2];
#pragma unroll
      for (int i = 0; i < 2; ++i)
        av[i] = *reinterpret_cast<const uint2*>(&At[ty*2 + i][kk2*2]);
      uint4 cA = *reinterpret_cast<const uint4*>(&WtT[2*kk2][tx*4]);
      uint4 cB = *reinterpret_cast<const uint4*>(&WtT[2*kk2+1][tx*4]);
#pragma unroll
      for (int i = 0; i < 2; ++i) {
        acc[i][0] = dd2(av[i].y, cB.x, dd2(av[i].x, cA.x, acc[i][0]));
        acc[i][1] = dd2(av[i].y, cB.y, dd2(av[i].x, cA.y, acc[i][1]));
        acc[i][2] = dd2(av[i].y, cB.z, dd2(av[i].x, cA.z, acc[i][2]));
        acc[i][3] = dd2(av[i].y, cB.w, dd2(av[i].x, cA.w, acc[i][3]));
      }
    }
  }
#pragma unroll
  for (int i = 0; i < 2; ++i)
#pragma unroll
    for (int j = 0; j < 4; ++j)
      lg[ty*2 + i][tx*4 + j] = acc[i][j] + bout[tx*4 + j];
  __syncthreads();
  const int w = tid >> 6, lane = tid & 63;
#pragma unroll
  for (int rr = 0; rr < 4; ++rr) {
    const int row = w * 4 + rr;
    float v0 = lg[row][lane], v1 = lg[row][lane + 64];
    float mx = fmaxf(v0, v1);
#pragma unroll
    for (int o = 32; o > 0; o >>= 1) mx = fmaxf(mx, __shfl_xor(mx, o));
    float sm = __expf(v0 - mx) + __expf(v1 - mx);
#pragma unroll
    for (int o = 32; o > 0; o >>= 1) sm += __shfl_xor(sm, o);
    float lse = mx + __logf(sm);
    float* op = out + ((size_t)b * LL + t0 + row) * ED;
    op[lane]      = v0 - lse;
    op[lane + 64] = v1 - lse;
  }
}

extern "C" void kernel_launch(void* const* d_in, const int* in_sizes, int n_in,
                              void* d_out, int out_size, void* d_ws, size_t ws_size,
                              hipStream_t stream) {
  (void)in_sizes; (void)n_in; (void)out_size; (void)ws_size;
  const float* ctxt = (const float*)d_in[0];
  const float* gt   = (const float*)d_in[1];
  const float* Wih  = (const float*)d_in[2];
  const float* Whh  = (const float*)d_in[3];
  const float* bih  = (const float*)d_in[4];
  const float* bhh  = (const float*)d_in[5];
  const float* Wout = (const float*)d_in[6];
  const float* bout = (const float*)d_in[7];
  float* out = (float*)d_out;
  float* ws  = (float*)d_ws;

  hipMemsetAsync(ws + HBUF_OFF, 0, (size_t)HSTEP * 2, stream);                 // h_0 = 0 (f16)
  hipMemsetAsync(ws + ARR_OFF, 0, (8192 + 64) * sizeof(float), stream);        // arr flags

  base_kernel<<<(BATCH * GD) / 256, 256, 0, stream>>>(ctxt, Wih, bih, bhh, ws);
  phase0_wordg<<<1024, 256, 0, stream>>>(gt, Wih, ws);
  packA_kernel<<<2048, 256, 0, stream>>>(Whh, ws);

  static int smem_set = 0;
  if (!smem_set) {
    (void)hipFuncSetAttribute((const void*)&phaseA,
                              hipFuncAttributeMaxDynamicSharedMemorySize, 100352);
    smem_set = 1;
  }
  void* argsA[] = { (void*)&ws };
  (void)hipLaunchCooperativeKernel((const void*)&phaseA, dim3(256), dim3(1024),
                                   argsA, 100352, stream);

  b1_energy<<<512, 256, 0, stream>>>(ctxt, ws);
  b2_softmax<<<256, 1024, 0, stream>>>(ws);
  b3_ctx<<<512, 256, 0, stream>>>(ctxt, ws);
  b4_logits<<<256, 256, 0, stream>>>(Wout, bout, ws, out);
}

// Round 13
// 875.776 us; speedup vs baseline: 28.0648x; 1.1302x over previous
//
#include <hip/hip_runtime.h>

#define BATCH 32
#define TENC  1024
#define HD    1024
#define ED    128
#define LL    128
#define GD    4096
#define IND   1152
#define HSTEP (BATCH*HD)

// ws float offsets
#define HBUF_OFF 131072                       // base: [0, 131072)
#define ARR_OFF  (HBUF_OFF + 129*HSTEP)       // h ring [129][32][1024] f16 (uses half)
#define REL_OFF  (ARR_OFF + 8192)
#define E_OFF    (REL_OFF + 64)
#define P_OFF    (E_OFF + BATCH*LL*TENC)      // PA: P in A-frag layout (8.4MB)
#define CTX_OFF  (P_OFF + BATCH*LL*TENC)
#define W16_OFF  CTX_OFF                      // WA: packed Whh A-frags (8.4MB), dead after phaseA
#define HA_OFF   (CTX_OFF + 2097152)          // h in A-frag layout (8.4MB)
// wordg bf16 (16.8MB) at E_OFF until phaseA ends; then E f32 there.
// ctx16 (8.4MB) overlays WA after phaseA.

typedef _Float16 h16x2 __attribute__((ext_vector_type(2)));
typedef __fp16   f16x2 __attribute__((ext_vector_type(2)));
typedef _Float16 f16x8v __attribute__((ext_vector_type(8)));
typedef float    f32x4v __attribute__((ext_vector_type(4)));
union CVT { f16x2 f; h16x2 h; unsigned u; };
union U4H8 { uint4 u; f16x8v h; };

__device__ __forceinline__ unsigned pk16(float x, float y) {
  CVT c; c.f = __builtin_amdgcn_cvt_pkrtz(x, y); return c.u;
}
__device__ __forceinline__ float dd2(unsigned a, unsigned b, float c) {
  CVT x{.u = a}, y{.u = b};
  return __builtin_amdgcn_fdot2(x.h, y.h, c, false);
}
__device__ __forceinline__ float sigf(float x) {
  return __builtin_amdgcn_rcpf(1.0f + __expf(-x));
}
__device__ __forceinline__ float tanhf_fast(float x) {
  return 1.0f - 2.0f * __builtin_amdgcn_rcpf(1.0f + __expf(2.0f * x));
}
__device__ __forceinline__ unsigned bfrne(float f) {
  unsigned v = __float_as_uint(f);
  return (v + 0x7fffu + ((v >> 16) & 1u)) >> 16;
}
__device__ __forceinline__ float bf2f(unsigned short u) {
  return __uint_as_float(((unsigned)u) << 16);
}
__device__ __forceinline__ void csth(unsigned short* p, unsigned short v) {
  __hip_atomic_store(p, v, __ATOMIC_RELAXED, __HIP_MEMORY_SCOPE_AGENT);
}
__device__ __forceinline__ void cstu(unsigned* p, unsigned v) {
  __hip_atomic_store(p, v, __ATOMIC_RELAXED, __HIP_MEMORY_SCOPE_AGENT);
}
__device__ __forceinline__ unsigned cldu(const unsigned* p) {
  return __hip_atomic_load(p, __ATOMIC_RELAXED, __HIP_MEMORY_SCOPE_AGENT);
}

// base[b][g] = b_ih[g]+b_hh[g]+dot(ctx0[b], W_ih[g][E:])
__global__ __launch_bounds__(256) void base_kernel(
    const float* __restrict__ ctxt, const float* __restrict__ Wih,
    const float* __restrict__ bih, const float* __restrict__ bhh,
    float* __restrict__ base) {
  int id = blockIdx.x * 256 + threadIdx.x;
  int b = id & (BATCH - 1);
  int g = id >> 5;
  const float4* c4 = reinterpret_cast<const float4*>(ctxt + (size_t)b * TENC * HD);
  const float4* w4 = reinterpret_cast<const float4*>(Wih + (size_t)g * IND + ED);
  float a = 0.f;
#pragma unroll 8
  for (int kk = 0; kk < HD/4; ++kk) {
    float4 c = c4[kk], w = w4[kk];
    a += c.x*w.x + c.y*w.y + c.z*w.z + c.w*w.w;
  }
  base[(size_t)b * GD + g] = a + bih[g] + bhh[g];
}

// Pack Whh into per-wave MFMA A-fragments (f16) — unchanged from R12.
__global__ __launch_bounds__(256) void packA_kernel(
    const float* __restrict__ Whh, float* __restrict__ ws) {
  uint4* WA = reinterpret_cast<uint4*>(ws + W16_OFF);
  const int t = blockIdx.x * 256 + threadIdx.x;
  const int l = t & 63;
  const int s = (t >> 6) & 1;
  const int w = (t >> 7) & 15;
  const int rg = t >> 11;
  const int m = l & 15;
  const int row = (m & 3) * 1024 + rg * 4 + (m >> 2);
  const int kb = 64 * w + 32 * s + (l >> 4) * 8;
  const float* src = Whh + (size_t)row * 1024 + kb;
  float4 a = *reinterpret_cast<const float4*>(src);
  float4 b = *reinterpret_cast<const float4*>(src + 4);
  uint4 o;
  o.x = pk16(a.x, a.y); o.y = pk16(a.z, a.w);
  o.z = pk16(b.x, b.y); o.w = pk16(b.z, b.w);
  WA[t] = o;
}

// ---------------- Phase 0: wordg[t][row][b] (bf16) — unchanged ----------------
__global__ __launch_bounds__(256) void phase0_wordg(
    const float* __restrict__ gt, const float* __restrict__ Wih,
    float* __restrict__ ws) {
  const int mt = blockIdx.x & 31, nt = blockIdx.x >> 5;
  const int r0 = mt * 128, n0 = nt * 128;
  const int tid = threadIdx.x, tx = tid & 15, ty = tid >> 4;
  unsigned short* wg = reinterpret_cast<unsigned short*>(ws + E_OFF);
  __shared__ float At[128][18];
  __shared__ float BtT[16][132];
  float acc[8][8];
#pragma unroll
  for (int i = 0; i < 8; ++i)
#pragma unroll
    for (int j = 0; j < 8; ++j) acc[i][j] = 0.f;

  const int sr = tid >> 1, sc = (tid & 1) * 8;
  for (int kt = 0; kt < 8; ++kt) {
    const int k0 = kt * 16;
    const float* ap = Wih + (size_t)(r0 + sr) * IND + k0 + sc;
    float4 a0 = *reinterpret_cast<const float4*>(ap);
    float4 a1 = *reinterpret_cast<const float4*>(ap + 4);
    const int n = n0 + sr, t = n >> 5, bb = n & 31;
    float4 b0, b1;
    if (t == 0) {
      b0 = make_float4((k0 + sc == 0) ? 1.f : 0.f, 0.f, 0.f, 0.f);
      b1 = make_float4(0.f, 0.f, 0.f, 0.f);
    } else {
      const float* bp = gt + ((size_t)bb * LL + (t - 1)) * ED + k0 + sc;
      b0 = *reinterpret_cast<const float4*>(bp);
      b1 = *reinterpret_cast<const float4*>(bp + 4);
    }
    __syncthreads();
    *reinterpret_cast<float4*>(&At[sr][sc]) = a0;
    *reinterpret_cast<float4*>(&At[sr][sc + 4]) = a1;
    BtT[sc+0][sr] = b0.x; BtT[sc+1][sr] = b0.y; BtT[sc+2][sr] = b0.z; BtT[sc+3][sr] = b0.w;
    BtT[sc+4][sr] = b1.x; BtT[sc+5][sr] = b1.y; BtT[sc+6][sr] = b1.z; BtT[sc+7][sr] = b1.w;
    __syncthreads();
#pragma unroll
    for (int kk2 = 0; kk2 < 8; ++kk2) {
      float2 av[8];
#pragma unroll
      for (int i = 0; i < 8; ++i)
        av[i] = *reinterpret_cast<const float2*>(&At[ty*8 + i][kk2*2]);
      float4 c00 = *reinterpret_cast<const float4*>(&BtT[kk2*2][tx*8]);
      float4 c01 = *reinterpret_cast<const float4*>(&BtT[kk2*2][tx*8 + 4]);
      float4 c10 = *reinterpret_cast<const float4*>(&BtT[kk2*2+1][tx*8]);
      float4 c11 = *reinterpret_cast<const float4*>(&BtT[kk2*2+1][tx*8 + 4]);
#pragma unroll
      for (int i = 0; i < 8; ++i) {
        acc[i][0] += av[i].x*c00.x + av[i].y*c10.x;
        acc[i][1] += av[i].x*c00.y + av[i].y*c10.y;
        acc[i][2] += av[i].x*c00.z + av[i].y*c10.z;
        acc[i][3] += av[i].x*c00.w + av[i].y*c10.w;
        acc[i][4] += av[i].x*c01.x + av[i].y*c11.x;
        acc[i][5] += av[i].x*c01.y + av[i].y*c11.y;
        acc[i][6] += av[i].x*c01.z + av[i].y*c11.z;
        acc[i][7] += av[i].x*c01.w + av[i].y*c11.w;
      }
    }
  }
  const int nb = n0 + tx * 8, t = nb >> 5, b0i = nb & 31;
#pragma unroll
  for (int i = 0; i < 8; ++i) {
    const int row = r0 + ty * 8 + i;
    uint4 pk;
    pk.x = bfrne(acc[i][0]) | (bfrne(acc[i][1]) << 16);
    pk.y = bfrne(acc[i][2]) | (bfrne(acc[i][3]) << 16);
    pk.z = bfrne(acc[i][4]) | (bfrne(acc[i][5]) << 16);
    pk.w = bfrne(acc[i][6]) | (bfrne(acc[i][7]) << 16);
    *reinterpret_cast<uint4*>(wg + ((size_t)t * GD + row) * 32 + b0i) = pk;
  }
}

// ---------------- Phase A: recurrence via MFMA (race-fixed direct reduce) ----------------
// LDS: h (f16, XOR-swizzled, 64KB) | part[2][16][16][16] f32 (32KB).
__global__ __launch_bounds__(1024, 4) void phaseA(float* __restrict__ ws) {
  const int rg = blockIdx.x;
  const int tid = threadIdx.x;
  const int lane = tid & 63;
  const int w = tid >> 6;
  float* base = ws;
  unsigned short* h16 = reinterpret_cast<unsigned short*>(ws + HBUF_OFF);
  unsigned* arr = reinterpret_cast<unsigned*>(ws + ARR_OFF);
  const unsigned short* wg = reinterpret_cast<const unsigned short*>(ws + E_OFF);
  const uint4* WA = reinterpret_cast<const uint4*>(ws + W16_OFF);
  unsigned short* HAu = reinterpret_cast<unsigned short*>(ws + HA_OFF);

  extern __shared__ float smem[];
  uint4* h_lds = reinterpret_cast<uint4*>(smem);   // 4096 16B units
  float* part = smem + 16384;                      // [T][m][w][b16]

  U4H8 afr0, afr1;
  afr0.u = WA[((size_t)rg * 32 + w * 2 + 0) * 64 + lane];
  afr1.u = WA[((size_t)rg * 32 + w * 2 + 1) * 64 + lane];

  // cell-thread constants (tid < 128): (jloc, b)
  const int cjl = tid >> 5, cb = tid & 31;
  const int cj = rg * 4 + cjl;
  float bs4[4];
  if (tid < 128) {
#pragma unroll
    for (int g = 0; g < 4; ++g)
      bs4[g] = base[(size_t)cb * GD + g * HD + cj];
  }
  float c_reg = 0.f;

  for (int k = 0; k < LL; ++k) {
    uint4 sv[4];
    const uint4* src = reinterpret_cast<const uint4*>(h16 + (size_t)k * HSTEP);
#pragma unroll
    for (int i = 0; i < 4; ++i) sv[i] = src[tid + 1024 * i];
#pragma unroll
    for (int i = 0; i < 4; ++i) {
      const int u = tid + 1024 * i;
      h_lds[u ^ ((u >> 7) & 15)] = sv[i];
    }
    __syncthreads();

    f32x4v acc0 = {0.f, 0.f, 0.f, 0.f}, acc1 = acc0;
    {
      const int b0 = lane & 15, b1 = 16 + (lane & 15);
      const int k0u = 8 * w + (lane >> 4);
      U4H8 bf00, bf01, bf10, bf11;
      bf00.u = h_lds[(b0 * 128 + k0u) ^ (b0 & 15)];
      bf10.u = h_lds[(b1 * 128 + k0u) ^ (b1 & 15)];
      bf01.u = h_lds[(b0 * 128 + k0u + 4) ^ (b0 & 15)];
      bf11.u = h_lds[(b1 * 128 + k0u + 4) ^ (b1 & 15)];
      acc0 = __builtin_amdgcn_mfma_f32_16x16x32_f16(afr0.h, bf00.h, acc0, 0, 0, 0);
      acc1 = __builtin_amdgcn_mfma_f32_16x16x32_f16(afr0.h, bf10.h, acc1, 0, 0, 0);
      acc0 = __builtin_amdgcn_mfma_f32_16x16x32_f16(afr1.h, bf01.h, acc0, 0, 0, 0);
      acc1 = __builtin_amdgcn_mfma_f32_16x16x32_f16(afr1.h, bf11.h, acc1, 0, 0, 0);
    }
#pragma unroll
    for (int q = 0; q < 4; ++q) {
      const int m = (lane >> 4) * 4 + q;
      part[(m * 16 + w) * 16 + (lane & 15)] = acc0[q];
      part[4096 + (m * 16 + w) * 16 + (lane & 15)] = acc1[q];
    }
    __syncthreads();

    // cell: direct 16-way reduce of its 4 gates (race-free: after sync)
    if (tid < 128) {
      const int T = cb >> 4, b16 = cb & 15;
      float s[4];
#pragma unroll
      for (int g = 0; g < 4; ++g) {
        const int m = 4 * cjl + g;
        float acc = 0.f;
#pragma unroll
        for (int ww = 0; ww < 16; ++ww)
          acc += part[T * 4096 + (m * 16 + ww) * 16 + b16];
        s[g] = acc + bf2f(wg[((size_t)k * GD + g * HD + cj) * 32 + cb]) + bs4[g];
      }
      float ig = sigf(s[0]);
      float fg = sigf(s[1]);
      float gg = tanhf_fast(s[2]);
      float og = sigf(s[3]);
      c_reg = fg * c_reg + ig * gg;
      float hv = og * tanhf_fast(c_reg);
      unsigned short hu = (unsigned short)(pk16(hv, hv) & 0xffffu);
      csth(h16 + (size_t)(k + 1) * HSTEP + (size_t)cb * HD + cj, hu);
      // HA scatter: A-frag layout for b1 (output row t = k)
      const size_t unit = (((size_t)cb * 8 + (k >> 4)) * 32 + (cj >> 5)) * 64
                          + ((cj >> 3) & 3) * 16 + (k & 15);
      HAu[unit * 8 + (cj & 7)] = hu;
    }

    if (k < LL - 1) {
      __syncthreads();
      const unsigned tgt = (unsigned)(k + 1);
      if (tid == 0) cstu(arr + rg * 32, tgt);
      if (tid < 64) {
        int ok;
        do {
          ok = 1;
#pragma unroll
          for (int q = 0; q < 4; ++q)
            ok &= (cldu(arr + (lane * 4 + q) * 32) >= (unsigned)tgt);
        } while (!__all(ok));
      }
      __syncthreads();
    }
  }
}

// ---------------- Phase B1: E = H·C^T via MFMA, pure-register ----------------
// 256 blocks: b = blk>>3, pt = blk&7 (128-p tile). Wave w: p-range pt*128+w*32.
__global__ __launch_bounds__(256) void b1_energy(
    const float* __restrict__ ctxt, float* __restrict__ ws) {
  const int b = blockIdx.x >> 3, pt = blockIdx.x & 7;
  const int lane = threadIdx.x & 63, w = threadIdx.x >> 6;
  const int p0 = pt * 128 + w * 32;
  const uint4* HA = reinterpret_cast<const uint4*>(ws + HA_OFF);
  float* E = ws + E_OFF;
  f32x4v acc[8][2];
#pragma unroll
  for (int i = 0; i < 8; ++i) { acc[i][0] = {0,0,0,0}; acc[i][1] = {0,0,0,0}; }

  const float* c0 = ctxt + ((size_t)b * TENC + p0 + (lane & 15)) * HD + (lane >> 4) * 8;
  const float* c1 = c0 + 16 * HD;
  const uint4* hab = HA + (size_t)b * 8 * 32 * 64 + lane;
  for (int ks = 0; ks < 32; ++ks) {
    float4 x0 = *reinterpret_cast<const float4*>(c0 + ks * 32);
    float4 x1 = *reinterpret_cast<const float4*>(c0 + ks * 32 + 4);
    float4 y0 = *reinterpret_cast<const float4*>(c1 + ks * 32);
    float4 y1 = *reinterpret_cast<const float4*>(c1 + ks * 32 + 4);
    U4H8 bf0, bf1;
    bf0.u.x = pk16(x0.x, x0.y); bf0.u.y = pk16(x0.z, x0.w);
    bf0.u.z = pk16(x1.x, x1.y); bf0.u.w = pk16(x1.z, x1.w);
    bf1.u.x = pk16(y0.x, y0.y); bf1.u.y = pk16(y0.z, y0.w);
    bf1.u.z = pk16(y1.x, y1.y); bf1.u.w = pk16(y1.z, y1.w);
    const uint4* ha = hab + (size_t)ks * 64;
#pragma unroll
    for (int mt = 0; mt < 8; ++mt) {
      U4H8 af; af.u = ha[(size_t)mt * 2048];
      acc[mt][0] = __builtin_amdgcn_mfma_f32_16x16x32_f16(af.h, bf0.h, acc[mt][0], 0, 0, 0);
      acc[mt][1] = __builtin_amdgcn_mfma_f32_16x16x32_f16(af.h, bf1.h, acc[mt][1], 0, 0, 0);
    }
  }
#pragma unroll
  for (int mt = 0; mt < 8; ++mt)
#pragma unroll
    for (int q = 0; q < 4; ++q) {
      const int t = mt * 16 + (lane >> 4) * 4 + q;
      E[((size_t)b * LL + t) * TENC + p0 + (lane & 15)] = acc[mt][0][q];
      E[((size_t)b * LL + t) * TENC + p0 + 16 + (lane & 15)] = acc[mt][1][q];
    }
}

// ---------------- Phase B2: row softmax E(f32) -> PA (A-frag f16) ----------------
__global__ __launch_bounds__(1024) void b2_softmax(float* __restrict__ ws) {
  const int b = blockIdx.x >> 3, tc = blockIdx.x & 7;
  const int w = threadIdx.x >> 6, lane = threadIdx.x & 63;
  const int t = tc * 16 + w;
  const float* E = ws + E_OFF;
  unsigned* PA32 = reinterpret_cast<unsigned*>(ws + P_OFF);
  const float4* e4 = reinterpret_cast<const float4*>(E + ((size_t)b * LL + t) * TENC);
  float4 v[4];
#pragma unroll
  for (int c = 0; c < 4; ++c) v[c] = e4[c * 64 + lane];
  float m = fmaxf(fmaxf(fmaxf(v[0].x, v[0].y), fmaxf(v[0].z, v[0].w)),
                  fmaxf(fmaxf(v[1].x, v[1].y), fmaxf(v[1].z, v[1].w)));
  m = fmaxf(m, fmaxf(fmaxf(fmaxf(v[2].x, v[2].y), fmaxf(v[2].z, v[2].w)),
                     fmaxf(fmaxf(v[3].x, v[3].y), fmaxf(v[3].z, v[3].w))));
#pragma unroll
  for (int o = 32; o > 0; o >>= 1) m = fmaxf(m, __shfl_xor(m, o));
  float s = 0.f;
#pragma unroll
  for (int c = 0; c < 4; ++c) {
    v[c].x = __expf(v[c].x - m); v[c].y = __expf(v[c].y - m);
    v[c].z = __expf(v[c].z - m); v[c].w = __expf(v[c].w - m);
    s += v[c].x + v[c].y + v[c].z + v[c].w;
  }
#pragma unroll
  for (int o = 32; o > 0; o >>= 1) s += __shfl_xor(s, o);
  float inv = __builtin_amdgcn_rcpf(s);
#pragma unroll
  for (int c = 0; c < 4; ++c) {
    const int p = (c * 64 + lane) * 4;
    uint2 o2;
    o2.x = pk16(v[c].x * inv, v[c].y * inv);
    o2.y = pk16(v[c].z * inv, v[c].w * inv);
    const size_t unit = (((size_t)b * 8 + tc) * 32 + (p >> 5)) * 64
                        + ((p >> 3) & 3) * 16 + w;
    *reinterpret_cast<uint2*>(PA32 + unit * 4 + ((p & 7) >> 1)) = o2;
  }
}

// ---------------- Phase B3: CTX16 = P·C via MFMA ----------------
// 256 blocks: b = blk>>3, dt = blk&7 (128-d tile). Wave w: d-range dt*128+w*32.
__global__ __launch_bounds__(256) void b3_ctx(
    const float* __restrict__ ctxt, float* __restrict__ ws) {
  const int b = blockIdx.x >> 3, dt = blockIdx.x & 7;
  const int lane = threadIdx.x & 63, w = threadIdx.x >> 6;
  const int d0 = dt * 128 + w * 32;
  const uint4* PA = reinterpret_cast<const uint4*>(ws + P_OFF);
  unsigned short* ctx16u = reinterpret_cast<unsigned short*>(ws + CTX_OFF);
  f32x4v acc[8][2];
#pragma unroll
  for (int i = 0; i < 8; ++i) { acc[i][0] = {0,0,0,0}; acc[i][1] = {0,0,0,0}; }

  const float* cb0 = ctxt + (size_t)b * TENC * HD + d0 + (lane & 15);
  const uint4* pab = PA + (size_t)b * 8 * 32 * 64 + lane;
  for (int ks = 0; ks < 32; ++ks) {
    const int pbase = ks * 32 + (lane >> 4) * 8;
    U4H8 bf0, bf1;
#pragma unroll
    for (int jj = 0; jj < 4; ++jj) {
      const float* r0 = cb0 + (size_t)(pbase + 2 * jj) * HD;
      const float* r1 = r0 + HD;
      unsigned u0 = pk16(r0[0], r1[0]);
      unsigned u1 = pk16(r0[16], r1[16]);
      (&bf0.u.x)[jj] = u0;
      (&bf1.u.x)[jj] = u1;
    }
    const uint4* pa = pab + (size_t)ks * 64;
#pragma unroll
    for (int mt = 0; mt < 8; ++mt) {
      U4H8 af; af.u = pa[(size_t)mt * 2048];
      acc[mt][0] = __builtin_amdgcn_mfma_f32_16x16x32_f16(af.h, bf0.h, acc[mt][0], 0, 0, 0);
      acc[mt][1] = __builtin_amdgcn_mfma_f32_16x16x32_f16(af.h, bf1.h, acc[mt][1], 0, 0, 0);
    }
  }
#pragma unroll
  for (int mt = 0; mt < 8; ++mt)
#pragma unroll
    for (int q = 0; q < 4; ++q) {
      const int t = mt * 16 + (lane >> 4) * 4 + q;
      ctx16u[((size_t)b * LL + t) * 1024 + d0 + (lane & 15)] =
          (unsigned short)(pk16(acc[mt][0][q], acc[mt][0][q]) & 0xffffu);
      ctx16u[((size_t)b * LL + t) * 1024 + d0 + 16 + (lane & 15)] =
          (unsigned short)(pk16(acc[mt][1][q], acc[mt][1][q]) & 0xffffu);
    }
}

// ---------------- Phase B4: logits + log-softmax (f16 dot2) — unchanged ----------------
__global__ __launch_bounds__(256) void b4_logits(
    const float* __restrict__ Wout, const float* __restrict__ bout,
    const float* __restrict__ ws, float* __restrict__ out) {
  const int b = blockIdx.x >> 3, tq = blockIdx.x & 7;
  const int t0 = tq * 16;
  const int tid = threadIdx.x, tx = tid & 31, ty = tid >> 5;
  const unsigned short* h16 = reinterpret_cast<const unsigned short*>(ws + HBUF_OFF);
  const unsigned* ctx16 = reinterpret_cast<const unsigned*>(ws + CTX_OFF);
  __shared__ unsigned At[16][8];
  __shared__ unsigned WtT[8][128];
  __shared__ float lg[16][132];
  float acc[2][4];
#pragma unroll
  for (int i = 0; i < 2; ++i)
#pragma unroll
    for (int j = 0; j < 4; ++j) acc[i][j] = 0.f;

  const int wr = tid >> 1, wh = tid & 1;
  for (int kt = 0; kt < 128; ++kt) {
    const int k0 = kt * 16;
    unsigned au = 0;
    if (tid < 128) {
      const int r = tid >> 3, k = k0 + (tid & 7) * 2;
      if (k < 1024) {
        au = *reinterpret_cast<const unsigned*>(
            h16 + (size_t)(t0 + r + 1) * HSTEP + (size_t)b * HD + k);
      } else {
        au = ctx16[((size_t)b * LL + t0 + r) * 512 + (k - 1024) / 2];
      }
    }
    const float* wsrc = Wout + (size_t)wr * (2*HD) + k0 + wh * 8;
    float4 w0 = *reinterpret_cast<const float4*>(wsrc);
    float4 w1 = *reinterpret_cast<const float4*>(wsrc + 4);
    __syncthreads();
    if (tid < 128) At[tid >> 3][tid & 7] = au;
    WtT[wh*4+0][wr] = pk16(w0.x, w0.y);
    WtT[wh*4+1][wr] = pk16(w0.z, w0.w);
    WtT[wh*4+2][wr] = pk16(w1.x, w1.y);
    WtT[wh*4+3][wr] = pk16(w1.z, w1.w);
    __syncthreads();
#pragma unroll
    for (int kk2 = 0; kk2 < 4; ++kk2) {
      uint2 av[2];
#pragma unroll
      for (int i = 0; i < 2; ++i)
        av[i] = *reinterpret_cast<const uint2*>(&At[ty*2 + i][kk2*2]);
      uint4 cA = *reinterpret_cast<const uint4*>(&WtT[2*kk2][tx*4]);
      uint4 cB = *reinterpret_cast<const uint4*>(&WtT[2*kk2+1][tx*4]);
#pragma unroll
      for (int i = 0; i < 2; ++i) {
        acc[i][0] = dd2(av[i].y, cB.x, dd2(av[i].x, cA.x, acc[i][0]));
        acc[i][1] = dd2(av[i].y, cB.y, dd2(av[i].x, cA.y, acc[i][1]));
        acc[i][2] = dd2(av[i].y, cB.z, dd2(av[i].x, cA.z, acc[i][2]));
        acc[i][3] = dd2(av[i].y, cB.w, dd2(av[i].x, cA.w, acc[i][3]));
      }
    }
  }
#pragma unroll
  for (int i = 0; i < 2; ++i)
#pragma unroll
    for (int j = 0; j < 4; ++j)
      lg[ty*2 + i][tx*4 + j] = acc[i][j] + bout[tx*4 + j];
  __syncthreads();
  const int w = tid >> 6, lane = tid & 63;
#pragma unroll
  for (int rr = 0; rr < 4; ++rr) {
    const int row = w * 4 + rr;
    float v0 = lg[row][lane], v1 = lg[row][lane + 64];
    float mx = fmaxf(v0, v1);
#pragma unroll
    for (int o = 32; o > 0; o >>= 1) mx = fmaxf(mx, __shfl_xor(mx, o));
    float sm = __expf(v0 - mx) + __expf(v1 - mx);
#pragma unroll
    for (int o = 32; o > 0; o >>= 1) sm += __shfl_xor(sm, o);
    float lse = mx + __logf(sm);
    float* op = out + ((size_t)b * LL + t0 + row) * ED;
    op[lane]      = v0 - lse;
    op[lane + 64] = v1 - lse;
  }
}

extern "C" void kernel_launch(void* const* d_in, const int* in_sizes, int n_in,
                              void* d_out, int out_size, void* d_ws, size_t ws_size,
                              hipStream_t stream) {
  (void)in_sizes; (void)n_in; (void)out_size; (void)ws_size;
  const float* ctxt = (const float*)d_in[0];
  const float* gt   = (const float*)d_in[1];
  const float* Wih  = (const float*)d_in[2];
  const float* Whh  = (const float*)d_in[3];
  const float* bih  = (const float*)d_in[4];
  const float* bhh  = (const float*)d_in[5];
  const float* Wout = (const float*)d_in[6];
  const float* bout = (const float*)d_in[7];
  float* out = (float*)d_out;
  float* ws  = (float*)d_ws;

  hipMemsetAsync(ws + HBUF_OFF, 0, (size_t)HSTEP * 2, stream);                 // h_0 = 0 (f16)
  hipMemsetAsync(ws + ARR_OFF, 0, (8192 + 64) * sizeof(float), stream);        // arr flags

  base_kernel<<<(BATCH * GD) / 256, 256, 0, stream>>>(ctxt, Wih, bih, bhh, ws);
  phase0_wordg<<<1024, 256, 0, stream>>>(gt, Wih, ws);
  packA_kernel<<<2048, 256, 0, stream>>>(Whh, ws);

  static int smem_set = 0;
  if (!smem_set) {
    (void)hipFuncSetAttribute((const void*)&phaseA,
                              hipFuncAttributeMaxDynamicSharedMemorySize, 98304);
    smem_set = 1;
  }
  void* argsA[] = { (void*)&ws };
  (void)hipLaunchCooperativeKernel((const void*)&phaseA, dim3(256), dim3(1024),
                                   argsA, 98304, stream);

  b1_energy<<<256, 256, 0, stream>>>(ctxt, ws);
  b2_softmax<<<256, 1024, 0, stream>>>(ws);
  b3_ctx<<<256, 256, 0, stream>>>(ctxt, ws);
  b4_logits<<<256, 256, 0, stream>>>(Wout, bout, ws, out);
}